// Round 7
// baseline (7973.718 us; speedup 1.0000x reference)
//
#include <hip/hip_runtime.h>
#include <hip/hip_bf16.h>

// MMGCRN: graph convs + dense layers on MFMA (bf16x3 split = fp32-class),
// 2-phase double-buffered LDS pipeline with counted vmcnt (T3-minimum).
// B=64, T=12, N=1024, HOR=12, RNN=64, DEC=96, K=3.
constexpr int B_ = 64, T_ = 12, NN = 1024, HOR_ = 12;

typedef __attribute__((ext_vector_type(8))) short short8;   // 8 bf16 (4 VGPRs)
typedef __attribute__((ext_vector_type(4))) float f32x4;    // MFMA C/D frag
typedef unsigned short ushort_t;

static __device__ inline ushort_t f2bh(float v) {
  __hip_bfloat16 h = __float2bfloat16(v);
  return *reinterpret_cast<ushort_t*>(&h);
}
static __device__ inline float bh2f(ushort_t u) {
  __hip_bfloat16 h = *reinterpret_cast<__hip_bfloat16*>(&u);
  return __bfloat162float(h);
}
static __device__ inline void split_bf16(float v, ushort_t& hi, ushort_t& lo) {
  hi = f2bh(v);
  lo = f2bh(v - bh2f(hi));
}

// async global->LDS, 16B per lane (LDS dest = wave-uniform base + lane*16).
static __device__ inline void gload_lds16(const ushort_t* g, ushort_t* l) {
  __builtin_amdgcn_global_load_lds(
      (const __attribute__((address_space(1))) unsigned int*)g,
      (__attribute__((address_space(3))) unsigned int*)l, 16, 0, 0);
}

template <int N>
static __device__ inline void wait_vmcnt() {
  if constexpr (N == 0)  asm volatile("s_waitcnt vmcnt(0)" ::: "memory");
  else if constexpr (N == 6)  asm volatile("s_waitcnt vmcnt(6)" ::: "memory");
  else if constexpr (N == 8)  asm volatile("s_waitcnt vmcnt(8)" ::: "memory");
  else if constexpr (N == 10) asm volatile("s_waitcnt vmcnt(10)" ::: "memory");
  else static_assert(N == 0, "unsupported vmcnt literal");
}

// ---------------------------------------------------------------------------
// C = A (M x Kd) @ B (Ncol x Kd)^T, row-major, 64x64 tile, 4x4/thread. fp32.
__global__ void gemm_nt_kernel(const float* __restrict__ A, const float* __restrict__ Bm,
                               float* __restrict__ C, int Ncol, int Kd) {
  __shared__ float As[16][68];
  __shared__ float Bs[16][68];
  const int bm = blockIdx.y * 64, bn = blockIdx.x * 64;
  const int tid = threadIdx.x;
  const int tx = tid & 15, ty = tid >> 4;
  float acc[4][4] = {};
  for (int k0 = 0; k0 < Kd; k0 += 16) {
#pragma unroll
    for (int r = 0; r < 4; ++r) {
      const int m = (tid >> 4) + r * 16;
      const int kk = tid & 15;
      const int k = k0 + kk;
      As[kk][m] = (k < Kd) ? A[(size_t)(bm + m) * Kd + k] : 0.f;
      Bs[kk][m] = (k < Kd) ? Bm[(size_t)(bn + m) * Kd + k] : 0.f;
    }
    __syncthreads();
#pragma unroll
    for (int kk = 0; kk < 16; ++kk) {
      float a[4], b[4];
#pragma unroll
      for (int i = 0; i < 4; ++i) a[i] = As[kk][ty * 4 + i];
#pragma unroll
      for (int j = 0; j < 4; ++j) b[j] = Bs[kk][tx * 4 + j];
#pragma unroll
      for (int i = 0; i < 4; ++i)
#pragma unroll
        for (int j = 0; j < 4; ++j) acc[i][j] += a[i] * b[j];
    }
    __syncthreads();
  }
#pragma unroll
  for (int i = 0; i < 4; ++i)
#pragma unroll
    for (int j = 0; j < 4; ++j)
      C[(size_t)(bm + ty * 4 + i) * Ncol + bn + tx * 4 + j] = acc[i][j];
}

// ---------------------------------------------------------------------------
// In-place row softmax(relu(x)) over 1024 cols; also emits bf16 hi/lo split.
__global__ void relu_softmax_kernel(float* __restrict__ S, ushort_t* __restrict__ Sh,
                                    ushort_t* __restrict__ Sl) {
  const int row = blockIdx.x;
  float* r = S + (size_t)row * NN;
  const int tid = threadIdx.x;  // 256
  float v[4];
  float mx = 0.f;
#pragma unroll
  for (int j = 0; j < 4; ++j) {
    float xv = fmaxf(r[tid + j * 256], 0.f);
    v[j] = xv;
    mx = fmaxf(mx, xv);
  }
#pragma unroll
  for (int off = 1; off < 64; off <<= 1) mx = fmaxf(mx, __shfl_xor(mx, off));
  __shared__ float sred[4];
  const int wv = tid >> 6;
  if ((tid & 63) == 0) sred[wv] = mx;
  __syncthreads();
  mx = fmaxf(fmaxf(sred[0], sred[1]), fmaxf(sred[2], sred[3]));
  __syncthreads();
  float s = 0.f;
#pragma unroll
  for (int j = 0; j < 4; ++j) { v[j] = expf(v[j] - mx); s += v[j]; }
#pragma unroll
  for (int off = 1; off < 64; off <<= 1) s += __shfl_xor(s, off);
  if ((tid & 63) == 0) sred[wv] = s;
  __syncthreads();
  s = sred[0] + sred[1] + sred[2] + sred[3];
  const float inv = 1.f / s;
#pragma unroll
  for (int j = 0; j < 4; ++j) {
    const float sv = v[j] * inv;
    const size_t e = (size_t)row * NN + tid + j * 256;
    r[tid + j * 256] = sv;
    ushort_t hi, lo;
    split_bf16(sv, hi, lo);
    Sh[e] = hi;
    Sl[e] = lo;
  }
}

// ---------------------------------------------------------------------------
// S2 = 2*S@S - I, emitted directly as bf16 hi/lo split.
__global__ void cheb_kernel(const float* __restrict__ S, ushort_t* __restrict__ S2h,
                            ushort_t* __restrict__ S2l) {
  __shared__ float As[16][68];
  __shared__ float Bs[16][68];
  const int bm = blockIdx.y * 64, bn = blockIdx.x * 64;
  const int tid = threadIdx.x;
  const int tx = tid & 15, ty = tid >> 4;
  float acc[4][4] = {};
  for (int k0 = 0; k0 < NN; k0 += 16) {
#pragma unroll
    for (int r = 0; r < 4; ++r) {
      const int m = (tid >> 4) + r * 16, kk = tid & 15;
      As[kk][m] = S[(size_t)(bm + m) * NN + k0 + kk];
    }
#pragma unroll
    for (int r = 0; r < 4; ++r) {
      const int kk = (tid >> 6) + r * 4, c = tid & 63;
      Bs[kk][c] = S[(size_t)(k0 + kk) * NN + bn + c];
    }
    __syncthreads();
#pragma unroll
    for (int kk = 0; kk < 16; ++kk) {
      float a[4], b[4];
#pragma unroll
      for (int i = 0; i < 4; ++i) a[i] = As[kk][ty * 4 + i];
#pragma unroll
      for (int j = 0; j < 4; ++j) b[j] = Bs[kk][tx * 4 + j];
#pragma unroll
      for (int i = 0; i < 4; ++i)
#pragma unroll
        for (int j = 0; j < 4; ++j) acc[i][j] += a[i] * b[j];
    }
    __syncthreads();
  }
#pragma unroll
  for (int i = 0; i < 4; ++i) {
    const int row = bm + ty * 4 + i;
#pragma unroll
    for (int j = 0; j < 4; ++j) {
      const int col = bn + tx * 4 + j;
      const float val = 2.f * acc[i][j] - (row == col ? 1.f : 0.f);
      ushort_t hi, lo;
      split_bf16(val, hi, lo);
      S2h[(size_t)row * NN + col] = hi;
      S2l[(size_t)row * NN + col] = lo;
    }
  }
}

// ---------------------------------------------------------------------------
// Wt[no][k] = W[k][no], bf16 hi/lo, zero-padded to [NOP][KP].
__global__ void wt_kernel(const float* __restrict__ W, ushort_t* __restrict__ Wth,
                          ushort_t* __restrict__ Wtl, int KK, int NO, int KP, int NOP) {
  const int e = blockIdx.x * 256 + threadIdx.x;
  if (e >= NOP * KP) return;
  const int no = e / KP, k = e - no * KP;
  const float v = (no < NO && k < KK) ? W[(size_t)k * NO + no] : 0.f;
  ushort_t hi, lo;
  split_bf16(v, hi, lo);
  Wth[e] = hi;
  Wtl[e] = lo;
}

// ---------------------------------------------------------------------------
// prep: build cell input on the fly; write Ag (idx-major, bf16 hi/lo) and
// XT (j-major transpose, bf16 hi/lo). One block = 64 j x 64 nodes.
// MODE 0: enc build [x_t, h]; 1: enc cand [x_t, z*h];
//      2: dec build [go, yc, h]; 3: dec cand [go, yc, z*h].
template <int C, int KP, int MODE>
__global__ void prep_kernel(const float* __restrict__ src0, const float* __restrict__ src1,
                            const float* __restrict__ hst, const float* __restrict__ zr,
                            ushort_t* __restrict__ Agh, ushort_t* __restrict__ Agl,
                            ushort_t* __restrict__ XTh, ushort_t* __restrict__ XTl, int t) {
  __shared__ float tile[64][65];
  const int bj = blockIdx.x * 64, bn = blockIdx.y * 64;
  const int tid = threadIdx.x;
  const int jl = tid & 63, nq = tid >> 6;
  const int j = bj + jl;
  const int b = j / C, c = j - b * C;
#pragma unroll
  for (int r = 0; r < 16; ++r) {
    const int node = bn + nq + r * 4;
    const int idx = node * 64 + b;
    float v;
    if (MODE == 0) {
      v = (c == 0) ? src0[((size_t)b * T_ + t) * NN + node]
                   : hst[(size_t)idx * 64 + (c - 1)];
    } else if (MODE == 1) {
      v = (c == 0) ? src0[((size_t)b * T_ + t) * NN + node]
                   : zr[(size_t)idx * 128 + (c - 1)] * hst[(size_t)idx * 64 + (c - 1)];
    } else if (MODE == 2) {
      v = (c == 0) ? src0[idx]
        : (c == 1) ? src1[((size_t)b * HOR_ + t) * NN + node]
                   : hst[(size_t)idx * 96 + (c - 2)];
    } else {
      v = (c == 0) ? src0[idx]
        : (c == 1) ? src1[((size_t)b * HOR_ + t) * NN + node]
                   : zr[(size_t)idx * 192 + (c - 2)] * hst[(size_t)idx * 96 + (c - 2)];
    }
    tile[nq + r * 4][jl] = v;
    ushort_t hi, lo;
    split_bf16(v, hi, lo);
    Agh[(size_t)idx * KP + c] = hi;
    Agl[(size_t)idx * KP + c] = lo;
  }
  __syncthreads();
  const int nl = tid & 63, jq = tid >> 6;
#pragma unroll
  for (int r = 0; r < 16; ++r) {
    const int jj = bj + jq + r * 4;
    const float v = tile[nl][jq + r * 4];
    ushort_t hi, lo;
    split_bf16(v, hi, lo);
    XTh[(size_t)jj * NN + bn + nl] = hi;
    XTl[(size_t)jj * NN + bn + nl] = lo;
  }
}

// ---------------------------------------------------------------------------
// Graph conv, double-buffered LDS + counted vmcnt.
// Per block: 64 nodes x 128 j, both supports. Writes slices 1,2 of Ag.
template <int C, int KP>
__global__ void graph_mfma_kernel(const ushort_t* __restrict__ S1h,
                                  const ushort_t* __restrict__ S1l,
                                  const ushort_t* __restrict__ S2h,
                                  const ushort_t* __restrict__ S2l,
                                  const ushort_t* __restrict__ XTh,
                                  const ushort_t* __restrict__ XTl,
                                  ushort_t* __restrict__ Agh, ushort_t* __restrict__ Agl) {
  constexpr int W = B_ * C;
  constexpr int ASZ = 4 * 64 * 32, BSZ = 2 * 128 * 32;
  __shared__ __align__(16) ushort_t sA[2][ASZ];   // 32 KB
  __shared__ __align__(16) ushort_t sB[2][BSZ];   // 32 KB
  const int bj = blockIdx.x * 128;
  const int bn = blockIdx.y * 64;
  const int tid = threadIdx.x;
  const int w = tid >> 6, lane = tid & 63;
  const int row = lane & 15, kq = lane >> 4;

  const ushort_t* myA = (w == 0) ? S1h : (w == 1) ? S1l : (w == 2) ? S2h : S2l;
  const ushort_t* myB = (w < 2) ? XTh : XTl;
  const int bhalf = (w & 1) * 64;
  const int aoff_w = w * (64 * 32);
  const int boff_w = (w < 2 ? 0 : 128 * 32) + bhalf * 32;
  const int srow = lane >> 2;
  const int scol = lane & 3;

  const int s = w >> 1;
  const int jhalf = (w & 1) * 64;
  const int a_hi = (2 * s) * (64 * 32), a_lo = (2 * s + 1) * (64 * 32);

  auto stage = [&](int buf, int k0) {
#pragma unroll
    for (int i = 0; i < 4; ++i) {
      const ushort_t* g = myA + (size_t)(bn + i * 16 + srow) * NN + k0 + scol * 8;
      gload_lds16(g, sA[buf] + aoff_w + i * 16 * 32);
    }
#pragma unroll
    for (int i = 0; i < 4; ++i) {
      const ushort_t* g = myB + (size_t)(bj + bhalf + i * 16 + srow) * NN + k0 + scol * 8;
      gload_lds16(g, sB[buf] + boff_w + i * 16 * 32);
    }
  };

  f32x4 acc[4][4] = {};
  stage(0, 0);
  constexpr int NT = NN / 32;
  for (int it = 0; it < NT; ++it) {
    const int cur = it & 1;
    if (it + 1 < NT) {
      stage(cur ^ 1, (it + 1) * 32);
      wait_vmcnt<8>();   // drain cur's 8 loads; next batch stays in flight
    } else {
      wait_vmcnt<0>();
    }
    __builtin_amdgcn_s_barrier();
    const ushort_t* Ah_lds = sA[cur] + a_hi;
    const ushort_t* Al_lds = sA[cur] + a_lo;
    const ushort_t* Bh_lds = sB[cur];
    const ushort_t* Bl_lds = sB[cur] + 128 * 32;
    short8 ah[4], al[4];
#pragma unroll
    for (int mt = 0; mt < 4; ++mt) {
      ah[mt] = *(const short8*)(Ah_lds + (mt * 16 + row) * 32 + kq * 8);
      al[mt] = *(const short8*)(Al_lds + (mt * 16 + row) * 32 + kq * 8);
    }
#pragma unroll
    for (int nt = 0; nt < 4; ++nt) {
      const short8 bh = *(const short8*)(Bh_lds + (jhalf + nt * 16 + row) * 32 + kq * 8);
      const short8 bl = *(const short8*)(Bl_lds + (jhalf + nt * 16 + row) * 32 + kq * 8);
#pragma unroll
      for (int mt = 0; mt < 4; ++mt) {
        acc[mt][nt] = __builtin_amdgcn_mfma_f32_16x16x32_bf16(ah[mt], bh, acc[mt][nt], 0, 0, 0);
        acc[mt][nt] = __builtin_amdgcn_mfma_f32_16x16x32_bf16(ah[mt], bl, acc[mt][nt], 0, 0, 0);
        acc[mt][nt] = __builtin_amdgcn_mfma_f32_16x16x32_bf16(al[mt], bh, acc[mt][nt], 0, 0, 0);
      }
    }
    __builtin_amdgcn_s_barrier();  // compute(cur) done before cur is restaged
  }
  // D mapping: col (=j) = lane&15, row (=node) = (lane>>4)*4 + reg.
  const int slice_off = (s + 1) * C;
#pragma unroll
  for (int nt = 0; nt < 4; ++nt) {
    const int j = bj + jhalf + nt * 16 + row;
    if (j < W) {
      const int b = j / C, c = j - b * C;
      const size_t coloff = (size_t)(slice_off + c);
#pragma unroll
      for (int mt = 0; mt < 4; ++mt) {
        const int node0 = bn + mt * 16 + kq * 4;
#pragma unroll
        for (int r = 0; r < 4; ++r) {
          const size_t a = (size_t)((node0 + r) * 64 + b) * KP + coloff;
          ushort_t hi, lo;
          split_bf16(acc[mt][nt][r], hi, lo);
          Agh[a] = hi;
          Agl[a] = lo;
        }
      }
    }
  }
}

// ---------------------------------------------------------------------------
// Dense on MFMA, double-buffered LDS + counted vmcnt.
// Block: 128 rows x NO cols; 4 waves, wave w = rows [w*32, +32).
// MODE 0: sigmoid -> outp(zr, stride NO=2H). MODE 1: fused GRU combine.
template <int KP, int NO, int NOP, int MODE, int H>
__global__ void dense_mfma_kernel(const ushort_t* __restrict__ Agh,
                                  const ushort_t* __restrict__ Agl,
                                  const ushort_t* __restrict__ Wth,
                                  const ushort_t* __restrict__ Wtl,
                                  const float* __restrict__ bias,
                                  float* __restrict__ outp,
                                  const float* __restrict__ zrin) {
  constexpr int NFR = NO / 16;
  constexpr int NBT = NOP / 16;                 // B row-tiles
  constexpr int NL = 4 + 2 * ((NBT + 3) / 4);   // loads per wave per stage
  constexpr int ASZ = 128 * 32, BSZ = NOP * 32;
  __shared__ __align__(16) ushort_t sAh[2][ASZ];
  __shared__ __align__(16) ushort_t sAl[2][ASZ];
  __shared__ __align__(16) ushort_t sBh[2][BSZ];
  __shared__ __align__(16) ushort_t sBl[2][BSZ];
  const int row0 = blockIdx.x * 128;
  const int tid = threadIdx.x;
  const int w = tid >> 6, lane = tid & 63;
  const int col16 = lane & 15, four = lane >> 4;
  const int srow = lane >> 2, scol = (lane & 3) * 8;

  auto stage = [&](int buf, int k0) {
    for (int c = w; c < 8; c += 4) {
      const size_t g = (size_t)(row0 + c * 16 + srow) * KP + k0 + scol;
      gload_lds16(Agh + g, sAh[buf] + c * 512);
      gload_lds16(Agl + g, sAl[buf] + c * 512);
    }
    for (int c = w; c < NBT; c += 4) {
      const size_t g = (size_t)(c * 16 + srow) * KP + k0 + scol;
      gload_lds16(Wth + g, sBh[buf] + c * 512);
      gload_lds16(Wtl + g, sBl[buf] + c * 512);
    }
  };

  f32x4 acc[2][NFR] = {};
  stage(0, 0);
  constexpr int NT = KP / 32;
  for (int it = 0; it < NT; ++it) {
    const int cur = it & 1;
    if (it + 1 < NT) {
      stage(cur ^ 1, (it + 1) * 32);
      wait_vmcnt<NL>();
    } else {
      wait_vmcnt<0>();
    }
    __builtin_amdgcn_s_barrier();
    short8 ah[2], al[2];
#pragma unroll
    for (int mt = 0; mt < 2; ++mt) {
      const int r = (w * 32 + mt * 16 + col16) * 32 + four * 8;
      ah[mt] = *(const short8*)(sAh[cur] + r);
      al[mt] = *(const short8*)(sAl[cur] + r);
    }
#pragma unroll
    for (int nt = 0; nt < NFR; ++nt) {
      const int r = (nt * 16 + col16) * 32 + four * 8;
      const short8 bh = *(const short8*)(sBh[cur] + r);
      const short8 bl = *(const short8*)(sBl[cur] + r);
#pragma unroll
      for (int mt = 0; mt < 2; ++mt) {
        acc[mt][nt] = __builtin_amdgcn_mfma_f32_16x16x32_bf16(ah[mt], bh, acc[mt][nt], 0, 0, 0);
        acc[mt][nt] = __builtin_amdgcn_mfma_f32_16x16x32_bf16(ah[mt], bl, acc[mt][nt], 0, 0, 0);
        acc[mt][nt] = __builtin_amdgcn_mfma_f32_16x16x32_bf16(al[mt], bh, acc[mt][nt], 0, 0, 0);
      }
    }
    __builtin_amdgcn_s_barrier();
  }
#pragma unroll
  for (int nt = 0; nt < NFR; ++nt) {
    const int col = nt * 16 + col16;
    const float bv = bias[col];
#pragma unroll
    for (int mt = 0; mt < 2; ++mt) {
      const int rbase = row0 + w * 32 + mt * 16 + four * 4;
#pragma unroll
      for (int r = 0; r < 4; ++r) {
        const int row = rbase + r;
        const float v = acc[mt][nt][r] + bv;
        if (MODE == 0) {
          outp[(size_t)row * NO + col] = 1.f / (1.f + expf(-v));
        } else {
          const float rg = zrin[(size_t)row * (2 * H) + H + col];
          const float hv = outp[(size_t)row * H + col];
          outp[(size_t)row * H + col] = rg * hv + (1.f - rg) * tanhf(v);
        }
      }
    }
  }
}

// ---------------------------------------------------------------------------
// attention + prototype + W_E + h0 build, fused. One thread per (n,b).
__global__ void attn_kernel(const float* __restrict__ h, const float* __restrict__ Wq,
                            const float* __restrict__ Mem, const float* __restrict__ FCE,
                            float* __restrict__ hB, float* __restrict__ WE) {
  __shared__ float sWq[64 * 32];
  __shared__ float sM[10 * 32];
  __shared__ float sF[32 * 8];
  const int tid = threadIdx.x;
  for (int i = tid; i < 64 * 32; i += 256) sWq[i] = Wq[i];
  for (int i = tid; i < 10 * 32; i += 256) sM[i] = Mem[i];
  for (int i = tid; i < 32 * 8; i += 256) sF[i] = FCE[i];
  __syncthreads();
  const int idx = blockIdx.x * 256 + tid;
  const float* hp = h + (size_t)idx * 64;
  float* hd = hB + (size_t)idx * 96;
  float q[32] = {};
  for (int i0 = 0; i0 < 16; ++i0) {
    const float4 h4 = *(const float4*)(hp + i0 * 4);
#pragma unroll
    for (int jj = 0; jj < 4; ++jj) {
      const float hv = ((const float*)&h4)[jj];
      hd[i0 * 4 + jj] = hv;  // h0 = [h, proto]
      const int i = i0 * 4 + jj;
#pragma unroll
      for (int c = 0; c < 32; ++c) q[c] += hv * sWq[i * 32 + c];
    }
  }
  float lg[10];
  float mx = -1e30f;
#pragma unroll
  for (int m = 0; m < 10; ++m) {
    float s = 0.f;
#pragma unroll
    for (int c = 0; c < 32; ++c) s += q[c] * sM[m * 32 + c];
    lg[m] = s;
    mx = fmaxf(mx, s);
  }
  float den = 0.f;
#pragma unroll
  for (int m = 0; m < 10; ++m) { lg[m] = expf(lg[m] - mx); den += lg[m]; }
  const float inv = 1.f / den;
  float p[32] = {};
#pragma unroll
  for (int m = 0; m < 10; ++m) {
    const float a = lg[m] * inv;
#pragma unroll
    for (int c = 0; c < 32; ++c) p[c] += a * sM[m * 32 + c];
  }
#pragma unroll
  for (int c = 0; c < 32; ++c) hd[64 + c] = p[c];
  float* wd = WE + (size_t)idx * 8;
#pragma unroll
  for (int e = 0; e < 8; ++e) {
    float s = 0.f;
#pragma unroll
    for (int c = 0; c < 32; ++c) s += p[c] * sF[c * 8 + e];
    wd[e] = s;
  }
}

__global__ void proj_kernel(const float* __restrict__ h, const float* __restrict__ pW,
                            const float* __restrict__ pb, float* __restrict__ go,
                            float* __restrict__ out, int t) {
  __shared__ float sW[96];
  if (threadIdx.x < 96) sW[threadIdx.x] = pW[threadIdx.x];
  __syncthreads();
  const int idx = blockIdx.x * 256 + threadIdx.x;
  const float* hp = h + (size_t)idx * 96;
  float acc = pb[0];
  for (int j0 = 0; j0 < 24; ++j0) {
    const float4 h4 = *(const float4*)(hp + j0 * 4);
    acc += h4.x * sW[j0 * 4] + h4.y * sW[j0 * 4 + 1] + h4.z * sW[j0 * 4 + 2] + h4.w * sW[j0 * 4 + 3];
  }
  go[idx] = acc;
  const int n = idx >> 6, b = idx & 63;
  out[((size_t)b * HOR_ + t) * NN + n] = acc;
}

// ---------------------------------------------------------------------------
extern "C" void kernel_launch(void* const* d_in, const int* in_sizes, int n_in,
                              void* d_out, int out_size, void* d_ws, size_t ws_size,
                              hipStream_t stream) {
  const float* x    = (const float*)d_in[0];
  const float* ycov = (const float*)d_in[1];
  const float* emb  = (const float*)d_in[2];
  const float* egW  = (const float*)d_in[3];
  const float* egb  = (const float*)d_in[4];
  const float* euW  = (const float*)d_in[5];
  const float* eub  = (const float*)d_in[6];
  const float* Mem  = (const float*)d_in[7];
  const float* Wq   = (const float*)d_in[8];
  const float* FCE  = (const float*)d_in[9];
  const float* dgW  = (const float*)d_in[10];
  const float* dgb  = (const float*)d_in[11];
  const float* duW  = (const float*)d_in[12];
  const float* dub  = (const float*)d_in[13];
  const float* pW   = (const float*)d_in[14];
  const float* pb   = (const float*)d_in[15];
  float* out = (float*)d_out;

  char* w = (char*)d_ws;
  auto alloc = [&](size_t bytes) {
    void* p = (void*)w;
    w += (bytes + 255) & ~(size_t)255;
    return p;
  };
  float* S1  = (float*)alloc((size_t)NN * NN * 4);
  float* zr  = (float*)alloc((size_t)NN * B_ * 192 * 4);
  float* hA  = (float*)alloc((size_t)NN * B_ * 64 * 4);
  float* hB  = (float*)alloc((size_t)NN * B_ * 96 * 4);
  float* go  = (float*)alloc((size_t)NN * B_ * 4);
  float* WE  = (float*)alloc((size_t)NN * B_ * 8 * 4);
  ushort_t* S1h = (ushort_t*)alloc((size_t)NN * NN * 2);
  ushort_t* S1l = (ushort_t*)alloc((size_t)NN * NN * 2);
  ushort_t* S2h = (ushort_t*)alloc((size_t)NN * NN * 2);
  ushort_t* S2l = (ushort_t*)alloc((size_t)NN * NN * 2);
  ushort_t* XTh = (ushort_t*)alloc((size_t)B_ * 98 * NN * 2);
  ushort_t* XTl = (ushort_t*)alloc((size_t)B_ * 98 * NN * 2);
  ushort_t* Agh = (ushort_t*)alloc((size_t)NN * B_ * 320 * 2);
  ushort_t* Agl = (ushort_t*)alloc((size_t)NN * B_ * 320 * 2);
  ushort_t* WtegH = (ushort_t*)alloc(128 * 224 * 2);
  ushort_t* WtegL = (ushort_t*)alloc(128 * 224 * 2);
  ushort_t* WteuH = (ushort_t*)alloc(64 * 224 * 2);
  ushort_t* WteuL = (ushort_t*)alloc(64 * 224 * 2);
  ushort_t* WtdgH = (ushort_t*)alloc(192 * 320 * 2);
  ushort_t* WtdgL = (ushort_t*)alloc(192 * 320 * 2);
  ushort_t* WtduH = (ushort_t*)alloc(128 * 320 * 2);
  ushort_t* WtduL = (ushort_t*)alloc(128 * 320 * 2);
  (void)ws_size; (void)in_sizes; (void)n_in; (void)out_size;

  const dim3 blk(256);

  // ---- weight transposes + buffer init (pad regions must be defined) ----
  wt_kernel<<<(128 * 224 + 255) / 256, blk, 0, stream>>>(egW, WtegH, WtegL, 195, 128, 224, 128);
  wt_kernel<<<(64 * 224 + 255) / 256, blk, 0, stream>>>(euW, WteuH, WteuL, 195, 64, 224, 64);
  wt_kernel<<<(192 * 320 + 255) / 256, blk, 0, stream>>>(dgW, WtdgH, WtdgL, 294, 192, 320, 192);
  wt_kernel<<<(128 * 320 + 255) / 256, blk, 0, stream>>>(duW, WtduH, WtduL, 294, 96, 320, 128);
  hipMemsetAsync(Agh, 0, (size_t)NN * B_ * 320 * 2, stream);
  hipMemsetAsync(Agl, 0, (size_t)NN * B_ * 320 * 2, stream);
  hipMemsetAsync(hA, 0, (size_t)NN * B_ * 64 * 4, stream);
  hipMemsetAsync(go, 0, (size_t)NN * B_ * 4, stream);

  // ---- encoder supports ----
  gemm_nt_kernel<<<dim3(16, 16), blk, 0, stream>>>(emb, emb, S1, NN, 8);
  relu_softmax_kernel<<<NN, blk, 0, stream>>>(S1, S1h, S1l);
  cheb_kernel<<<dim3(16, 16), blk, 0, stream>>>(S1, S2h, S2l);

  // ---- encoder scan ----  (W_enc = 4160; graph grid 33*128 = 4224 padded)
  for (int t = 0; t < T_; ++t) {
    prep_kernel<65, 224, 0><<<dim3(65, 16), blk, 0, stream>>>(x, nullptr, hA, nullptr, Agh, Agl, XTh, XTl, t);
    graph_mfma_kernel<65, 224><<<dim3(33, 16), blk, 0, stream>>>(S1h, S1l, S2h, S2l, XTh, XTl, Agh, Agl);
    dense_mfma_kernel<224, 128, 128, 0, 64><<<512, blk, 0, stream>>>(Agh, Agl, WtegH, WtegL, egb, zr, nullptr);
    prep_kernel<65, 224, 1><<<dim3(65, 16), blk, 0, stream>>>(x, nullptr, hA, zr, Agh, Agl, XTh, XTl, t);
    graph_mfma_kernel<65, 224><<<dim3(33, 16), blk, 0, stream>>>(S1h, S1l, S2h, S2l, XTh, XTl, Agh, Agl);
    dense_mfma_kernel<224, 64, 64, 1, 64><<<512, blk, 0, stream>>>(Agh, Agl, WteuH, WteuL, eub, hA, zr);
  }

  // ---- attention / memory / decoder supports ----
  attn_kernel<<<256, blk, 0, stream>>>(hA, Wq, Mem, FCE, hB, WE);
  gemm_nt_kernel<<<dim3(16, 16), blk, 0, stream>>>(WE, WE, S1, NN, 512);
  relu_softmax_kernel<<<NN, blk, 0, stream>>>(S1, S1h, S1l);
  cheb_kernel<<<dim3(16, 16), blk, 0, stream>>>(S1, S2h, S2l);

  // ---- decoder scan ----  (W_dec = 6272 = 49*128 exactly)
  for (int t = 0; t < HOR_; ++t) {
    prep_kernel<98, 320, 2><<<dim3(98, 16), blk, 0, stream>>>(go, ycov, hB, nullptr, Agh, Agl, XTh, XTl, t);
    graph_mfma_kernel<98, 320><<<dim3(49, 16), blk, 0, stream>>>(S1h, S1l, S2h, S2l, XTh, XTl, Agh, Agl);
    dense_mfma_kernel<320, 192, 192, 0, 96><<<512, blk, 0, stream>>>(Agh, Agl, WtdgH, WtdgL, dgb, zr, nullptr);
    prep_kernel<98, 320, 3><<<dim3(98, 16), blk, 0, stream>>>(go, ycov, hB, zr, Agh, Agl, XTh, XTl, t);
    graph_mfma_kernel<98, 320><<<dim3(49, 16), blk, 0, stream>>>(S1h, S1l, S2h, S2l, XTh, XTl, Agh, Agl);
    dense_mfma_kernel<320, 96, 128, 1, 96><<<512, blk, 0, stream>>>(Agh, Agl, WtduH, WtduL, dub, hB, zr);
    proj_kernel<<<256, blk, 0, stream>>>(hB, pW, pb, go, out, t);
  }
}

// Round 8
// 6724.792 us; speedup vs baseline: 1.1857x; 1.1857x over previous
//
#include <hip/hip_runtime.h>
#include <hip/hip_bf16.h>

// MMGCRN: graph convs + dense layers on MFMA (bf16x3 split = fp32-class).
// Graph grid padded to multiple-of-8 j-tiles -> stable j-tile->XCD binding
// (B-chunk stays resident in its XCD's L2 across all bn rows).
// B=64, T=12, N=1024, HOR=12, RNN=64, DEC=96, K=3.
constexpr int B_ = 64, T_ = 12, NN = 1024, HOR_ = 12;

typedef __attribute__((ext_vector_type(8))) short short8;   // 8 bf16 (4 VGPRs)
typedef __attribute__((ext_vector_type(4))) float f32x4;    // MFMA C/D frag
typedef unsigned short ushort_t;

static __device__ inline ushort_t f2bh(float v) {
  __hip_bfloat16 h = __float2bfloat16(v);
  return *reinterpret_cast<ushort_t*>(&h);
}
static __device__ inline float bh2f(ushort_t u) {
  __hip_bfloat16 h = *reinterpret_cast<__hip_bfloat16*>(&u);
  return __bfloat162float(h);
}
static __device__ inline void split_bf16(float v, ushort_t& hi, ushort_t& lo) {
  hi = f2bh(v);
  lo = f2bh(v - bh2f(hi));
}

// async global->LDS, 16B per lane (LDS dest = wave-uniform base + lane*16).
static __device__ inline void gload_lds16(const ushort_t* g, ushort_t* l) {
  __builtin_amdgcn_global_load_lds(
      (const __attribute__((address_space(1))) unsigned int*)g,
      (__attribute__((address_space(3))) unsigned int*)l, 16, 0, 0);
}

// ---------------------------------------------------------------------------
// C = A (M x Kd) @ B (Ncol x Kd)^T, row-major, 64x64 tile, 4x4/thread. fp32.
__global__ void gemm_nt_kernel(const float* __restrict__ A, const float* __restrict__ Bm,
                               float* __restrict__ C, int Ncol, int Kd) {
  __shared__ float As[16][68];
  __shared__ float Bs[16][68];
  const int bm = blockIdx.y * 64, bn = blockIdx.x * 64;
  const int tid = threadIdx.x;
  const int tx = tid & 15, ty = tid >> 4;
  float acc[4][4] = {};
  for (int k0 = 0; k0 < Kd; k0 += 16) {
#pragma unroll
    for (int r = 0; r < 4; ++r) {
      const int m = (tid >> 4) + r * 16;
      const int kk = tid & 15;
      const int k = k0 + kk;
      As[kk][m] = (k < Kd) ? A[(size_t)(bm + m) * Kd + k] : 0.f;
      Bs[kk][m] = (k < Kd) ? Bm[(size_t)(bn + m) * Kd + k] : 0.f;
    }
    __syncthreads();
#pragma unroll
    for (int kk = 0; kk < 16; ++kk) {
      float a[4], b[4];
#pragma unroll
      for (int i = 0; i < 4; ++i) a[i] = As[kk][ty * 4 + i];
#pragma unroll
      for (int j = 0; j < 4; ++j) b[j] = Bs[kk][tx * 4 + j];
#pragma unroll
      for (int i = 0; i < 4; ++i)
#pragma unroll
        for (int j = 0; j < 4; ++j) acc[i][j] += a[i] * b[j];
    }
    __syncthreads();
  }
#pragma unroll
  for (int i = 0; i < 4; ++i)
#pragma unroll
    for (int j = 0; j < 4; ++j)
      C[(size_t)(bm + ty * 4 + i) * Ncol + bn + tx * 4 + j] = acc[i][j];
}

// ---------------------------------------------------------------------------
// In-place row softmax(relu(x)) over 1024 cols; also emits bf16 hi/lo split.
__global__ void relu_softmax_kernel(float* __restrict__ S, ushort_t* __restrict__ Sh,
                                    ushort_t* __restrict__ Sl) {
  const int row = blockIdx.x;
  float* r = S + (size_t)row * NN;
  const int tid = threadIdx.x;  // 256
  float v[4];
  float mx = 0.f;
#pragma unroll
  for (int j = 0; j < 4; ++j) {
    float xv = fmaxf(r[tid + j * 256], 0.f);
    v[j] = xv;
    mx = fmaxf(mx, xv);
  }
#pragma unroll
  for (int off = 1; off < 64; off <<= 1) mx = fmaxf(mx, __shfl_xor(mx, off));
  __shared__ float sred[4];
  const int wv = tid >> 6;
  if ((tid & 63) == 0) sred[wv] = mx;
  __syncthreads();
  mx = fmaxf(fmaxf(sred[0], sred[1]), fmaxf(sred[2], sred[3]));
  __syncthreads();
  float s = 0.f;
#pragma unroll
  for (int j = 0; j < 4; ++j) { v[j] = expf(v[j] - mx); s += v[j]; }
#pragma unroll
  for (int off = 1; off < 64; off <<= 1) s += __shfl_xor(s, off);
  if ((tid & 63) == 0) sred[wv] = s;
  __syncthreads();
  s = sred[0] + sred[1] + sred[2] + sred[3];
  const float inv = 1.f / s;
#pragma unroll
  for (int j = 0; j < 4; ++j) {
    const float sv = v[j] * inv;
    const size_t e = (size_t)row * NN + tid + j * 256;
    r[tid + j * 256] = sv;
    ushort_t hi, lo;
    split_bf16(sv, hi, lo);
    Sh[e] = hi;
    Sl[e] = lo;
  }
}

// ---------------------------------------------------------------------------
// S2 = 2*S@S - I, emitted directly as bf16 hi/lo split.
__global__ void cheb_kernel(const float* __restrict__ S, ushort_t* __restrict__ S2h,
                            ushort_t* __restrict__ S2l) {
  __shared__ float As[16][68];
  __shared__ float Bs[16][68];
  const int bm = blockIdx.y * 64, bn = blockIdx.x * 64;
  const int tid = threadIdx.x;
  const int tx = tid & 15, ty = tid >> 4;
  float acc[4][4] = {};
  for (int k0 = 0; k0 < NN; k0 += 16) {
#pragma unroll
    for (int r = 0; r < 4; ++r) {
      const int m = (tid >> 4) + r * 16, kk = tid & 15;
      As[kk][m] = S[(size_t)(bm + m) * NN + k0 + kk];
    }
#pragma unroll
    for (int r = 0; r < 4; ++r) {
      const int kk = (tid >> 6) + r * 4, c = tid & 63;
      Bs[kk][c] = S[(size_t)(k0 + kk) * NN + bn + c];
    }
    __syncthreads();
#pragma unroll
    for (int kk = 0; kk < 16; ++kk) {
      float a[4], b[4];
#pragma unroll
      for (int i = 0; i < 4; ++i) a[i] = As[kk][ty * 4 + i];
#pragma unroll
      for (int j = 0; j < 4; ++j) b[j] = Bs[kk][tx * 4 + j];
#pragma unroll
      for (int i = 0; i < 4; ++i)
#pragma unroll
        for (int j = 0; j < 4; ++j) acc[i][j] += a[i] * b[j];
    }
    __syncthreads();
  }
#pragma unroll
  for (int i = 0; i < 4; ++i) {
    const int row = bm + ty * 4 + i;
#pragma unroll
    for (int j = 0; j < 4; ++j) {
      const int col = bn + tx * 4 + j;
      const float val = 2.f * acc[i][j] - (row == col ? 1.f : 0.f);
      ushort_t hi, lo;
      split_bf16(val, hi, lo);
      S2h[(size_t)row * NN + col] = hi;
      S2l[(size_t)row * NN + col] = lo;
    }
  }
}

// ---------------------------------------------------------------------------
// Wt[no][k] = W[k][no], bf16 hi/lo, zero-padded to [NOP][KP].
__global__ void wt_kernel(const float* __restrict__ W, ushort_t* __restrict__ Wth,
                          ushort_t* __restrict__ Wtl, int KK, int NO, int KP, int NOP) {
  const int e = blockIdx.x * 256 + threadIdx.x;
  if (e >= NOP * KP) return;
  const int no = e / KP, k = e - no * KP;
  const float v = (no < NO && k < KK) ? W[(size_t)k * NO + no] : 0.f;
  ushort_t hi, lo;
  split_bf16(v, hi, lo);
  Wth[e] = hi;
  Wtl[e] = lo;
}

// ---------------------------------------------------------------------------
// prep: build cell input on the fly; write Ag (idx-major, bf16 hi/lo) and
// XT (j-major transpose, bf16 hi/lo). One block = 64 j x 64 nodes.
// MODE 0: enc build [x_t, h]; 1: enc cand [x_t, z*h];
//      2: dec build [go, yc, h]; 3: dec cand [go, yc, z*h].
template <int C, int KP, int MODE>
__global__ void prep_kernel(const float* __restrict__ src0, const float* __restrict__ src1,
                            const float* __restrict__ hst, const float* __restrict__ zr,
                            ushort_t* __restrict__ Agh, ushort_t* __restrict__ Agl,
                            ushort_t* __restrict__ XTh, ushort_t* __restrict__ XTl, int t) {
  __shared__ float tile[64][65];
  const int bj = blockIdx.x * 64, bn = blockIdx.y * 64;
  const int tid = threadIdx.x;
  const int jl = tid & 63, nq = tid >> 6;
  const int j = bj + jl;
  const int b = j / C, c = j - b * C;
#pragma unroll
  for (int r = 0; r < 16; ++r) {
    const int node = bn + nq + r * 4;
    const int idx = node * 64 + b;
    float v;
    if (MODE == 0) {
      v = (c == 0) ? src0[((size_t)b * T_ + t) * NN + node]
                   : hst[(size_t)idx * 64 + (c - 1)];
    } else if (MODE == 1) {
      v = (c == 0) ? src0[((size_t)b * T_ + t) * NN + node]
                   : zr[(size_t)idx * 128 + (c - 1)] * hst[(size_t)idx * 64 + (c - 1)];
    } else if (MODE == 2) {
      v = (c == 0) ? src0[idx]
        : (c == 1) ? src1[((size_t)b * HOR_ + t) * NN + node]
                   : hst[(size_t)idx * 96 + (c - 2)];
    } else {
      v = (c == 0) ? src0[idx]
        : (c == 1) ? src1[((size_t)b * HOR_ + t) * NN + node]
                   : zr[(size_t)idx * 192 + (c - 2)] * hst[(size_t)idx * 96 + (c - 2)];
    }
    tile[nq + r * 4][jl] = v;
    ushort_t hi, lo;
    split_bf16(v, hi, lo);
    Agh[(size_t)idx * KP + c] = hi;
    Agl[(size_t)idx * KP + c] = lo;
  }
  __syncthreads();
  const int nl = tid & 63, jq = tid >> 6;
#pragma unroll
  for (int r = 0; r < 16; ++r) {
    const int jj = bj + jq + r * 4;
    const float v = tile[nl][jq + r * 4];
    ushort_t hi, lo;
    split_bf16(v, hi, lo);
    XTh[(size_t)jj * NN + bn + nl] = hi;
    XTl[(size_t)jj * NN + bn + nl] = lo;
  }
}

// ---------------------------------------------------------------------------
// Graph conv, LDS-staged (single-buffer, round-6 body): 64 nodes x 128 j.
// gridDim.x padded to a multiple of 8 -> j-tile % 8 == XCD id, stable across
// bn rows (NJP % 8 == 0) -> each XCD's XT chunk stays L2-resident.
template <int C, int KP>
__global__ void graph_mfma_kernel(const ushort_t* __restrict__ S1h,
                                  const ushort_t* __restrict__ S1l,
                                  const ushort_t* __restrict__ S2h,
                                  const ushort_t* __restrict__ S2l,
                                  const ushort_t* __restrict__ XTh,
                                  const ushort_t* __restrict__ XTl,
                                  ushort_t* __restrict__ Agh, ushort_t* __restrict__ Agl) {
  constexpr int W = B_ * C;
  const int bj = blockIdx.x * 128;
  if (bj >= W) return;  // padding block (keeps NJP % 8 == 0)
  __shared__ __align__(16) ushort_t sA[4 * 64 * 32];   // 16 KB
  __shared__ __align__(16) ushort_t sB[2 * 128 * 32];  // 16 KB
  const int bn = blockIdx.y * 64;
  const int tid = threadIdx.x;
  const int w = tid >> 6, lane = tid & 63;
  const int row = lane & 15, kq = lane >> 4;

  const ushort_t* myA = (w == 0) ? S1h : (w == 1) ? S1l : (w == 2) ? S2h : S2l;
  const ushort_t* myB = (w < 2) ? XTh : XTl;
  const int bhalf = (w & 1) * 64;
  ushort_t* ldsA_w = sA + w * (64 * 32);
  ushort_t* ldsB_w = sB + (w < 2 ? 0 : 128 * 32) + bhalf * 32;
  const int srow = lane >> 2;
  const int scol = lane & 3;

  const int s = w >> 1;
  const int jhalf = (w & 1) * 64;
  const ushort_t* Ah_lds = sA + (2 * s) * (64 * 32);
  const ushort_t* Al_lds = sA + (2 * s + 1) * (64 * 32);
  const ushort_t* Bh_lds = sB;
  const ushort_t* Bl_lds = sB + 128 * 32;

  f32x4 acc[4][4] = {};
  for (int k0 = 0; k0 < NN; k0 += 32) {
#pragma unroll
    for (int i = 0; i < 4; ++i) {
      const ushort_t* g = myA + (size_t)(bn + i * 16 + srow) * NN + k0 + scol * 8;
      gload_lds16(g, ldsA_w + i * 16 * 32);
    }
#pragma unroll
    for (int i = 0; i < 4; ++i) {
      const ushort_t* g = myB + (size_t)(bj + bhalf + i * 16 + srow) * NN + k0 + scol * 8;
      gload_lds16(g, ldsB_w + i * 16 * 32);
    }
    __syncthreads();
    short8 ah[4], al[4];
#pragma unroll
    for (int mt = 0; mt < 4; ++mt) {
      ah[mt] = *(const short8*)(Ah_lds + (mt * 16 + row) * 32 + kq * 8);
      al[mt] = *(const short8*)(Al_lds + (mt * 16 + row) * 32 + kq * 8);
    }
#pragma unroll
    for (int nt = 0; nt < 4; ++nt) {
      const short8 bh = *(const short8*)(Bh_lds + (jhalf + nt * 16 + row) * 32 + kq * 8);
      const short8 bl = *(const short8*)(Bl_lds + (jhalf + nt * 16 + row) * 32 + kq * 8);
#pragma unroll
      for (int mt = 0; mt < 4; ++mt) {
        acc[mt][nt] = __builtin_amdgcn_mfma_f32_16x16x32_bf16(ah[mt], bh, acc[mt][nt], 0, 0, 0);
        acc[mt][nt] = __builtin_amdgcn_mfma_f32_16x16x32_bf16(ah[mt], bl, acc[mt][nt], 0, 0, 0);
        acc[mt][nt] = __builtin_amdgcn_mfma_f32_16x16x32_bf16(al[mt], bh, acc[mt][nt], 0, 0, 0);
      }
    }
    __syncthreads();
  }
  // D mapping: col (=j) = lane&15, row (=node) = (lane>>4)*4 + reg.
  const int slice_off = (s + 1) * C;
#pragma unroll
  for (int nt = 0; nt < 4; ++nt) {
    const int j = bj + jhalf + nt * 16 + row;
    if (j < W) {
      const int b = j / C, c = j - b * C;
      const size_t coloff = (size_t)(slice_off + c);
#pragma unroll
      for (int mt = 0; mt < 4; ++mt) {
        const int node0 = bn + mt * 16 + kq * 4;
#pragma unroll
        for (int r = 0; r < 4; ++r) {
          const size_t a = (size_t)((node0 + r) * 64 + b) * KP + coloff;
          ushort_t hi, lo;
          split_bf16(acc[mt][nt][r], hi, lo);
          Agh[a] = hi;
          Agl[a] = lo;
        }
      }
    }
  }
}

// ---------------------------------------------------------------------------
// Dense on MFMA (single-buffer, round-6 body): 128 rows x NO cols.
// MODE 0: sigmoid -> outp(zr, stride NO=2H). MODE 1: fused GRU combine.
template <int KP, int NO, int NOP, int MODE, int H>
__global__ void dense_mfma_kernel(const ushort_t* __restrict__ Agh,
                                  const ushort_t* __restrict__ Agl,
                                  const ushort_t* __restrict__ Wth,
                                  const ushort_t* __restrict__ Wtl,
                                  const float* __restrict__ bias,
                                  float* __restrict__ outp,
                                  const float* __restrict__ zrin) {
  constexpr int NFR = NO / 16;
  __shared__ __align__(16) ushort_t sAh[128 * 32];
  __shared__ __align__(16) ushort_t sAl[128 * 32];
  __shared__ __align__(16) ushort_t sBh[NOP * 32];
  __shared__ __align__(16) ushort_t sBl[NOP * 32];
  const int row0 = blockIdx.x * 128;
  const int tid = threadIdx.x;
  const int w = tid >> 6, lane = tid & 63;
  const int col16 = lane & 15, four = lane >> 4;
  const int srow = lane >> 2, scol = (lane & 3) * 8;
  f32x4 acc[2][NFR] = {};
  for (int k0 = 0; k0 < KP; k0 += 32) {
    for (int c = w; c < 8; c += 4) {
      const size_t g = (size_t)(row0 + c * 16 + srow) * KP + k0 + scol;
      gload_lds16(Agh + g, sAh + c * 512);
      gload_lds16(Agl + g, sAl + c * 512);
    }
    for (int c = w; c < NOP / 16; c += 4) {
      const size_t g = (size_t)(c * 16 + srow) * KP + k0 + scol;
      gload_lds16(Wth + g, sBh + c * 512);
      gload_lds16(Wtl + g, sBl + c * 512);
    }
    __syncthreads();
    short8 ah[2], al[2];
#pragma unroll
    for (int mt = 0; mt < 2; ++mt) {
      const int r = (w * 32 + mt * 16 + col16) * 32 + four * 8;
      ah[mt] = *(const short8*)(sAh + r);
      al[mt] = *(const short8*)(sAl + r);
    }
#pragma unroll
    for (int nt = 0; nt < NFR; ++nt) {
      const int r = (nt * 16 + col16) * 32 + four * 8;
      const short8 bh = *(const short8*)(sBh + r);
      const short8 bl = *(const short8*)(sBl + r);
#pragma unroll
      for (int mt = 0; mt < 2; ++mt) {
        acc[mt][nt] = __builtin_amdgcn_mfma_f32_16x16x32_bf16(ah[mt], bh, acc[mt][nt], 0, 0, 0);
        acc[mt][nt] = __builtin_amdgcn_mfma_f32_16x16x32_bf16(ah[mt], bl, acc[mt][nt], 0, 0, 0);
        acc[mt][nt] = __builtin_amdgcn_mfma_f32_16x16x32_bf16(al[mt], bh, acc[mt][nt], 0, 0, 0);
      }
    }
    __syncthreads();
  }
#pragma unroll
  for (int nt = 0; nt < NFR; ++nt) {
    const int col = nt * 16 + col16;
    const float bv = bias[col];
#pragma unroll
    for (int mt = 0; mt < 2; ++mt) {
      const int rbase = row0 + w * 32 + mt * 16 + four * 4;
#pragma unroll
      for (int r = 0; r < 4; ++r) {
        const int row = rbase + r;
        const float v = acc[mt][nt][r] + bv;
        if (MODE == 0) {
          outp[(size_t)row * NO + col] = 1.f / (1.f + expf(-v));
        } else {
          const float rg = zrin[(size_t)row * (2 * H) + H + col];
          const float hv = outp[(size_t)row * H + col];
          outp[(size_t)row * H + col] = rg * hv + (1.f - rg) * tanhf(v);
        }
      }
    }
  }
}

// ---------------------------------------------------------------------------
// attention + prototype + W_E + h0 build, fused. One thread per (n,b).
__global__ void attn_kernel(const float* __restrict__ h, const float* __restrict__ Wq,
                            const float* __restrict__ Mem, const float* __restrict__ FCE,
                            float* __restrict__ hB, float* __restrict__ WE) {
  __shared__ float sWq[64 * 32];
  __shared__ float sM[10 * 32];
  __shared__ float sF[32 * 8];
  const int tid = threadIdx.x;
  for (int i = tid; i < 64 * 32; i += 256) sWq[i] = Wq[i];
  for (int i = tid; i < 10 * 32; i += 256) sM[i] = Mem[i];
  for (int i = tid; i < 32 * 8; i += 256) sF[i] = FCE[i];
  __syncthreads();
  const int idx = blockIdx.x * 256 + tid;
  const float* hp = h + (size_t)idx * 64;
  float* hd = hB + (size_t)idx * 96;
  float q[32] = {};
  for (int i0 = 0; i0 < 16; ++i0) {
    const float4 h4 = *(const float4*)(hp + i0 * 4);
#pragma unroll
    for (int jj = 0; jj < 4; ++jj) {
      const float hv = ((const float*)&h4)[jj];
      hd[i0 * 4 + jj] = hv;  // h0 = [h, proto]
      const int i = i0 * 4 + jj;
#pragma unroll
      for (int c = 0; c < 32; ++c) q[c] += hv * sWq[i * 32 + c];
    }
  }
  float lg[10];
  float mx = -1e30f;
#pragma unroll
  for (int m = 0; m < 10; ++m) {
    float s = 0.f;
#pragma unroll
    for (int c = 0; c < 32; ++c) s += q[c] * sM[m * 32 + c];
    lg[m] = s;
    mx = fmaxf(mx, s);
  }
  float den = 0.f;
#pragma unroll
  for (int m = 0; m < 10; ++m) { lg[m] = expf(lg[m] - mx); den += lg[m]; }
  const float inv = 1.f / den;
  float p[32] = {};
#pragma unroll
  for (int m = 0; m < 10; ++m) {
    const float a = lg[m] * inv;
#pragma unroll
    for (int c = 0; c < 32; ++c) p[c] += a * sM[m * 32 + c];
  }
#pragma unroll
  for (int c = 0; c < 32; ++c) hd[64 + c] = p[c];
  float* wd = WE + (size_t)idx * 8;
#pragma unroll
  for (int e = 0; e < 8; ++e) {
    float s = 0.f;
#pragma unroll
    for (int c = 0; c < 32; ++c) s += p[c] * sF[c * 8 + e];
    wd[e] = s;
  }
}

__global__ void proj_kernel(const float* __restrict__ h, const float* __restrict__ pW,
                            const float* __restrict__ pb, float* __restrict__ go,
                            float* __restrict__ out, int t) {
  __shared__ float sW[96];
  if (threadIdx.x < 96) sW[threadIdx.x] = pW[threadIdx.x];
  __syncthreads();
  const int idx = blockIdx.x * 256 + threadIdx.x;
  const float* hp = h + (size_t)idx * 96;
  float acc = pb[0];
  for (int j0 = 0; j0 < 24; ++j0) {
    const float4 h4 = *(const float4*)(hp + j0 * 4);
    acc += h4.x * sW[j0 * 4] + h4.y * sW[j0 * 4 + 1] + h4.z * sW[j0 * 4 + 2] + h4.w * sW[j0 * 4 + 3];
  }
  go[idx] = acc;
  const int n = idx >> 6, b = idx & 63;
  out[((size_t)b * HOR_ + t) * NN + n] = acc;
}

// ---------------------------------------------------------------------------
extern "C" void kernel_launch(void* const* d_in, const int* in_sizes, int n_in,
                              void* d_out, int out_size, void* d_ws, size_t ws_size,
                              hipStream_t stream) {
  const float* x    = (const float*)d_in[0];
  const float* ycov = (const float*)d_in[1];
  const float* emb  = (const float*)d_in[2];
  const float* egW  = (const float*)d_in[3];
  const float* egb  = (const float*)d_in[4];
  const float* euW  = (const float*)d_in[5];
  const float* eub  = (const float*)d_in[6];
  const float* Mem  = (const float*)d_in[7];
  const float* Wq   = (const float*)d_in[8];
  const float* FCE  = (const float*)d_in[9];
  const float* dgW  = (const float*)d_in[10];
  const float* dgb  = (const float*)d_in[11];
  const float* duW  = (const float*)d_in[12];
  const float* dub  = (const float*)d_in[13];
  const float* pW   = (const float*)d_in[14];
  const float* pb   = (const float*)d_in[15];
  float* out = (float*)d_out;

  char* w = (char*)d_ws;
  auto alloc = [&](size_t bytes) {
    void* p = (void*)w;
    w += (bytes + 255) & ~(size_t)255;
    return p;
  };
  float* S1  = (float*)alloc((size_t)NN * NN * 4);
  float* zr  = (float*)alloc((size_t)NN * B_ * 192 * 4);
  float* hA  = (float*)alloc((size_t)NN * B_ * 64 * 4);
  float* hB  = (float*)alloc((size_t)NN * B_ * 96 * 4);
  float* go  = (float*)alloc((size_t)NN * B_ * 4);
  float* WE  = (float*)alloc((size_t)NN * B_ * 8 * 4);
  ushort_t* S1h = (ushort_t*)alloc((size_t)NN * NN * 2);
  ushort_t* S1l = (ushort_t*)alloc((size_t)NN * NN * 2);
  ushort_t* S2h = (ushort_t*)alloc((size_t)NN * NN * 2);
  ushort_t* S2l = (ushort_t*)alloc((size_t)NN * NN * 2);
  ushort_t* XTh = (ushort_t*)alloc((size_t)B_ * 98 * NN * 2);
  ushort_t* XTl = (ushort_t*)alloc((size_t)B_ * 98 * NN * 2);
  ushort_t* Agh = (ushort_t*)alloc((size_t)NN * B_ * 320 * 2);
  ushort_t* Agl = (ushort_t*)alloc((size_t)NN * B_ * 320 * 2);
  ushort_t* WtegH = (ushort_t*)alloc(128 * 224 * 2);
  ushort_t* WtegL = (ushort_t*)alloc(128 * 224 * 2);
  ushort_t* WteuH = (ushort_t*)alloc(64 * 224 * 2);
  ushort_t* WteuL = (ushort_t*)alloc(64 * 224 * 2);
  ushort_t* WtdgH = (ushort_t*)alloc(192 * 320 * 2);
  ushort_t* WtdgL = (ushort_t*)alloc(192 * 320 * 2);
  ushort_t* WtduH = (ushort_t*)alloc(128 * 320 * 2);
  ushort_t* WtduL = (ushort_t*)alloc(128 * 320 * 2);
  (void)ws_size; (void)in_sizes; (void)n_in; (void)out_size;

  const dim3 blk(256);

  // ---- weight transposes + buffer init (pad regions must be defined) ----
  wt_kernel<<<(128 * 224 + 255) / 256, blk, 0, stream>>>(egW, WtegH, WtegL, 195, 128, 224, 128);
  wt_kernel<<<(64 * 224 + 255) / 256, blk, 0, stream>>>(euW, WteuH, WteuL, 195, 64, 224, 64);
  wt_kernel<<<(192 * 320 + 255) / 256, blk, 0, stream>>>(dgW, WtdgH, WtdgL, 294, 192, 320, 192);
  wt_kernel<<<(128 * 320 + 255) / 256, blk, 0, stream>>>(duW, WtduH, WtduL, 294, 96, 320, 128);
  hipMemsetAsync(Agh, 0, (size_t)NN * B_ * 320 * 2, stream);
  hipMemsetAsync(Agl, 0, (size_t)NN * B_ * 320 * 2, stream);
  hipMemsetAsync(hA, 0, (size_t)NN * B_ * 64 * 4, stream);
  hipMemsetAsync(go, 0, (size_t)NN * B_ * 4, stream);

  // ---- encoder supports ----
  gemm_nt_kernel<<<dim3(16, 16), blk, 0, stream>>>(emb, emb, S1, NN, 8);
  relu_softmax_kernel<<<NN, blk, 0, stream>>>(S1, S1h, S1l);
  cheb_kernel<<<dim3(16, 16), blk, 0, stream>>>(S1, S2h, S2l);

  // ---- encoder scan ----  (W_enc = 4160; live j-tiles 33, padded to 40)
  for (int t = 0; t < T_; ++t) {
    prep_kernel<65, 224, 0><<<dim3(65, 16), blk, 0, stream>>>(x, nullptr, hA, nullptr, Agh, Agl, XTh, XTl, t);
    graph_mfma_kernel<65, 224><<<dim3(40, 16), blk, 0, stream>>>(S1h, S1l, S2h, S2l, XTh, XTl, Agh, Agl);
    dense_mfma_kernel<224, 128, 128, 0, 64><<<512, blk, 0, stream>>>(Agh, Agl, WtegH, WtegL, egb, zr, nullptr);
    prep_kernel<65, 224, 1><<<dim3(65, 16), blk, 0, stream>>>(x, nullptr, hA, zr, Agh, Agl, XTh, XTl, t);
    graph_mfma_kernel<65, 224><<<dim3(40, 16), blk, 0, stream>>>(S1h, S1l, S2h, S2l, XTh, XTl, Agh, Agl);
    dense_mfma_kernel<224, 64, 64, 1, 64><<<512, blk, 0, stream>>>(Agh, Agl, WteuH, WteuL, eub, hA, zr);
  }

  // ---- attention / memory / decoder supports ----
  attn_kernel<<<256, blk, 0, stream>>>(hA, Wq, Mem, FCE, hB, WE);
  gemm_nt_kernel<<<dim3(16, 16), blk, 0, stream>>>(WE, WE, S1, NN, 512);
  relu_softmax_kernel<<<NN, blk, 0, stream>>>(S1, S1h, S1l);
  cheb_kernel<<<dim3(16, 16), blk, 0, stream>>>(S1, S2h, S2l);

  // ---- decoder scan ----  (W_dec = 6272; live j-tiles 49, padded to 56)
  for (int t = 0; t < HOR_; ++t) {
    prep_kernel<98, 320, 2><<<dim3(98, 16), blk, 0, stream>>>(go, ycov, hB, nullptr, Agh, Agl, XTh, XTl, t);
    graph_mfma_kernel<98, 320><<<dim3(56, 16), blk, 0, stream>>>(S1h, S1l, S2h, S2l, XTh, XTl, Agh, Agl);
    dense_mfma_kernel<320, 192, 192, 0, 96><<<512, blk, 0, stream>>>(Agh, Agl, WtdgH, WtdgL, dgb, zr, nullptr);
    prep_kernel<98, 320, 3><<<dim3(98, 16), blk, 0, stream>>>(go, ycov, hB, zr, Agh, Agl, XTh, XTl, t);
    graph_mfma_kernel<98, 320><<<dim3(56, 16), blk, 0, stream>>>(S1h, S1l, S2h, S2l, XTh, XTl, Agh, Agl);
    dense_mfma_kernel<320, 96, 128, 1, 96><<<512, blk, 0, stream>>>(Agh, Agl, WtduH, WtduL, dub, hB, zr);
    proj_kernel<<<256, blk, 0, stream>>>(hB, pW, pb, go, out, t);
  }
}

// Round 9
// 6676.605 us; speedup vs baseline: 1.1943x; 1.0072x over previous
//
#include <hip/hip_runtime.h>
#include <hip/hip_bf16.h>

// MMGCRN: graph convs + dense layers on MFMA (bf16x3 split = fp32-class).
// + XCD-stable grid padding (r8) + T2 LDS XOR-swizzle (this round):
//   LDS slot kq' = kq ^ ((row>>1)&3), via pre-swizzled global source
//   (global_load_lds writes linearly) + swizzled ds_read.
// B=64, T=12, N=1024, HOR=12, RNN=64, DEC=96, K=3.
constexpr int B_ = 64, T_ = 12, NN = 1024, HOR_ = 12;

typedef __attribute__((ext_vector_type(8))) short short8;   // 8 bf16 (4 VGPRs)
typedef __attribute__((ext_vector_type(4))) float f32x4;    // MFMA C/D frag
typedef unsigned short ushort_t;

static __device__ inline ushort_t f2bh(float v) {
  __hip_bfloat16 h = __float2bfloat16(v);
  return *reinterpret_cast<ushort_t*>(&h);
}
static __device__ inline float bh2f(ushort_t u) {
  __hip_bfloat16 h = *reinterpret_cast<__hip_bfloat16*>(&u);
  return __bfloat162float(h);
}
static __device__ inline void split_bf16(float v, ushort_t& hi, ushort_t& lo) {
  hi = f2bh(v);
  lo = f2bh(v - bh2f(hi));
}

// async global->LDS, 16B per lane (LDS dest = wave-uniform base + lane*16).
static __device__ inline void gload_lds16(const ushort_t* g, ushort_t* l) {
  __builtin_amdgcn_global_load_lds(
      (const __attribute__((address_space(1))) unsigned int*)g,
      (__attribute__((address_space(3))) unsigned int*)l, 16, 0, 0);
}

// ---------------------------------------------------------------------------
// C = A (M x Kd) @ B (Ncol x Kd)^T, row-major, 64x64 tile, 4x4/thread. fp32.
__global__ void gemm_nt_kernel(const float* __restrict__ A, const float* __restrict__ Bm,
                               float* __restrict__ C, int Ncol, int Kd) {
  __shared__ float As[16][68];
  __shared__ float Bs[16][68];
  const int bm = blockIdx.y * 64, bn = blockIdx.x * 64;
  const int tid = threadIdx.x;
  const int tx = tid & 15, ty = tid >> 4;
  float acc[4][4] = {};
  for (int k0 = 0; k0 < Kd; k0 += 16) {
#pragma unroll
    for (int r = 0; r < 4; ++r) {
      const int m = (tid >> 4) + r * 16;
      const int kk = tid & 15;
      const int k = k0 + kk;
      As[kk][m] = (k < Kd) ? A[(size_t)(bm + m) * Kd + k] : 0.f;
      Bs[kk][m] = (k < Kd) ? Bm[(size_t)(bn + m) * Kd + k] : 0.f;
    }
    __syncthreads();
#pragma unroll
    for (int kk = 0; kk < 16; ++kk) {
      float a[4], b[4];
#pragma unroll
      for (int i = 0; i < 4; ++i) a[i] = As[kk][ty * 4 + i];
#pragma unroll
      for (int j = 0; j < 4; ++j) b[j] = Bs[kk][tx * 4 + j];
#pragma unroll
      for (int i = 0; i < 4; ++i)
#pragma unroll
        for (int j = 0; j < 4; ++j) acc[i][j] += a[i] * b[j];
    }
    __syncthreads();
  }
#pragma unroll
  for (int i = 0; i < 4; ++i)
#pragma unroll
    for (int j = 0; j < 4; ++j)
      C[(size_t)(bm + ty * 4 + i) * Ncol + bn + tx * 4 + j] = acc[i][j];
}

// ---------------------------------------------------------------------------
// In-place row softmax(relu(x)) over 1024 cols; also emits bf16 hi/lo split.
__global__ void relu_softmax_kernel(float* __restrict__ S, ushort_t* __restrict__ Sh,
                                    ushort_t* __restrict__ Sl) {
  const int row = blockIdx.x;
  float* r = S + (size_t)row * NN;
  const int tid = threadIdx.x;  // 256
  float v[4];
  float mx = 0.f;
#pragma unroll
  for (int j = 0; j < 4; ++j) {
    float xv = fmaxf(r[tid + j * 256], 0.f);
    v[j] = xv;
    mx = fmaxf(mx, xv);
  }
#pragma unroll
  for (int off = 1; off < 64; off <<= 1) mx = fmaxf(mx, __shfl_xor(mx, off));
  __shared__ float sred[4];
  const int wv = tid >> 6;
  if ((tid & 63) == 0) sred[wv] = mx;
  __syncthreads();
  mx = fmaxf(fmaxf(sred[0], sred[1]), fmaxf(sred[2], sred[3]));
  __syncthreads();
  float s = 0.f;
#pragma unroll
  for (int j = 0; j < 4; ++j) { v[j] = expf(v[j] - mx); s += v[j]; }
#pragma unroll
  for (int off = 1; off < 64; off <<= 1) s += __shfl_xor(s, off);
  if ((tid & 63) == 0) sred[wv] = s;
  __syncthreads();
  s = sred[0] + sred[1] + sred[2] + sred[3];
  const float inv = 1.f / s;
#pragma unroll
  for (int j = 0; j < 4; ++j) {
    const float sv = v[j] * inv;
    const size_t e = (size_t)row * NN + tid + j * 256;
    r[tid + j * 256] = sv;
    ushort_t hi, lo;
    split_bf16(sv, hi, lo);
    Sh[e] = hi;
    Sl[e] = lo;
  }
}

// ---------------------------------------------------------------------------
// S2 = 2*S@S - I, emitted directly as bf16 hi/lo split.
__global__ void cheb_kernel(const float* __restrict__ S, ushort_t* __restrict__ S2h,
                            ushort_t* __restrict__ S2l) {
  __shared__ float As[16][68];
  __shared__ float Bs[16][68];
  const int bm = blockIdx.y * 64, bn = blockIdx.x * 64;
  const int tid = threadIdx.x;
  const int tx = tid & 15, ty = tid >> 4;
  float acc[4][4] = {};
  for (int k0 = 0; k0 < NN; k0 += 16) {
#pragma unroll
    for (int r = 0; r < 4; ++r) {
      const int m = (tid >> 4) + r * 16, kk = tid & 15;
      As[kk][m] = S[(size_t)(bm + m) * NN + k0 + kk];
    }
#pragma unroll
    for (int r = 0; r < 4; ++r) {
      const int kk = (tid >> 6) + r * 4, c = tid & 63;
      Bs[kk][c] = S[(size_t)(k0 + kk) * NN + bn + c];
    }
    __syncthreads();
#pragma unroll
    for (int kk = 0; kk < 16; ++kk) {
      float a[4], b[4];
#pragma unroll
      for (int i = 0; i < 4; ++i) a[i] = As[kk][ty * 4 + i];
#pragma unroll
      for (int j = 0; j < 4; ++j) b[j] = Bs[kk][tx * 4 + j];
#pragma unroll
      for (int i = 0; i < 4; ++i)
#pragma unroll
        for (int j = 0; j < 4; ++j) acc[i][j] += a[i] * b[j];
    }
    __syncthreads();
  }
#pragma unroll
  for (int i = 0; i < 4; ++i) {
    const int row = bm + ty * 4 + i;
#pragma unroll
    for (int j = 0; j < 4; ++j) {
      const int col = bn + tx * 4 + j;
      const float val = 2.f * acc[i][j] - (row == col ? 1.f : 0.f);
      ushort_t hi, lo;
      split_bf16(val, hi, lo);
      S2h[(size_t)row * NN + col] = hi;
      S2l[(size_t)row * NN + col] = lo;
    }
  }
}

// ---------------------------------------------------------------------------
// Wt[no][k] = W[k][no], bf16 hi/lo, zero-padded to [NOP][KP].
__global__ void wt_kernel(const float* __restrict__ W, ushort_t* __restrict__ Wth,
                          ushort_t* __restrict__ Wtl, int KK, int NO, int KP, int NOP) {
  const int e = blockIdx.x * 256 + threadIdx.x;
  if (e >= NOP * KP) return;
  const int no = e / KP, k = e - no * KP;
  const float v = (no < NO && k < KK) ? W[(size_t)k * NO + no] : 0.f;
  ushort_t hi, lo;
  split_bf16(v, hi, lo);
  Wth[e] = hi;
  Wtl[e] = lo;
}

// ---------------------------------------------------------------------------
// prep: build cell input on the fly; write Ag (idx-major, bf16 hi/lo) and
// XT (j-major transpose, bf16 hi/lo). One block = 64 j x 64 nodes.
// MODE 0: enc build [x_t, h]; 1: enc cand [x_t, z*h];
//      2: dec build [go, yc, h]; 3: dec cand [go, yc, z*h].
template <int C, int KP, int MODE>
__global__ void prep_kernel(const float* __restrict__ src0, const float* __restrict__ src1,
                            const float* __restrict__ hst, const float* __restrict__ zr,
                            ushort_t* __restrict__ Agh, ushort_t* __restrict__ Agl,
                            ushort_t* __restrict__ XTh, ushort_t* __restrict__ XTl, int t) {
  __shared__ float tile[64][65];
  const int bj = blockIdx.x * 64, bn = blockIdx.y * 64;
  const int tid = threadIdx.x;
  const int jl = tid & 63, nq = tid >> 6;
  const int j = bj + jl;
  const int b = j / C, c = j - b * C;
#pragma unroll
  for (int r = 0; r < 16; ++r) {
    const int node = bn + nq + r * 4;
    const int idx = node * 64 + b;
    float v;
    if (MODE == 0) {
      v = (c == 0) ? src0[((size_t)b * T_ + t) * NN + node]
                   : hst[(size_t)idx * 64 + (c - 1)];
    } else if (MODE == 1) {
      v = (c == 0) ? src0[((size_t)b * T_ + t) * NN + node]
                   : zr[(size_t)idx * 128 + (c - 1)] * hst[(size_t)idx * 64 + (c - 1)];
    } else if (MODE == 2) {
      v = (c == 0) ? src0[idx]
        : (c == 1) ? src1[((size_t)b * HOR_ + t) * NN + node]
                   : hst[(size_t)idx * 96 + (c - 2)];
    } else {
      v = (c == 0) ? src0[idx]
        : (c == 1) ? src1[((size_t)b * HOR_ + t) * NN + node]
                   : zr[(size_t)idx * 192 + (c - 2)] * hst[(size_t)idx * 96 + (c - 2)];
    }
    tile[nq + r * 4][jl] = v;
    ushort_t hi, lo;
    split_bf16(v, hi, lo);
    Agh[(size_t)idx * KP + c] = hi;
    Agl[(size_t)idx * KP + c] = lo;
  }
  __syncthreads();
  const int nl = tid & 63, jq = tid >> 6;
#pragma unroll
  for (int r = 0; r < 16; ++r) {
    const int jj = bj + jq + r * 4;
    const float v = tile[nl][jq + r * 4];
    ushort_t hi, lo;
    split_bf16(v, hi, lo);
    XTh[(size_t)jj * NN + bn + nl] = hi;
    XTl[(size_t)jj * NN + bn + nl] = lo;
  }
}

// ---------------------------------------------------------------------------
// Graph conv, LDS-staged, T2-swizzled: 64 nodes x 128 j, both supports.
// LDS row = 64B (32 bf16); slot kq' = kq ^ ((row>>1)&3) -> 2-way (free).
template <int C, int KP>
__global__ void graph_mfma_kernel(const ushort_t* __restrict__ S1h,
                                  const ushort_t* __restrict__ S1l,
                                  const ushort_t* __restrict__ S2h,
                                  const ushort_t* __restrict__ S2l,
                                  const ushort_t* __restrict__ XTh,
                                  const ushort_t* __restrict__ XTl,
                                  ushort_t* __restrict__ Agh, ushort_t* __restrict__ Agl) {
  constexpr int W = B_ * C;
  const int bj = blockIdx.x * 128;
  if (bj >= W) return;  // padding block (keeps NJP % 8 == 0)
  __shared__ __align__(16) ushort_t sA[4 * 64 * 32];   // 16 KB
  __shared__ __align__(16) ushort_t sB[2 * 128 * 32];  // 16 KB
  const int bn = blockIdx.y * 64;
  const int tid = threadIdx.x;
  const int w = tid >> 6, lane = tid & 63;
  const int row = lane & 15, kq = lane >> 4;

  const ushort_t* myA = (w == 0) ? S1h : (w == 1) ? S1l : (w == 2) ? S2h : S2l;
  const ushort_t* myB = (w < 2) ? XTh : XTl;
  const int bhalf = (w & 1) * 64;
  ushort_t* ldsA_w = sA + w * (64 * 32);
  ushort_t* ldsB_w = sB + (w < 2 ? 0 : 128 * 32) + bhalf * 32;
  const int srow = lane >> 2;
  // pre-swizzled global slot: LDS slot (lane&3) receives global chunk scol_sw
  const int scol_sw = (lane & 3) ^ ((srow >> 1) & 3);

  const int s = w >> 1;
  const int jhalf = (w & 1) * 64;
  const ushort_t* Ah_lds = sA + (2 * s) * (64 * 32);
  const ushort_t* Al_lds = sA + (2 * s + 1) * (64 * 32);
  const ushort_t* Bh_lds = sB;
  const ushort_t* Bl_lds = sB + 128 * 32;

  // swizzled read slot for fragments (row = lane&15)
  const int kqs = (kq ^ ((row >> 1) & 3)) * 8;

  f32x4 acc[4][4] = {};
  for (int k0 = 0; k0 < NN; k0 += 32) {
#pragma unroll
    for (int i = 0; i < 4; ++i) {
      const ushort_t* g = myA + (size_t)(bn + i * 16 + srow) * NN + k0 + scol_sw * 8;
      gload_lds16(g, ldsA_w + i * 16 * 32);
    }
#pragma unroll
    for (int i = 0; i < 4; ++i) {
      const ushort_t* g = myB + (size_t)(bj + bhalf + i * 16 + srow) * NN + k0 + scol_sw * 8;
      gload_lds16(g, ldsB_w + i * 16 * 32);
    }
    __syncthreads();
    short8 ah[4], al[4];
#pragma unroll
    for (int mt = 0; mt < 4; ++mt) {
      ah[mt] = *(const short8*)(Ah_lds + (mt * 16 + row) * 32 + kqs);
      al[mt] = *(const short8*)(Al_lds + (mt * 16 + row) * 32 + kqs);
    }
#pragma unroll
    for (int nt = 0; nt < 4; ++nt) {
      const short8 bh = *(const short8*)(Bh_lds + (jhalf + nt * 16 + row) * 32 + kqs);
      const short8 bl = *(const short8*)(Bl_lds + (jhalf + nt * 16 + row) * 32 + kqs);
#pragma unroll
      for (int mt = 0; mt < 4; ++mt) {
        acc[mt][nt] = __builtin_amdgcn_mfma_f32_16x16x32_bf16(ah[mt], bh, acc[mt][nt], 0, 0, 0);
        acc[mt][nt] = __builtin_amdgcn_mfma_f32_16x16x32_bf16(ah[mt], bl, acc[mt][nt], 0, 0, 0);
        acc[mt][nt] = __builtin_amdgcn_mfma_f32_16x16x32_bf16(al[mt], bh, acc[mt][nt], 0, 0, 0);
      }
    }
    __syncthreads();
  }
  // D mapping: col (=j) = lane&15, row (=node) = (lane>>4)*4 + reg.
  const int slice_off = (s + 1) * C;
#pragma unroll
  for (int nt = 0; nt < 4; ++nt) {
    const int j = bj + jhalf + nt * 16 + row;
    if (j < W) {
      const int b = j / C, c = j - b * C;
      const size_t coloff = (size_t)(slice_off + c);
#pragma unroll
      for (int mt = 0; mt < 4; ++mt) {
        const int node0 = bn + mt * 16 + kq * 4;
#pragma unroll
        for (int r = 0; r < 4; ++r) {
          const size_t a = (size_t)((node0 + r) * 64 + b) * KP + coloff;
          ushort_t hi, lo;
          split_bf16(acc[mt][nt][r], hi, lo);
          Agh[a] = hi;
          Agl[a] = lo;
        }
      }
    }
  }
}

// ---------------------------------------------------------------------------
// Dense on MFMA, T2-swizzled: 128 rows x NO cols.
// MODE 0: sigmoid -> outp(zr, stride NO=2H). MODE 1: fused GRU combine.
template <int KP, int NO, int NOP, int MODE, int H>
__global__ void dense_mfma_kernel(const ushort_t* __restrict__ Agh,
                                  const ushort_t* __restrict__ Agl,
                                  const ushort_t* __restrict__ Wth,
                                  const ushort_t* __restrict__ Wtl,
                                  const float* __restrict__ bias,
                                  float* __restrict__ outp,
                                  const float* __restrict__ zrin) {
  constexpr int NFR = NO / 16;
  __shared__ __align__(16) ushort_t sAh[128 * 32];
  __shared__ __align__(16) ushort_t sAl[128 * 32];
  __shared__ __align__(16) ushort_t sBh[NOP * 32];
  __shared__ __align__(16) ushort_t sBl[NOP * 32];
  const int row0 = blockIdx.x * 128;
  const int tid = threadIdx.x;
  const int w = tid >> 6, lane = tid & 63;
  const int col16 = lane & 15, four = lane >> 4;
  const int srow = lane >> 2;
  const int scol = ((lane & 3) ^ ((srow >> 1) & 3)) * 8;  // pre-swizzled source
  const int kqs = (four ^ ((col16 >> 1) & 3)) * 8;        // swizzled read slot
  f32x4 acc[2][NFR] = {};
  for (int k0 = 0; k0 < KP; k0 += 32) {
    for (int c = w; c < 8; c += 4) {
      const size_t g = (size_t)(row0 + c * 16 + srow) * KP + k0 + scol;
      gload_lds16(Agh + g, sAh + c * 512);
      gload_lds16(Agl + g, sAl + c * 512);
    }
    for (int c = w; c < NOP / 16; c += 4) {
      const size_t g = (size_t)(c * 16 + srow) * KP + k0 + scol;
      gload_lds16(Wth + g, sBh + c * 512);
      gload_lds16(Wtl + g, sBl + c * 512);
    }
    __syncthreads();
    short8 ah[2], al[2];
#pragma unroll
    for (int mt = 0; mt < 2; ++mt) {
      const int r = (w * 32 + mt * 16 + col16) * 32 + kqs;
      ah[mt] = *(const short8*)(sAh + r);
      al[mt] = *(const short8*)(sAl + r);
    }
#pragma unroll
    for (int nt = 0; nt < NFR; ++nt) {
      const int r = (nt * 16 + col16) * 32 + kqs;
      const short8 bh = *(const short8*)(sBh + r);
      const short8 bl = *(const short8*)(sBl + r);
#pragma unroll
      for (int mt = 0; mt < 2; ++mt) {
        acc[mt][nt] = __builtin_amdgcn_mfma_f32_16x16x32_bf16(ah[mt], bh, acc[mt][nt], 0, 0, 0);
        acc[mt][nt] = __builtin_amdgcn_mfma_f32_16x16x32_bf16(ah[mt], bl, acc[mt][nt], 0, 0, 0);
        acc[mt][nt] = __builtin_amdgcn_mfma_f32_16x16x32_bf16(al[mt], bh, acc[mt][nt], 0, 0, 0);
      }
    }
    __syncthreads();
  }
#pragma unroll
  for (int nt = 0; nt < NFR; ++nt) {
    const int col = nt * 16 + col16;
    const float bv = bias[col];
#pragma unroll
    for (int mt = 0; mt < 2; ++mt) {
      const int rbase = row0 + w * 32 + mt * 16 + four * 4;
#pragma unroll
      for (int r = 0; r < 4; ++r) {
        const int row = rbase + r;
        const float v = acc[mt][nt][r] + bv;
        if (MODE == 0) {
          outp[(size_t)row * NO + col] = 1.f / (1.f + expf(-v));
        } else {
          const float rg = zrin[(size_t)row * (2 * H) + H + col];
          const float hv = outp[(size_t)row * H + col];
          outp[(size_t)row * H + col] = rg * hv + (1.f - rg) * tanhf(v);
        }
      }
    }
  }
}

// ---------------------------------------------------------------------------
// attention + prototype + W_E + h0 build, fused. One thread per (n,b).
__global__ void attn_kernel(const float* __restrict__ h, const float* __restrict__ Wq,
                            const float* __restrict__ Mem, const float* __restrict__ FCE,
                            float* __restrict__ hB, float* __restrict__ WE) {
  __shared__ float sWq[64 * 32];
  __shared__ float sM[10 * 32];
  __shared__ float sF[32 * 8];
  const int tid = threadIdx.x;
  for (int i = tid; i < 64 * 32; i += 256) sWq[i] = Wq[i];
  for (int i = tid; i < 10 * 32; i += 256) sM[i] = Mem[i];
  for (int i = tid; i < 32 * 8; i += 256) sF[i] = FCE[i];
  __syncthreads();
  const int idx = blockIdx.x * 256 + tid;
  const float* hp = h + (size_t)idx * 64;
  float* hd = hB + (size_t)idx * 96;
  float q[32] = {};
  for (int i0 = 0; i0 < 16; ++i0) {
    const float4 h4 = *(const float4*)(hp + i0 * 4);
#pragma unroll
    for (int jj = 0; jj < 4; ++jj) {
      const float hv = ((const float*)&h4)[jj];
      hd[i0 * 4 + jj] = hv;  // h0 = [h, proto]
      const int i = i0 * 4 + jj;
#pragma unroll
      for (int c = 0; c < 32; ++c) q[c] += hv * sWq[i * 32 + c];
    }
  }
  float lg[10];
  float mx = -1e30f;
#pragma unroll
  for (int m = 0; m < 10; ++m) {
    float s = 0.f;
#pragma unroll
    for (int c = 0; c < 32; ++c) s += q[c] * sM[m * 32 + c];
    lg[m] = s;
    mx = fmaxf(mx, s);
  }
  float den = 0.f;
#pragma unroll
  for (int m = 0; m < 10; ++m) { lg[m] = expf(lg[m] - mx); den += lg[m]; }
  const float inv = 1.f / den;
  float p[32] = {};
#pragma unroll
  for (int m = 0; m < 10; ++m) {
    const float a = lg[m] * inv;
#pragma unroll
    for (int c = 0; c < 32; ++c) p[c] += a * sM[m * 32 + c];
  }
#pragma unroll
  for (int c = 0; c < 32; ++c) hd[64 + c] = p[c];
  float* wd = WE + (size_t)idx * 8;
#pragma unroll
  for (int e = 0; e < 8; ++e) {
    float s = 0.f;
#pragma unroll
    for (int c = 0; c < 32; ++c) s += p[c] * sF[c * 8 + e];
    wd[e] = s;
  }
}

__global__ void proj_kernel(const float* __restrict__ h, const float* __restrict__ pW,
                            const float* __restrict__ pb, float* __restrict__ go,
                            float* __restrict__ out, int t) {
  __shared__ float sW[96];
  if (threadIdx.x < 96) sW[threadIdx.x] = pW[threadIdx.x];
  __syncthreads();
  const int idx = blockIdx.x * 256 + threadIdx.x;
  const float* hp = h + (size_t)idx * 96;
  float acc = pb[0];
  for (int j0 = 0; j0 < 24; ++j0) {
    const float4 h4 = *(const float4*)(hp + j0 * 4);
    acc += h4.x * sW[j0 * 4] + h4.y * sW[j0 * 4 + 1] + h4.z * sW[j0 * 4 + 2] + h4.w * sW[j0 * 4 + 3];
  }
  go[idx] = acc;
  const int n = idx >> 6, b = idx & 63;
  out[((size_t)b * HOR_ + t) * NN + n] = acc;
}

// ---------------------------------------------------------------------------
extern "C" void kernel_launch(void* const* d_in, const int* in_sizes, int n_in,
                              void* d_out, int out_size, void* d_ws, size_t ws_size,
                              hipStream_t stream) {
  const float* x    = (const float*)d_in[0];
  const float* ycov = (const float*)d_in[1];
  const float* emb  = (const float*)d_in[2];
  const float* egW  = (const float*)d_in[3];
  const float* egb  = (const float*)d_in[4];
  const float* euW  = (const float*)d_in[5];
  const float* eub  = (const float*)d_in[6];
  const float* Mem  = (const float*)d_in[7];
  const float* Wq   = (const float*)d_in[8];
  const float* FCE  = (const float*)d_in[9];
  const float* dgW  = (const float*)d_in[10];
  const float* dgb  = (const float*)d_in[11];
  const float* duW  = (const float*)d_in[12];
  const float* dub  = (const float*)d_in[13];
  const float* pW   = (const float*)d_in[14];
  const float* pb   = (const float*)d_in[15];
  float* out = (float*)d_out;

  char* w = (char*)d_ws;
  auto alloc = [&](size_t bytes) {
    void* p = (void*)w;
    w += (bytes + 255) & ~(size_t)255;
    return p;
  };
  float* S1  = (float*)alloc((size_t)NN * NN * 4);
  float* zr  = (float*)alloc((size_t)NN * B_ * 192 * 4);
  float* hA  = (float*)alloc((size_t)NN * B_ * 64 * 4);
  float* hB  = (float*)alloc((size_t)NN * B_ * 96 * 4);
  float* go  = (float*)alloc((size_t)NN * B_ * 4);
  float* WE  = (float*)alloc((size_t)NN * B_ * 8 * 4);
  ushort_t* S1h = (ushort_t*)alloc((size_t)NN * NN * 2);
  ushort_t* S1l = (ushort_t*)alloc((size_t)NN * NN * 2);
  ushort_t* S2h = (ushort_t*)alloc((size_t)NN * NN * 2);
  ushort_t* S2l = (ushort_t*)alloc((size_t)NN * NN * 2);
  ushort_t* XTh = (ushort_t*)alloc((size_t)B_ * 98 * NN * 2);
  ushort_t* XTl = (ushort_t*)alloc((size_t)B_ * 98 * NN * 2);
  ushort_t* Agh = (ushort_t*)alloc((size_t)NN * B_ * 320 * 2);
  ushort_t* Agl = (ushort_t*)alloc((size_t)NN * B_ * 320 * 2);
  ushort_t* WtegH = (ushort_t*)alloc(128 * 224 * 2);
  ushort_t* WtegL = (ushort_t*)alloc(128 * 224 * 2);
  ushort_t* WteuH = (ushort_t*)alloc(64 * 224 * 2);
  ushort_t* WteuL = (ushort_t*)alloc(64 * 224 * 2);
  ushort_t* WtdgH = (ushort_t*)alloc(192 * 320 * 2);
  ushort_t* WtdgL = (ushort_t*)alloc(192 * 320 * 2);
  ushort_t* WtduH = (ushort_t*)alloc(128 * 320 * 2);
  ushort_t* WtduL = (ushort_t*)alloc(128 * 320 * 2);
  (void)ws_size; (void)in_sizes; (void)n_in; (void)out_size;

  const dim3 blk(256);

  // ---- weight transposes + buffer init (pad regions must be defined) ----
  wt_kernel<<<(128 * 224 + 255) / 256, blk, 0, stream>>>(egW, WtegH, WtegL, 195, 128, 224, 128);
  wt_kernel<<<(64 * 224 + 255) / 256, blk, 0, stream>>>(euW, WteuH, WteuL, 195, 64, 224, 64);
  wt_kernel<<<(192 * 320 + 255) / 256, blk, 0, stream>>>(dgW, WtdgH, WtdgL, 294, 192, 320, 192);
  wt_kernel<<<(128 * 320 + 255) / 256, blk, 0, stream>>>(duW, WtduH, WtduL, 294, 96, 320, 128);
  hipMemsetAsync(Agh, 0, (size_t)NN * B_ * 320 * 2, stream);
  hipMemsetAsync(Agl, 0, (size_t)NN * B_ * 320 * 2, stream);
  hipMemsetAsync(hA, 0, (size_t)NN * B_ * 64 * 4, stream);
  hipMemsetAsync(go, 0, (size_t)NN * B_ * 4, stream);

  // ---- encoder supports ----
  gemm_nt_kernel<<<dim3(16, 16), blk, 0, stream>>>(emb, emb, S1, NN, 8);
  relu_softmax_kernel<<<NN, blk, 0, stream>>>(S1, S1h, S1l);
  cheb_kernel<<<dim3(16, 16), blk, 0, stream>>>(S1, S2h, S2l);

  // ---- encoder scan ----  (W_enc = 4160; live j-tiles 33, padded to 40)
  for (int t = 0; t < T_; ++t) {
    prep_kernel<65, 224, 0><<<dim3(65, 16), blk, 0, stream>>>(x, nullptr, hA, nullptr, Agh, Agl, XTh, XTl, t);
    graph_mfma_kernel<65, 224><<<dim3(40, 16), blk, 0, stream>>>(S1h, S1l, S2h, S2l, XTh, XTl, Agh, Agl);
    dense_mfma_kernel<224, 128, 128, 0, 64><<<512, blk, 0, stream>>>(Agh, Agl, WtegH, WtegL, egb, zr, nullptr);
    prep_kernel<65, 224, 1><<<dim3(65, 16), blk, 0, stream>>>(x, nullptr, hA, zr, Agh, Agl, XTh, XTl, t);
    graph_mfma_kernel<65, 224><<<dim3(40, 16), blk, 0, stream>>>(S1h, S1l, S2h, S2l, XTh, XTl, Agh, Agl);
    dense_mfma_kernel<224, 64, 64, 1, 64><<<512, blk, 0, stream>>>(Agh, Agl, WteuH, WteuL, eub, hA, zr);
  }

  // ---- attention / memory / decoder supports ----
  attn_kernel<<<256, blk, 0, stream>>>(hA, Wq, Mem, FCE, hB, WE);
  gemm_nt_kernel<<<dim3(16, 16), blk, 0, stream>>>(WE, WE, S1, NN, 512);
  relu_softmax_kernel<<<NN, blk, 0, stream>>>(S1, S1h, S1l);
  cheb_kernel<<<dim3(16, 16), blk, 0, stream>>>(S1, S2h, S2l);

  // ---- decoder scan ----  (W_dec = 6272; live j-tiles 49, padded to 56)
  for (int t = 0; t < HOR_; ++t) {
    prep_kernel<98, 320, 2><<<dim3(98, 16), blk, 0, stream>>>(go, ycov, hB, nullptr, Agh, Agl, XTh, XTl, t);
    graph_mfma_kernel<98, 320><<<dim3(56, 16), blk, 0, stream>>>(S1h, S1l, S2h, S2l, XTh, XTl, Agh, Agl);
    dense_mfma_kernel<320, 192, 192, 0, 96><<<512, blk, 0, stream>>>(Agh, Agl, WtdgH, WtdgL, dgb, zr, nullptr);
    prep_kernel<98, 320, 3><<<dim3(98, 16), blk, 0, stream>>>(go, ycov, hB, zr, Agh, Agl, XTh, XTl, t);
    graph_mfma_kernel<98, 320><<<dim3(56, 16), blk, 0, stream>>>(S1h, S1l, S2h, S2l, XTh, XTl, Agh, Agl);
    dense_mfma_kernel<320, 96, 128, 1, 96><<<512, blk, 0, stream>>>(Agh, Agl, WtduH, WtduL, dub, hB, zr);
    proj_kernel<<<256, blk, 0, stream>>>(hB, pW, pb, go, out, t);
  }
}

// Round 10
// 6639.262 us; speedup vs baseline: 1.2010x; 1.0056x over previous
//
#include <hip/hip_runtime.h>
#include <hip/hip_bf16.h>

// MMGCRN: graph convs + dense layers on MFMA.
// Graph: A-side (S) bf16 hi+lo, B-side (X) plain bf16 -> 2 MFMAs/pair.
// Dense: full bf16x3. + XCD-stable grid padding (r8) + T2 swizzle (r9, free).
// B=64, T=12, N=1024, HOR=12, RNN=64, DEC=96, K=3.
constexpr int B_ = 64, T_ = 12, NN = 1024, HOR_ = 12;

typedef __attribute__((ext_vector_type(8))) short short8;   // 8 bf16 (4 VGPRs)
typedef __attribute__((ext_vector_type(4))) float f32x4;    // MFMA C/D frag
typedef unsigned short ushort_t;

static __device__ inline ushort_t f2bh(float v) {
  __hip_bfloat16 h = __float2bfloat16(v);
  return *reinterpret_cast<ushort_t*>(&h);
}
static __device__ inline float bh2f(ushort_t u) {
  __hip_bfloat16 h = *reinterpret_cast<__hip_bfloat16*>(&u);
  return __bfloat162float(h);
}
static __device__ inline void split_bf16(float v, ushort_t& hi, ushort_t& lo) {
  hi = f2bh(v);
  lo = f2bh(v - bh2f(hi));
}

// async global->LDS, 16B per lane (LDS dest = wave-uniform base + lane*16).
static __device__ inline void gload_lds16(const ushort_t* g, ushort_t* l) {
  __builtin_amdgcn_global_load_lds(
      (const __attribute__((address_space(1))) unsigned int*)g,
      (__attribute__((address_space(3))) unsigned int*)l, 16, 0, 0);
}

// ---------------------------------------------------------------------------
// C = A (M x Kd) @ B (Ncol x Kd)^T, row-major, 64x64 tile, 4x4/thread. fp32.
__global__ void gemm_nt_kernel(const float* __restrict__ A, const float* __restrict__ Bm,
                               float* __restrict__ C, int Ncol, int Kd) {
  __shared__ float As[16][68];
  __shared__ float Bs[16][68];
  const int bm = blockIdx.y * 64, bn = blockIdx.x * 64;
  const int tid = threadIdx.x;
  const int tx = tid & 15, ty = tid >> 4;
  float acc[4][4] = {};
  for (int k0 = 0; k0 < Kd; k0 += 16) {
#pragma unroll
    for (int r = 0; r < 4; ++r) {
      const int m = (tid >> 4) + r * 16;
      const int kk = tid & 15;
      const int k = k0 + kk;
      As[kk][m] = (k < Kd) ? A[(size_t)(bm + m) * Kd + k] : 0.f;
      Bs[kk][m] = (k < Kd) ? Bm[(size_t)(bn + m) * Kd + k] : 0.f;
    }
    __syncthreads();
#pragma unroll
    for (int kk = 0; kk < 16; ++kk) {
      float a[4], b[4];
#pragma unroll
      for (int i = 0; i < 4; ++i) a[i] = As[kk][ty * 4 + i];
#pragma unroll
      for (int j = 0; j < 4; ++j) b[j] = Bs[kk][tx * 4 + j];
#pragma unroll
      for (int i = 0; i < 4; ++i)
#pragma unroll
        for (int j = 0; j < 4; ++j) acc[i][j] += a[i] * b[j];
    }
    __syncthreads();
  }
#pragma unroll
  for (int i = 0; i < 4; ++i)
#pragma unroll
    for (int j = 0; j < 4; ++j)
      C[(size_t)(bm + ty * 4 + i) * Ncol + bn + tx * 4 + j] = acc[i][j];
}

// ---------------------------------------------------------------------------
// In-place row softmax(relu(x)) over 1024 cols; also emits bf16 hi/lo split.
__global__ void relu_softmax_kernel(float* __restrict__ S, ushort_t* __restrict__ Sh,
                                    ushort_t* __restrict__ Sl) {
  const int row = blockIdx.x;
  float* r = S + (size_t)row * NN;
  const int tid = threadIdx.x;  // 256
  float v[4];
  float mx = 0.f;
#pragma unroll
  for (int j = 0; j < 4; ++j) {
    float xv = fmaxf(r[tid + j * 256], 0.f);
    v[j] = xv;
    mx = fmaxf(mx, xv);
  }
#pragma unroll
  for (int off = 1; off < 64; off <<= 1) mx = fmaxf(mx, __shfl_xor(mx, off));
  __shared__ float sred[4];
  const int wv = tid >> 6;
  if ((tid & 63) == 0) sred[wv] = mx;
  __syncthreads();
  mx = fmaxf(fmaxf(sred[0], sred[1]), fmaxf(sred[2], sred[3]));
  __syncthreads();
  float s = 0.f;
#pragma unroll
  for (int j = 0; j < 4; ++j) { v[j] = expf(v[j] - mx); s += v[j]; }
#pragma unroll
  for (int off = 1; off < 64; off <<= 1) s += __shfl_xor(s, off);
  if ((tid & 63) == 0) sred[wv] = s;
  __syncthreads();
  s = sred[0] + sred[1] + sred[2] + sred[3];
  const float inv = 1.f / s;
#pragma unroll
  for (int j = 0; j < 4; ++j) {
    const float sv = v[j] * inv;
    const size_t e = (size_t)row * NN + tid + j * 256;
    r[tid + j * 256] = sv;
    ushort_t hi, lo;
    split_bf16(sv, hi, lo);
    Sh[e] = hi;
    Sl[e] = lo;
  }
}

// ---------------------------------------------------------------------------
// S2 = 2*S@S - I, emitted directly as bf16 hi/lo split.
__global__ void cheb_kernel(const float* __restrict__ S, ushort_t* __restrict__ S2h,
                            ushort_t* __restrict__ S2l) {
  __shared__ float As[16][68];
  __shared__ float Bs[16][68];
  const int bm = blockIdx.y * 64, bn = blockIdx.x * 64;
  const int tid = threadIdx.x;
  const int tx = tid & 15, ty = tid >> 4;
  float acc[4][4] = {};
  for (int k0 = 0; k0 < NN; k0 += 16) {
#pragma unroll
    for (int r = 0; r < 4; ++r) {
      const int m = (tid >> 4) + r * 16, kk = tid & 15;
      As[kk][m] = S[(size_t)(bm + m) * NN + k0 + kk];
    }
#pragma unroll
    for (int r = 0; r < 4; ++r) {
      const int kk = (tid >> 6) + r * 4, c = tid & 63;
      Bs[kk][c] = S[(size_t)(k0 + kk) * NN + bn + c];
    }
    __syncthreads();
#pragma unroll
    for (int kk = 0; kk < 16; ++kk) {
      float a[4], b[4];
#pragma unroll
      for (int i = 0; i < 4; ++i) a[i] = As[kk][ty * 4 + i];
#pragma unroll
      for (int j = 0; j < 4; ++j) b[j] = Bs[kk][tx * 4 + j];
#pragma unroll
      for (int i = 0; i < 4; ++i)
#pragma unroll
        for (int j = 0; j < 4; ++j) acc[i][j] += a[i] * b[j];
    }
    __syncthreads();
  }
#pragma unroll
  for (int i = 0; i < 4; ++i) {
    const int row = bm + ty * 4 + i;
#pragma unroll
    for (int j = 0; j < 4; ++j) {
      const int col = bn + tx * 4 + j;
      const float val = 2.f * acc[i][j] - (row == col ? 1.f : 0.f);
      ushort_t hi, lo;
      split_bf16(val, hi, lo);
      S2h[(size_t)row * NN + col] = hi;
      S2l[(size_t)row * NN + col] = lo;
    }
  }
}

// ---------------------------------------------------------------------------
// Wt[no][k] = W[k][no], bf16 hi/lo, zero-padded to [NOP][KP].
__global__ void wt_kernel(const float* __restrict__ W, ushort_t* __restrict__ Wth,
                          ushort_t* __restrict__ Wtl, int KK, int NO, int KP, int NOP) {
  const int e = blockIdx.x * 256 + threadIdx.x;
  if (e >= NOP * KP) return;
  const int no = e / KP, k = e - no * KP;
  const float v = (no < NO && k < KK) ? W[(size_t)k * NO + no] : 0.f;
  ushort_t hi, lo;
  split_bf16(v, hi, lo);
  Wth[e] = hi;
  Wtl[e] = lo;
}

// ---------------------------------------------------------------------------
// prep: build cell input on the fly; write Ag (idx-major, bf16 hi/lo, for
// dense) and XT (j-major transpose, plain bf16, for graph B-operand).
// MODE 0: enc build [x_t, h]; 1: enc cand [x_t, z*h];
//      2: dec build [go, yc, h]; 3: dec cand [go, yc, z*h].
template <int C, int KP, int MODE>
__global__ void prep_kernel(const float* __restrict__ src0, const float* __restrict__ src1,
                            const float* __restrict__ hst, const float* __restrict__ zr,
                            ushort_t* __restrict__ Agh, ushort_t* __restrict__ Agl,
                            ushort_t* __restrict__ XTh, int t) {
  __shared__ float tile[64][65];
  const int bj = blockIdx.x * 64, bn = blockIdx.y * 64;
  const int tid = threadIdx.x;
  const int jl = tid & 63, nq = tid >> 6;
  const int j = bj + jl;
  const int b = j / C, c = j - b * C;
#pragma unroll
  for (int r = 0; r < 16; ++r) {
    const int node = bn + nq + r * 4;
    const int idx = node * 64 + b;
    float v;
    if (MODE == 0) {
      v = (c == 0) ? src0[((size_t)b * T_ + t) * NN + node]
                   : hst[(size_t)idx * 64 + (c - 1)];
    } else if (MODE == 1) {
      v = (c == 0) ? src0[((size_t)b * T_ + t) * NN + node]
                   : zr[(size_t)idx * 128 + (c - 1)] * hst[(size_t)idx * 64 + (c - 1)];
    } else if (MODE == 2) {
      v = (c == 0) ? src0[idx]
        : (c == 1) ? src1[((size_t)b * HOR_ + t) * NN + node]
                   : hst[(size_t)idx * 96 + (c - 2)];
    } else {
      v = (c == 0) ? src0[idx]
        : (c == 1) ? src1[((size_t)b * HOR_ + t) * NN + node]
                   : zr[(size_t)idx * 192 + (c - 2)] * hst[(size_t)idx * 96 + (c - 2)];
    }
    tile[nq + r * 4][jl] = v;
    ushort_t hi, lo;
    split_bf16(v, hi, lo);
    Agh[(size_t)idx * KP + c] = hi;
    Agl[(size_t)idx * KP + c] = lo;
  }
  __syncthreads();
  const int nl = tid & 63, jq = tid >> 6;
#pragma unroll
  for (int r = 0; r < 16; ++r) {
    const int jj = bj + jq + r * 4;
    XTh[(size_t)jj * NN + bn + nl] = f2bh(tile[nl][jq + r * 4]);
  }
}

// ---------------------------------------------------------------------------
// Graph conv, LDS-staged, T2-swizzled: 64 nodes x 128 j, both supports.
// A = S hi+lo (4 planes), B = X plain bf16 -> 2 MFMAs per (mt,nt).
template <int C, int KP>
__global__ void graph_mfma_kernel(const ushort_t* __restrict__ S1h,
                                  const ushort_t* __restrict__ S1l,
                                  const ushort_t* __restrict__ S2h,
                                  const ushort_t* __restrict__ S2l,
                                  const ushort_t* __restrict__ XTh,
                                  ushort_t* __restrict__ Agh, ushort_t* __restrict__ Agl) {
  constexpr int W = B_ * C;
  const int bj = blockIdx.x * 128;
  if (bj >= W) return;  // padding block (keeps NJP % 8 == 0)
  __shared__ __align__(16) ushort_t sA[4 * 64 * 32];   // 16 KB
  __shared__ __align__(16) ushort_t sB[128 * 32];      // 8 KB
  const int bn = blockIdx.y * 64;
  const int tid = threadIdx.x;
  const int w = tid >> 6, lane = tid & 63;
  const int row = lane & 15, kq = lane >> 4;

  const ushort_t* myA = (w == 0) ? S1h : (w == 1) ? S1l : (w == 2) ? S2h : S2l;
  ushort_t* ldsA_w = sA + w * (64 * 32);
  const int srow = lane >> 2;
  // pre-swizzled global slot: LDS slot (lane&3) receives global chunk scol_sw
  const int scol_sw = (lane & 3) ^ ((srow >> 1) & 3);

  const int s = w >> 1;
  const int jhalf = (w & 1) * 64;
  const ushort_t* Ah_lds = sA + (2 * s) * (64 * 32);
  const ushort_t* Al_lds = sA + (2 * s + 1) * (64 * 32);

  // swizzled read slot for fragments (row = lane&15)
  const int kqs = (kq ^ ((row >> 1) & 3)) * 8;

  f32x4 acc[4][4] = {};
  for (int k0 = 0; k0 < NN; k0 += 32) {
#pragma unroll
    for (int i = 0; i < 4; ++i) {
      const ushort_t* g = myA + (size_t)(bn + i * 16 + srow) * NN + k0 + scol_sw * 8;
      gload_lds16(g, ldsA_w + i * 16 * 32);
    }
    // B: 8 16-row chunks of XTh; wave w stages chunks w and w+4.
#pragma unroll
    for (int i = 0; i < 2; ++i) {
      const int cb = w + i * 4;
      const ushort_t* g = XTh + (size_t)(bj + cb * 16 + srow) * NN + k0 + scol_sw * 8;
      gload_lds16(g, sB + cb * 16 * 32);
    }
    __syncthreads();
    short8 ah[4], al[4];
#pragma unroll
    for (int mt = 0; mt < 4; ++mt) {
      ah[mt] = *(const short8*)(Ah_lds + (mt * 16 + row) * 32 + kqs);
      al[mt] = *(const short8*)(Al_lds + (mt * 16 + row) * 32 + kqs);
    }
#pragma unroll
    for (int nt = 0; nt < 4; ++nt) {
      const short8 bh = *(const short8*)(sB + (jhalf + nt * 16 + row) * 32 + kqs);
#pragma unroll
      for (int mt = 0; mt < 4; ++mt) {
        acc[mt][nt] = __builtin_amdgcn_mfma_f32_16x16x32_bf16(ah[mt], bh, acc[mt][nt], 0, 0, 0);
        acc[mt][nt] = __builtin_amdgcn_mfma_f32_16x16x32_bf16(al[mt], bh, acc[mt][nt], 0, 0, 0);
      }
    }
    __syncthreads();
  }
  // D mapping: col (=j) = lane&15, row (=node) = (lane>>4)*4 + reg.
  const int slice_off = (s + 1) * C;
#pragma unroll
  for (int nt = 0; nt < 4; ++nt) {
    const int j = bj + jhalf + nt * 16 + row;
    if (j < W) {
      const int b = j / C, c = j - b * C;
      const size_t coloff = (size_t)(slice_off + c);
#pragma unroll
      for (int mt = 0; mt < 4; ++mt) {
        const int node0 = bn + mt * 16 + kq * 4;
#pragma unroll
        for (int r = 0; r < 4; ++r) {
          const size_t a = (size_t)((node0 + r) * 64 + b) * KP + coloff;
          ushort_t hi, lo;
          split_bf16(acc[mt][nt][r], hi, lo);
          Agh[a] = hi;
          Agl[a] = lo;
        }
      }
    }
  }
}

// ---------------------------------------------------------------------------
// Dense on MFMA, T2-swizzled, bf16x3: 128 rows x NO cols.
// MODE 0: sigmoid -> outp(zr, stride NO=2H). MODE 1: fused GRU combine.
template <int KP, int NO, int NOP, int MODE, int H>
__global__ void dense_mfma_kernel(const ushort_t* __restrict__ Agh,
                                  const ushort_t* __restrict__ Agl,
                                  const ushort_t* __restrict__ Wth,
                                  const ushort_t* __restrict__ Wtl,
                                  const float* __restrict__ bias,
                                  float* __restrict__ outp,
                                  const float* __restrict__ zrin) {
  constexpr int NFR = NO / 16;
  __shared__ __align__(16) ushort_t sAh[128 * 32];
  __shared__ __align__(16) ushort_t sAl[128 * 32];
  __shared__ __align__(16) ushort_t sBh[NOP * 32];
  __shared__ __align__(16) ushort_t sBl[NOP * 32];
  const int row0 = blockIdx.x * 128;
  const int tid = threadIdx.x;
  const int w = tid >> 6, lane = tid & 63;
  const int col16 = lane & 15, four = lane >> 4;
  const int srow = lane >> 2;
  const int scol = ((lane & 3) ^ ((srow >> 1) & 3)) * 8;  // pre-swizzled source
  const int kqs = (four ^ ((col16 >> 1) & 3)) * 8;        // swizzled read slot
  f32x4 acc[2][NFR] = {};
  for (int k0 = 0; k0 < KP; k0 += 32) {
    for (int c = w; c < 8; c += 4) {
      const size_t g = (size_t)(row0 + c * 16 + srow) * KP + k0 + scol;
      gload_lds16(Agh + g, sAh + c * 512);
      gload_lds16(Agl + g, sAl + c * 512);
    }
    for (int c = w; c < NOP / 16; c += 4) {
      const size_t g = (size_t)(c * 16 + srow) * KP + k0 + scol;
      gload_lds16(Wth + g, sBh + c * 512);
      gload_lds16(Wtl + g, sBl + c * 512);
    }
    __syncthreads();
    short8 ah[2], al[2];
#pragma unroll
    for (int mt = 0; mt < 2; ++mt) {
      const int r = (w * 32 + mt * 16 + col16) * 32 + kqs;
      ah[mt] = *(const short8*)(sAh + r);
      al[mt] = *(const short8*)(sAl + r);
    }
#pragma unroll
    for (int nt = 0; nt < NFR; ++nt) {
      const int r = (nt * 16 + col16) * 32 + kqs;
      const short8 bh = *(const short8*)(sBh + r);
      const short8 bl = *(const short8*)(sBl + r);
#pragma unroll
      for (int mt = 0; mt < 2; ++mt) {
        acc[mt][nt] = __builtin_amdgcn_mfma_f32_16x16x32_bf16(ah[mt], bh, acc[mt][nt], 0, 0, 0);
        acc[mt][nt] = __builtin_amdgcn_mfma_f32_16x16x32_bf16(ah[mt], bl, acc[mt][nt], 0, 0, 0);
        acc[mt][nt] = __builtin_amdgcn_mfma_f32_16x16x32_bf16(al[mt], bh, acc[mt][nt], 0, 0, 0);
      }
    }
    __syncthreads();
  }
#pragma unroll
  for (int nt = 0; nt < NFR; ++nt) {
    const int col = nt * 16 + col16;
    const float bv = bias[col];
#pragma unroll
    for (int mt = 0; mt < 2; ++mt) {
      const int rbase = row0 + w * 32 + mt * 16 + four * 4;
#pragma unroll
      for (int r = 0; r < 4; ++r) {
        const int row = rbase + r;
        const float v = acc[mt][nt][r] + bv;
        if (MODE == 0) {
          outp[(size_t)row * NO + col] = 1.f / (1.f + expf(-v));
        } else {
          const float rg = zrin[(size_t)row * (2 * H) + H + col];
          const float hv = outp[(size_t)row * H + col];
          outp[(size_t)row * H + col] = rg * hv + (1.f - rg) * tanhf(v);
        }
      }
    }
  }
}

// ---------------------------------------------------------------------------
// attention + prototype + W_E + h0 build, fused. One thread per (n,b).
__global__ void attn_kernel(const float* __restrict__ h, const float* __restrict__ Wq,
                            const float* __restrict__ Mem, const float* __restrict__ FCE,
                            float* __restrict__ hB, float* __restrict__ WE) {
  __shared__ float sWq[64 * 32];
  __shared__ float sM[10 * 32];
  __shared__ float sF[32 * 8];
  const int tid = threadIdx.x;
  for (int i = tid; i < 64 * 32; i += 256) sWq[i] = Wq[i];
  for (int i = tid; i < 10 * 32; i += 256) sM[i] = Mem[i];
  for (int i = tid; i < 32 * 8; i += 256) sF[i] = FCE[i];
  __syncthreads();
  const int idx = blockIdx.x * 256 + tid;
  const float* hp = h + (size_t)idx * 64;
  float* hd = hB + (size_t)idx * 96;
  float q[32] = {};
  for (int i0 = 0; i0 < 16; ++i0) {
    const float4 h4 = *(const float4*)(hp + i0 * 4);
#pragma unroll
    for (int jj = 0; jj < 4; ++jj) {
      const float hv = ((const float*)&h4)[jj];
      hd[i0 * 4 + jj] = hv;  // h0 = [h, proto]
      const int i = i0 * 4 + jj;
#pragma unroll
      for (int c = 0; c < 32; ++c) q[c] += hv * sWq[i * 32 + c];
    }
  }
  float lg[10];
  float mx = -1e30f;
#pragma unroll
  for (int m = 0; m < 10; ++m) {
    float s = 0.f;
#pragma unroll
    for (int c = 0; c < 32; ++c) s += q[c] * sM[m * 32 + c];
    lg[m] = s;
    mx = fmaxf(mx, s);
  }
  float den = 0.f;
#pragma unroll
  for (int m = 0; m < 10; ++m) { lg[m] = expf(lg[m] - mx); den += lg[m]; }
  const float inv = 1.f / den;
  float p[32] = {};
#pragma unroll
  for (int m = 0; m < 10; ++m) {
    const float a = lg[m] * inv;
#pragma unroll
    for (int c = 0; c < 32; ++c) p[c] += a * sM[m * 32 + c];
  }
#pragma unroll
  for (int c = 0; c < 32; ++c) hd[64 + c] = p[c];
  float* wd = WE + (size_t)idx * 8;
#pragma unroll
  for (int e = 0; e < 8; ++e) {
    float s = 0.f;
#pragma unroll
    for (int c = 0; c < 32; ++c) s += p[c] * sF[c * 8 + e];
    wd[e] = s;
  }
}

__global__ void proj_kernel(const float* __restrict__ h, const float* __restrict__ pW,
                            const float* __restrict__ pb, float* __restrict__ go,
                            float* __restrict__ out, int t) {
  __shared__ float sW[96];
  if (threadIdx.x < 96) sW[threadIdx.x] = pW[threadIdx.x];
  __syncthreads();
  const int idx = blockIdx.x * 256 + threadIdx.x;
  const float* hp = h + (size_t)idx * 96;
  float acc = pb[0];
  for (int j0 = 0; j0 < 24; ++j0) {
    const float4 h4 = *(const float4*)(hp + j0 * 4);
    acc += h4.x * sW[j0 * 4] + h4.y * sW[j0 * 4 + 1] + h4.z * sW[j0 * 4 + 2] + h4.w * sW[j0 * 4 + 3];
  }
  go[idx] = acc;
  const int n = idx >> 6, b = idx & 63;
  out[((size_t)b * HOR_ + t) * NN + n] = acc;
}

// ---------------------------------------------------------------------------
extern "C" void kernel_launch(void* const* d_in, const int* in_sizes, int n_in,
                              void* d_out, int out_size, void* d_ws, size_t ws_size,
                              hipStream_t stream) {
  const float* x    = (const float*)d_in[0];
  const float* ycov = (const float*)d_in[1];
  const float* emb  = (const float*)d_in[2];
  const float* egW  = (const float*)d_in[3];
  const float* egb  = (const float*)d_in[4];
  const float* euW  = (const float*)d_in[5];
  const float* eub  = (const float*)d_in[6];
  const float* Mem  = (const float*)d_in[7];
  const float* Wq   = (const float*)d_in[8];
  const float* FCE  = (const float*)d_in[9];
  const float* dgW  = (const float*)d_in[10];
  const float* dgb  = (const float*)d_in[11];
  const float* duW  = (const float*)d_in[12];
  const float* dub  = (const float*)d_in[13];
  const float* pW   = (const float*)d_in[14];
  const float* pb   = (const float*)d_in[15];
  float* out = (float*)d_out;

  char* w = (char*)d_ws;
  auto alloc = [&](size_t bytes) {
    void* p = (void*)w;
    w += (bytes + 255) & ~(size_t)255;
    return p;
  };
  float* S1  = (float*)alloc((size_t)NN * NN * 4);
  float* zr  = (float*)alloc((size_t)NN * B_ * 192 * 4);
  float* hA  = (float*)alloc((size_t)NN * B_ * 64 * 4);
  float* hB  = (float*)alloc((size_t)NN * B_ * 96 * 4);
  float* go  = (float*)alloc((size_t)NN * B_ * 4);
  float* WE  = (float*)alloc((size_t)NN * B_ * 8 * 4);
  ushort_t* S1h = (ushort_t*)alloc((size_t)NN * NN * 2);
  ushort_t* S1l = (ushort_t*)alloc((size_t)NN * NN * 2);
  ushort_t* S2h = (ushort_t*)alloc((size_t)NN * NN * 2);
  ushort_t* S2l = (ushort_t*)alloc((size_t)NN * NN * 2);
  ushort_t* XTh = (ushort_t*)alloc((size_t)B_ * 98 * NN * 2);
  ushort_t* Agh = (ushort_t*)alloc((size_t)NN * B_ * 320 * 2);
  ushort_t* Agl = (ushort_t*)alloc((size_t)NN * B_ * 320 * 2);
  ushort_t* WtegH = (ushort_t*)alloc(128 * 224 * 2);
  ushort_t* WtegL = (ushort_t*)alloc(128 * 224 * 2);
  ushort_t* WteuH = (ushort_t*)alloc(64 * 224 * 2);
  ushort_t* WteuL = (ushort_t*)alloc(64 * 224 * 2);
  ushort_t* WtdgH = (ushort_t*)alloc(192 * 320 * 2);
  ushort_t* WtdgL = (ushort_t*)alloc(192 * 320 * 2);
  ushort_t* WtduH = (ushort_t*)alloc(128 * 320 * 2);
  ushort_t* WtduL = (ushort_t*)alloc(128 * 320 * 2);
  (void)ws_size; (void)in_sizes; (void)n_in; (void)out_size;

  const dim3 blk(256);

  // ---- weight transposes + buffer init (pad regions must be defined) ----
  wt_kernel<<<(128 * 224 + 255) / 256, blk, 0, stream>>>(egW, WtegH, WtegL, 195, 128, 224, 128);
  wt_kernel<<<(64 * 224 + 255) / 256, blk, 0, stream>>>(euW, WteuH, WteuL, 195, 64, 224, 64);
  wt_kernel<<<(192 * 320 + 255) / 256, blk, 0, stream>>>(dgW, WtdgH, WtdgL, 294, 192, 320, 192);
  wt_kernel<<<(128 * 320 + 255) / 256, blk, 0, stream>>>(duW, WtduH, WtduL, 294, 96, 320, 128);
  hipMemsetAsync(Agh, 0, (size_t)NN * B_ * 320 * 2, stream);
  hipMemsetAsync(Agl, 0, (size_t)NN * B_ * 320 * 2, stream);
  hipMemsetAsync(hA, 0, (size_t)NN * B_ * 64 * 4, stream);
  hipMemsetAsync(go, 0, (size_t)NN * B_ * 4, stream);

  // ---- encoder supports ----
  gemm_nt_kernel<<<dim3(16, 16), blk, 0, stream>>>(emb, emb, S1, NN, 8);
  relu_softmax_kernel<<<NN, blk, 0, stream>>>(S1, S1h, S1l);
  cheb_kernel<<<dim3(16, 16), blk, 0, stream>>>(S1, S2h, S2l);

  // ---- encoder scan ----  (W_enc = 4160; live j-tiles 33, padded to 40)
  for (int t = 0; t < T_; ++t) {
    prep_kernel<65, 224, 0><<<dim3(65, 16), blk, 0, stream>>>(x, nullptr, hA, nullptr, Agh, Agl, XTh, t);
    graph_mfma_kernel<65, 224><<<dim3(40, 16), blk, 0, stream>>>(S1h, S1l, S2h, S2l, XTh, Agh, Agl);
    dense_mfma_kernel<224, 128, 128, 0, 64><<<512, blk, 0, stream>>>(Agh, Agl, WtegH, WtegL, egb, zr, nullptr);
    prep_kernel<65, 224, 1><<<dim3(65, 16), blk, 0, stream>>>(x, nullptr, hA, zr, Agh, Agl, XTh, t);
    graph_mfma_kernel<65, 224><<<dim3(40, 16), blk, 0, stream>>>(S1h, S1l, S2h, S2l, XTh, Agh, Agl);
    dense_mfma_kernel<224, 64, 64, 1, 64><<<512, blk, 0, stream>>>(Agh, Agl, WteuH, WteuL, eub, hA, zr);
  }

  // ---- attention / memory / decoder supports ----
  attn_kernel<<<256, blk, 0, stream>>>(hA, Wq, Mem, FCE, hB, WE);
  gemm_nt_kernel<<<dim3(16, 16), blk, 0, stream>>>(WE, WE, S1, NN, 512);
  relu_softmax_kernel<<<NN, blk, 0, stream>>>(S1, S1h, S1l);
  cheb_kernel<<<dim3(16, 16), blk, 0, stream>>>(S1, S2h, S2l);

  // ---- decoder scan ----  (W_dec = 6272; live j-tiles 49, padded to 56)
  for (int t = 0; t < HOR_; ++t) {
    prep_kernel<98, 320, 2><<<dim3(98, 16), blk, 0, stream>>>(go, ycov, hB, nullptr, Agh, Agl, XTh, t);
    graph_mfma_kernel<98, 320><<<dim3(56, 16), blk, 0, stream>>>(S1h, S1l, S2h, S2l, XTh, Agh, Agl);
    dense_mfma_kernel<320, 192, 192, 0, 96><<<512, blk, 0, stream>>>(Agh, Agl, WtdgH, WtdgL, dgb, zr, nullptr);
    prep_kernel<98, 320, 3><<<dim3(98, 16), blk, 0, stream>>>(go, ycov, hB, zr, Agh, Agl, XTh, t);
    graph_mfma_kernel<98, 320><<<dim3(56, 16), blk, 0, stream>>>(S1h, S1l, S2h, S2l, XTh, Agh, Agl);
    dense_mfma_kernel<320, 96, 128, 1, 96><<<512, blk, 0, stream>>>(Agh, Agl, WtduH, WtduL, dub, hB, zr);
    proj_kernel<<<256, blk, 0, stream>>>(hB, pW, pb, go, out, t);
  }
}

// Round 11
// 5280.595 us; speedup vs baseline: 1.5100x; 1.2573x over previous
//
#include <hip/hip_runtime.h>
#include <hip/hip_bf16.h>

// MMGCRN: graph convs + dense layers on MFMA.
// Graph: 32n x 128j tile, BK=64 (2x blocks -> ~6/CU, 16 drains/block),
//   A-side (S) bf16 hi+lo, B-side (X) plain bf16; XOR-swizzled LDS.
// Dense: full bf16x3. + XCD-stable grid padding.
// B=64, T=12, N=1024, HOR=12, RNN=64, DEC=96, K=3.
constexpr int B_ = 64, T_ = 12, NN = 1024, HOR_ = 12;

typedef __attribute__((ext_vector_type(8))) short short8;   // 8 bf16 (4 VGPRs)
typedef __attribute__((ext_vector_type(4))) float f32x4;    // MFMA C/D frag
typedef unsigned short ushort_t;

static __device__ inline ushort_t f2bh(float v) {
  __hip_bfloat16 h = __float2bfloat16(v);
  return *reinterpret_cast<ushort_t*>(&h);
}
static __device__ inline float bh2f(ushort_t u) {
  __hip_bfloat16 h = *reinterpret_cast<__hip_bfloat16*>(&u);
  return __bfloat162float(h);
}
static __device__ inline void split_bf16(float v, ushort_t& hi, ushort_t& lo) {
  hi = f2bh(v);
  lo = f2bh(v - bh2f(hi));
}

// async global->LDS, 16B per lane (LDS dest = wave-uniform base + lane*16).
static __device__ inline void gload_lds16(const ushort_t* g, ushort_t* l) {
  __builtin_amdgcn_global_load_lds(
      (const __attribute__((address_space(1))) unsigned int*)g,
      (__attribute__((address_space(3))) unsigned int*)l, 16, 0, 0);
}

// ---------------------------------------------------------------------------
// C = A (M x Kd) @ B (Ncol x Kd)^T, row-major, 64x64 tile, 4x4/thread. fp32.
__global__ void gemm_nt_kernel(const float* __restrict__ A, const float* __restrict__ Bm,
                               float* __restrict__ C, int Ncol, int Kd) {
  __shared__ float As[16][68];
  __shared__ float Bs[16][68];
  const int bm = blockIdx.y * 64, bn = blockIdx.x * 64;
  const int tid = threadIdx.x;
  const int tx = tid & 15, ty = tid >> 4;
  float acc[4][4] = {};
  for (int k0 = 0; k0 < Kd; k0 += 16) {
#pragma unroll
    for (int r = 0; r < 4; ++r) {
      const int m = (tid >> 4) + r * 16;
      const int kk = tid & 15;
      const int k = k0 + kk;
      As[kk][m] = (k < Kd) ? A[(size_t)(bm + m) * Kd + k] : 0.f;
      Bs[kk][m] = (k < Kd) ? Bm[(size_t)(bn + m) * Kd + k] : 0.f;
    }
    __syncthreads();
#pragma unroll
    for (int kk = 0; kk < 16; ++kk) {
      float a[4], b[4];
#pragma unroll
      for (int i = 0; i < 4; ++i) a[i] = As[kk][ty * 4 + i];
#pragma unroll
      for (int j = 0; j < 4; ++j) b[j] = Bs[kk][tx * 4 + j];
#pragma unroll
      for (int i = 0; i < 4; ++i)
#pragma unroll
        for (int j = 0; j < 4; ++j) acc[i][j] += a[i] * b[j];
    }
    __syncthreads();
  }
#pragma unroll
  for (int i = 0; i < 4; ++i)
#pragma unroll
    for (int j = 0; j < 4; ++j)
      C[(size_t)(bm + ty * 4 + i) * Ncol + bn + tx * 4 + j] = acc[i][j];
}

// ---------------------------------------------------------------------------
// In-place row softmax(relu(x)) over 1024 cols; also emits bf16 hi/lo split.
__global__ void relu_softmax_kernel(float* __restrict__ S, ushort_t* __restrict__ Sh,
                                    ushort_t* __restrict__ Sl) {
  const int row = blockIdx.x;
  float* r = S + (size_t)row * NN;
  const int tid = threadIdx.x;  // 256
  float v[4];
  float mx = 0.f;
#pragma unroll
  for (int j = 0; j < 4; ++j) {
    float xv = fmaxf(r[tid + j * 256], 0.f);
    v[j] = xv;
    mx = fmaxf(mx, xv);
  }
#pragma unroll
  for (int off = 1; off < 64; off <<= 1) mx = fmaxf(mx, __shfl_xor(mx, off));
  __shared__ float sred[4];
  const int wv = tid >> 6;
  if ((tid & 63) == 0) sred[wv] = mx;
  __syncthreads();
  mx = fmaxf(fmaxf(sred[0], sred[1]), fmaxf(sred[2], sred[3]));
  __syncthreads();
  float s = 0.f;
#pragma unroll
  for (int j = 0; j < 4; ++j) { v[j] = expf(v[j] - mx); s += v[j]; }
#pragma unroll
  for (int off = 1; off < 64; off <<= 1) s += __shfl_xor(s, off);
  if ((tid & 63) == 0) sred[wv] = s;
  __syncthreads();
  s = sred[0] + sred[1] + sred[2] + sred[3];
  const float inv = 1.f / s;
#pragma unroll
  for (int j = 0; j < 4; ++j) {
    const float sv = v[j] * inv;
    const size_t e = (size_t)row * NN + tid + j * 256;
    r[tid + j * 256] = sv;
    ushort_t hi, lo;
    split_bf16(sv, hi, lo);
    Sh[e] = hi;
    Sl[e] = lo;
  }
}

// ---------------------------------------------------------------------------
// S2 = 2*S@S - I, emitted directly as bf16 hi/lo split.
__global__ void cheb_kernel(const float* __restrict__ S, ushort_t* __restrict__ S2h,
                            ushort_t* __restrict__ S2l) {
  __shared__ float As[16][68];
  __shared__ float Bs[16][68];
  const int bm = blockIdx.y * 64, bn = blockIdx.x * 64;
  const int tid = threadIdx.x;
  const int tx = tid & 15, ty = tid >> 4;
  float acc[4][4] = {};
  for (int k0 = 0; k0 < NN; k0 += 16) {
#pragma unroll
    for (int r = 0; r < 4; ++r) {
      const int m = (tid >> 4) + r * 16, kk = tid & 15;
      As[kk][m] = S[(size_t)(bm + m) * NN + k0 + kk];
    }
#pragma unroll
    for (int r = 0; r < 4; ++r) {
      const int kk = (tid >> 6) + r * 4, c = tid & 63;
      Bs[kk][c] = S[(size_t)(k0 + kk) * NN + bn + c];
    }
    __syncthreads();
#pragma unroll
    for (int kk = 0; kk < 16; ++kk) {
      float a[4], b[4];
#pragma unroll
      for (int i = 0; i < 4; ++i) a[i] = As[kk][ty * 4 + i];
#pragma unroll
      for (int j = 0; j < 4; ++j) b[j] = Bs[kk][tx * 4 + j];
#pragma unroll
      for (int i = 0; i < 4; ++i)
#pragma unroll
        for (int j = 0; j < 4; ++j) acc[i][j] += a[i] * b[j];
    }
    __syncthreads();
  }
#pragma unroll
  for (int i = 0; i < 4; ++i) {
    const int row = bm + ty * 4 + i;
#pragma unroll
    for (int j = 0; j < 4; ++j) {
      const int col = bn + tx * 4 + j;
      const float val = 2.f * acc[i][j] - (row == col ? 1.f : 0.f);
      ushort_t hi, lo;
      split_bf16(val, hi, lo);
      S2h[(size_t)row * NN + col] = hi;
      S2l[(size_t)row * NN + col] = lo;
    }
  }
}

// ---------------------------------------------------------------------------
// Wt[no][k] = W[k][no], bf16 hi/lo, zero-padded to [NOP][KP].
__global__ void wt_kernel(const float* __restrict__ W, ushort_t* __restrict__ Wth,
                          ushort_t* __restrict__ Wtl, int KK, int NO, int KP, int NOP) {
  const int e = blockIdx.x * 256 + threadIdx.x;
  if (e >= NOP * KP) return;
  const int no = e / KP, k = e - no * KP;
  const float v = (no < NO && k < KK) ? W[(size_t)k * NO + no] : 0.f;
  ushort_t hi, lo;
  split_bf16(v, hi, lo);
  Wth[e] = hi;
  Wtl[e] = lo;
}

// ---------------------------------------------------------------------------
// prep: build cell input on the fly; write Ag (idx-major, bf16 hi/lo, for
// dense) and XT (j-major transpose, plain bf16, for graph B-operand).
// MODE 0: enc build [x_t, h]; 1: enc cand [x_t, z*h];
//      2: dec build [go, yc, h]; 3: dec cand [go, yc, z*h].
template <int C, int KP, int MODE>
__global__ void prep_kernel(const float* __restrict__ src0, const float* __restrict__ src1,
                            const float* __restrict__ hst, const float* __restrict__ zr,
                            ushort_t* __restrict__ Agh, ushort_t* __restrict__ Agl,
                            ushort_t* __restrict__ XTh, int t) {
  __shared__ float tile[64][65];
  const int bj = blockIdx.x * 64, bn = blockIdx.y * 64;
  const int tid = threadIdx.x;
  const int jl = tid & 63, nq = tid >> 6;
  const int j = bj + jl;
  const int b = j / C, c = j - b * C;
#pragma unroll
  for (int r = 0; r < 16; ++r) {
    const int node = bn + nq + r * 4;
    const int idx = node * 64 + b;
    float v;
    if (MODE == 0) {
      v = (c == 0) ? src0[((size_t)b * T_ + t) * NN + node]
                   : hst[(size_t)idx * 64 + (c - 1)];
    } else if (MODE == 1) {
      v = (c == 0) ? src0[((size_t)b * T_ + t) * NN + node]
                   : zr[(size_t)idx * 128 + (c - 1)] * hst[(size_t)idx * 64 + (c - 1)];
    } else if (MODE == 2) {
      v = (c == 0) ? src0[idx]
        : (c == 1) ? src1[((size_t)b * HOR_ + t) * NN + node]
                   : hst[(size_t)idx * 96 + (c - 2)];
    } else {
      v = (c == 0) ? src0[idx]
        : (c == 1) ? src1[((size_t)b * HOR_ + t) * NN + node]
                   : zr[(size_t)idx * 192 + (c - 2)] * hst[(size_t)idx * 96 + (c - 2)];
    }
    tile[nq + r * 4][jl] = v;
    ushort_t hi, lo;
    split_bf16(v, hi, lo);
    Agh[(size_t)idx * KP + c] = hi;
    Agl[(size_t)idx * KP + c] = lo;
  }
  __syncthreads();
  const int nl = tid & 63, jq = tid >> 6;
#pragma unroll
  for (int r = 0; r < 16; ++r) {
    const int jj = bj + jq + r * 4;
    XTh[(size_t)jj * NN + bn + nl] = f2bh(tile[nl][jq + r * 4]);
  }
}

// ---------------------------------------------------------------------------
// Graph conv: 32 nodes x 128 j, BK=64, both supports, XOR-swizzled LDS.
// A = S hi+lo (4 planes x 32 rows), B = X bf16 (128 rows); rows are 64
// ushorts (128 B); 16B slot s at row r holds global chunk s ^ (r&7).
// Waves: w stages A-plane w + B rows [w*32,+32); computes slice s=w>>1,
// j-half (w&1)*64, 2 mt x 4 nt frags, 2 K-halves, 2 planes = 32 MFMA/iter.
template <int C, int KP>
__global__ void graph_mfma_kernel(const ushort_t* __restrict__ S1h,
                                  const ushort_t* __restrict__ S1l,
                                  const ushort_t* __restrict__ S2h,
                                  const ushort_t* __restrict__ S2l,
                                  const ushort_t* __restrict__ XTh,
                                  ushort_t* __restrict__ Agh, ushort_t* __restrict__ Agl) {
  constexpr int W = B_ * C;
  const int bj = blockIdx.x * 128;
  if (bj >= W) return;  // padding block (keeps gridDim.x % 8 == 0)
  __shared__ __align__(16) ushort_t sA[4 * 32 * 64];   // 16 KB
  __shared__ __align__(16) ushort_t sB[128 * 64];      // 16 KB
  const int bn = blockIdx.y * 32;
  const int tid = threadIdx.x;
  const int w = tid >> 6, lane = tid & 63;
  const int row = lane & 15, kq = lane >> 4;

  const ushort_t* myA = (w == 0) ? S1h : (w == 1) ? S1l : (w == 2) ? S2h : S2l;
  ushort_t* ldsA_w = sA + w * (32 * 64);
  const int srow8 = lane >> 3;   // row within 8-row stage chunk
  const int sslot = lane & 7;    // LDS 16B slot within row

  const int s = w >> 1;
  const int jhalf = (w & 1) * 64;
  const ushort_t* Ah_lds = sA + (2 * s) * (32 * 64);
  const ushort_t* Al_lds = sA + (2 * s + 1) * (32 * 64);

  f32x4 acc[2][4] = {};
  for (int k0 = 0; k0 < NN; k0 += 64) {
    // stage A: plane w, 4 chunks of 8 rows (pre-swizzled source slot)
#pragma unroll
    for (int i = 0; i < 4; ++i) {
      const int grow = i * 8 + srow8;
      const int gchunk = sslot ^ (grow & 7);
      const ushort_t* g = myA + (size_t)(bn + grow) * NN + k0 + gchunk * 8;
      gload_lds16(g, ldsA_w + i * (8 * 64));
    }
    // stage B: rows [w*32, +32), 4 chunks
#pragma unroll
    for (int i = 0; i < 4; ++i) {
      const int brow = w * 32 + i * 8 + srow8;
      const int gchunk = sslot ^ (brow & 7);
      const ushort_t* g = XTh + (size_t)(bj + brow) * NN + k0 + gchunk * 8;
      gload_lds16(g, sB + (w * 32 + i * 8) * 64);
    }
    __syncthreads();
    short8 ah[2][2], al[2][2];  // [kk][mt]
#pragma unroll
    for (int kk = 0; kk < 2; ++kk)
#pragma unroll
      for (int mt = 0; mt < 2; ++mt) {
        const int r = mt * 16 + row;
        const int chunk = (kk * 4 + kq) ^ (r & 7);
        ah[kk][mt] = *(const short8*)(Ah_lds + r * 64 + chunk * 8);
        al[kk][mt] = *(const short8*)(Al_lds + r * 64 + chunk * 8);
      }
#pragma unroll
    for (int nt = 0; nt < 4; ++nt) {
#pragma unroll
      for (int kk = 0; kk < 2; ++kk) {
        const int r = jhalf + nt * 16 + row;
        const int chunk = (kk * 4 + kq) ^ (r & 7);
        const short8 bh = *(const short8*)(sB + r * 64 + chunk * 8);
#pragma unroll
        for (int mt = 0; mt < 2; ++mt) {
          acc[mt][nt] = __builtin_amdgcn_mfma_f32_16x16x32_bf16(ah[kk][mt], bh, acc[mt][nt], 0, 0, 0);
          acc[mt][nt] = __builtin_amdgcn_mfma_f32_16x16x32_bf16(al[kk][mt], bh, acc[mt][nt], 0, 0, 0);
        }
      }
    }
    __syncthreads();
  }
  // D mapping: col (=j) = lane&15, row (=node) = (lane>>4)*4 + reg.
  const int slice_off = (s + 1) * C;
#pragma unroll
  for (int nt = 0; nt < 4; ++nt) {
    const int j = bj + jhalf + nt * 16 + row;
    if (j < W) {
      const int b = j / C, c = j - b * C;
      const size_t coloff = (size_t)(slice_off + c);
#pragma unroll
      for (int mt = 0; mt < 2; ++mt) {
        const int node0 = bn + mt * 16 + kq * 4;
#pragma unroll
        for (int r = 0; r < 4; ++r) {
          const size_t a = (size_t)((node0 + r) * 64 + b) * KP + coloff;
          ushort_t hi, lo;
          split_bf16(acc[mt][nt][r], hi, lo);
          Agh[a] = hi;
          Agl[a] = lo;
        }
      }
    }
  }
}

// ---------------------------------------------------------------------------
// Dense on MFMA, T2-swizzled, bf16x3: 128 rows x NO cols (unchanged from r10).
// MODE 0: sigmoid -> outp(zr, stride NO=2H). MODE 1: fused GRU combine.
template <int KP, int NO, int NOP, int MODE, int H>
__global__ void dense_mfma_kernel(const ushort_t* __restrict__ Agh,
                                  const ushort_t* __restrict__ Agl,
                                  const ushort_t* __restrict__ Wth,
                                  const ushort_t* __restrict__ Wtl,
                                  const float* __restrict__ bias,
                                  float* __restrict__ outp,
                                  const float* __restrict__ zrin) {
  constexpr int NFR = NO / 16;
  __shared__ __align__(16) ushort_t sAh[128 * 32];
  __shared__ __align__(16) ushort_t sAl[128 * 32];
  __shared__ __align__(16) ushort_t sBh[NOP * 32];
  __shared__ __align__(16) ushort_t sBl[NOP * 32];
  const int row0 = blockIdx.x * 128;
  const int tid = threadIdx.x;
  const int w = tid >> 6, lane = tid & 63;
  const int col16 = lane & 15, four = lane >> 4;
  const int srow = lane >> 2;
  const int scol = ((lane & 3) ^ ((srow >> 1) & 3)) * 8;  // pre-swizzled source
  const int kqs = (four ^ ((col16 >> 1) & 3)) * 8;        // swizzled read slot
  f32x4 acc[2][NFR] = {};
  for (int k0 = 0; k0 < KP; k0 += 32) {
    for (int c = w; c < 8; c += 4) {
      const size_t g = (size_t)(row0 + c * 16 + srow) * KP + k0 + scol;
      gload_lds16(Agh + g, sAh + c * 512);
      gload_lds16(Agl + g, sAl + c * 512);
    }
    for (int c = w; c < NOP / 16; c += 4) {
      const size_t g = (size_t)(c * 16 + srow) * KP + k0 + scol;
      gload_lds16(Wth + g, sBh + c * 512);
      gload_lds16(Wtl + g, sBl + c * 512);
    }
    __syncthreads();
    short8 ah[2], al[2];
#pragma unroll
    for (int mt = 0; mt < 2; ++mt) {
      const int r = (w * 32 + mt * 16 + col16) * 32 + kqs;
      ah[mt] = *(const short8*)(sAh + r);
      al[mt] = *(const short8*)(sAl + r);
    }
#pragma unroll
    for (int nt = 0; nt < NFR; ++nt) {
      const int r = (nt * 16 + col16) * 32 + kqs;
      const short8 bh = *(const short8*)(sBh + r);
      const short8 bl = *(const short8*)(sBl + r);
#pragma unroll
      for (int mt = 0; mt < 2; ++mt) {
        acc[mt][nt] = __builtin_amdgcn_mfma_f32_16x16x32_bf16(ah[mt], bh, acc[mt][nt], 0, 0, 0);
        acc[mt][nt] = __builtin_amdgcn_mfma_f32_16x16x32_bf16(ah[mt], bl, acc[mt][nt], 0, 0, 0);
        acc[mt][nt] = __builtin_amdgcn_mfma_f32_16x16x32_bf16(al[mt], bh, acc[mt][nt], 0, 0, 0);
      }
    }
    __syncthreads();
  }
#pragma unroll
  for (int nt = 0; nt < NFR; ++nt) {
    const int col = nt * 16 + col16;
    const float bv = bias[col];
#pragma unroll
    for (int mt = 0; mt < 2; ++mt) {
      const int rbase = row0 + w * 32 + mt * 16 + four * 4;
#pragma unroll
      for (int r = 0; r < 4; ++r) {
        const int row = rbase + r;
        const float v = acc[mt][nt][r] + bv;
        if (MODE == 0) {
          outp[(size_t)row * NO + col] = 1.f / (1.f + expf(-v));
        } else {
          const float rg = zrin[(size_t)row * (2 * H) + H + col];
          const float hv = outp[(size_t)row * H + col];
          outp[(size_t)row * H + col] = rg * hv + (1.f - rg) * tanhf(v);
        }
      }
    }
  }
}

// ---------------------------------------------------------------------------
// attention + prototype + W_E + h0 build, fused. One thread per (n,b).
__global__ void attn_kernel(const float* __restrict__ h, const float* __restrict__ Wq,
                            const float* __restrict__ Mem, const float* __restrict__ FCE,
                            float* __restrict__ hB, float* __restrict__ WE) {
  __shared__ float sWq[64 * 32];
  __shared__ float sM[10 * 32];
  __shared__ float sF[32 * 8];
  const int tid = threadIdx.x;
  for (int i = tid; i < 64 * 32; i += 256) sWq[i] = Wq[i];
  for (int i = tid; i < 10 * 32; i += 256) sM[i] = Mem[i];
  for (int i = tid; i < 32 * 8; i += 256) sF[i] = FCE[i];
  __syncthreads();
  const int idx = blockIdx.x * 256 + tid;
  const float* hp = h + (size_t)idx * 64;
  float* hd = hB + (size_t)idx * 96;
  float q[32] = {};
  for (int i0 = 0; i0 < 16; ++i0) {
    const float4 h4 = *(const float4*)(hp + i0 * 4);
#pragma unroll
    for (int jj = 0; jj < 4; ++jj) {
      const float hv = ((const float*)&h4)[jj];
      hd[i0 * 4 + jj] = hv;  // h0 = [h, proto]
      const int i = i0 * 4 + jj;
#pragma unroll
      for (int c = 0; c < 32; ++c) q[c] += hv * sWq[i * 32 + c];
    }
  }
  float lg[10];
  float mx = -1e30f;
#pragma unroll
  for (int m = 0; m < 10; ++m) {
    float s = 0.f;
#pragma unroll
    for (int c = 0; c < 32; ++c) s += q[c] * sM[m * 32 + c];
    lg[m] = s;
    mx = fmaxf(mx, s);
  }
  float den = 0.f;
#pragma unroll
  for (int m = 0; m < 10; ++m) { lg[m] = expf(lg[m] - mx); den += lg[m]; }
  const float inv = 1.f / den;
  float p[32] = {};
#pragma unroll
  for (int m = 0; m < 10; ++m) {
    const float a = lg[m] * inv;
#pragma unroll
    for (int c = 0; c < 32; ++c) p[c] += a * sM[m * 32 + c];
  }
#pragma unroll
  for (int c = 0; c < 32; ++c) hd[64 + c] = p[c];
  float* wd = WE + (size_t)idx * 8;
#pragma unroll
  for (int e = 0; e < 8; ++e) {
    float s = 0.f;
#pragma unroll
    for (int c = 0; c < 32; ++c) s += p[c] * sF[c * 8 + e];
    wd[e] = s;
  }
}

__global__ void proj_kernel(const float* __restrict__ h, const float* __restrict__ pW,
                            const float* __restrict__ pb, float* __restrict__ go,
                            float* __restrict__ out, int t) {
  __shared__ float sW[96];
  if (threadIdx.x < 96) sW[threadIdx.x] = pW[threadIdx.x];
  __syncthreads();
  const int idx = blockIdx.x * 256 + threadIdx.x;
  const float* hp = h + (size_t)idx * 96;
  float acc = pb[0];
  for (int j0 = 0; j0 < 24; ++j0) {
    const float4 h4 = *(const float4*)(hp + j0 * 4);
    acc += h4.x * sW[j0 * 4] + h4.y * sW[j0 * 4 + 1] + h4.z * sW[j0 * 4 + 2] + h4.w * sW[j0 * 4 + 3];
  }
  go[idx] = acc;
  const int n = idx >> 6, b = idx & 63;
  out[((size_t)b * HOR_ + t) * NN + n] = acc;
}

// ---------------------------------------------------------------------------
extern "C" void kernel_launch(void* const* d_in, const int* in_sizes, int n_in,
                              void* d_out, int out_size, void* d_ws, size_t ws_size,
                              hipStream_t stream) {
  const float* x    = (const float*)d_in[0];
  const float* ycov = (const float*)d_in[1];
  const float* emb  = (const float*)d_in[2];
  const float* egW  = (const float*)d_in[3];
  const float* egb  = (const float*)d_in[4];
  const float* euW  = (const float*)d_in[5];
  const float* eub  = (const float*)d_in[6];
  const float* Mem  = (const float*)d_in[7];
  const float* Wq   = (const float*)d_in[8];
  const float* FCE  = (const float*)d_in[9];
  const float* dgW  = (const float*)d_in[10];
  const float* dgb  = (const float*)d_in[11];
  const float* duW  = (const float*)d_in[12];
  const float* dub  = (const float*)d_in[13];
  const float* pW   = (const float*)d_in[14];
  const float* pb   = (const float*)d_in[15];
  float* out = (float*)d_out;

  char* w = (char*)d_ws;
  auto alloc = [&](size_t bytes) {
    void* p = (void*)w;
    w += (bytes + 255) & ~(size_t)255;
    return p;
  };
  float* S1  = (float*)alloc((size_t)NN * NN * 4);
  float* zr  = (float*)alloc((size_t)NN * B_ * 192 * 4);
  float* hA  = (float*)alloc((size_t)NN * B_ * 64 * 4);
  float* hB  = (float*)alloc((size_t)NN * B_ * 96 * 4);
  float* go  = (float*)alloc((size_t)NN * B_ * 4);
  float* WE  = (float*)alloc((size_t)NN * B_ * 8 * 4);
  ushort_t* S1h = (ushort_t*)alloc((size_t)NN * NN * 2);
  ushort_t* S1l = (ushort_t*)alloc((size_t)NN * NN * 2);
  ushort_t* S2h = (ushort_t*)alloc((size_t)NN * NN * 2);
  ushort_t* S2l = (ushort_t*)alloc((size_t)NN * NN * 2);
  ushort_t* XTh = (ushort_t*)alloc((size_t)B_ * 98 * NN * 2);
  ushort_t* Agh = (ushort_t*)alloc((size_t)NN * B_ * 320 * 2);
  ushort_t* Agl = (ushort_t*)alloc((size_t)NN * B_ * 320 * 2);
  ushort_t* WtegH = (ushort_t*)alloc(128 * 224 * 2);
  ushort_t* WtegL = (ushort_t*)alloc(128 * 224 * 2);
  ushort_t* WteuH = (ushort_t*)alloc(64 * 224 * 2);
  ushort_t* WteuL = (ushort_t*)alloc(64 * 224 * 2);
  ushort_t* WtdgH = (ushort_t*)alloc(192 * 320 * 2);
  ushort_t* WtdgL = (ushort_t*)alloc(192 * 320 * 2);
  ushort_t* WtduH = (ushort_t*)alloc(128 * 320 * 2);
  ushort_t* WtduL = (ushort_t*)alloc(128 * 320 * 2);
  (void)ws_size; (void)in_sizes; (void)n_in; (void)out_size;

  const dim3 blk(256);

  // ---- weight transposes + buffer init (pad regions must be defined) ----
  wt_kernel<<<(128 * 224 + 255) / 256, blk, 0, stream>>>(egW, WtegH, WtegL, 195, 128, 224, 128);
  wt_kernel<<<(64 * 224 + 255) / 256, blk, 0, stream>>>(euW, WteuH, WteuL, 195, 64, 224, 64);
  wt_kernel<<<(192 * 320 + 255) / 256, blk, 0, stream>>>(dgW, WtdgH, WtdgL, 294, 192, 320, 192);
  wt_kernel<<<(128 * 320 + 255) / 256, blk, 0, stream>>>(duW, WtduH, WtduL, 294, 96, 320, 128);
  hipMemsetAsync(Agh, 0, (size_t)NN * B_ * 320 * 2, stream);
  hipMemsetAsync(Agl, 0, (size_t)NN * B_ * 320 * 2, stream);
  hipMemsetAsync(hA, 0, (size_t)NN * B_ * 64 * 4, stream);
  hipMemsetAsync(go, 0, (size_t)NN * B_ * 4, stream);

  // ---- encoder supports ----
  gemm_nt_kernel<<<dim3(16, 16), blk, 0, stream>>>(emb, emb, S1, NN, 8);
  relu_softmax_kernel<<<NN, blk, 0, stream>>>(S1, S1h, S1l);
  cheb_kernel<<<dim3(16, 16), blk, 0, stream>>>(S1, S2h, S2l);

  // ---- encoder scan ----  (W_enc = 4160; live j-tiles 33, padded to 40)
  for (int t = 0; t < T_; ++t) {
    prep_kernel<65, 224, 0><<<dim3(65, 16), blk, 0, stream>>>(x, nullptr, hA, nullptr, Agh, Agl, XTh, t);
    graph_mfma_kernel<65, 224><<<dim3(40, 32), blk, 0, stream>>>(S1h, S1l, S2h, S2l, XTh, Agh, Agl);
    dense_mfma_kernel<224, 128, 128, 0, 64><<<512, blk, 0, stream>>>(Agh, Agl, WtegH, WtegL, egb, zr, nullptr);
    prep_kernel<65, 224, 1><<<dim3(65, 16), blk, 0, stream>>>(x, nullptr, hA, zr, Agh, Agl, XTh, t);
    graph_mfma_kernel<65, 224><<<dim3(40, 32), blk, 0, stream>>>(S1h, S1l, S2h, S2l, XTh, Agh, Agl);
    dense_mfma_kernel<224, 64, 64, 1, 64><<<512, blk, 0, stream>>>(Agh, Agl, WteuH, WteuL, eub, hA, zr);
  }

  // ---- attention / memory / decoder supports ----
  attn_kernel<<<256, blk, 0, stream>>>(hA, Wq, Mem, FCE, hB, WE);
  gemm_nt_kernel<<<dim3(16, 16), blk, 0, stream>>>(WE, WE, S1, NN, 512);
  relu_softmax_kernel<<<NN, blk, 0, stream>>>(S1, S1h, S1l);
  cheb_kernel<<<dim3(16, 16), blk, 0, stream>>>(S1, S2h, S2l);

  // ---- decoder scan ----  (W_dec = 6272; live j-tiles 49, padded to 56)
  for (int t = 0; t < HOR_; ++t) {
    prep_kernel<98, 320, 2><<<dim3(98, 16), blk, 0, stream>>>(go, ycov, hB, nullptr, Agh, Agl, XTh, t);
    graph_mfma_kernel<98, 320><<<dim3(56, 32), blk, 0, stream>>>(S1h, S1l, S2h, S2l, XTh, Agh, Agl);
    dense_mfma_kernel<320, 192, 192, 0, 96><<<512, blk, 0, stream>>>(Agh, Agl, WtdgH, WtdgL, dgb, zr, nullptr);
    prep_kernel<98, 320, 3><<<dim3(98, 16), blk, 0, stream>>>(go, ycov, hB, zr, Agh, Agl, XTh, t);
    graph_mfma_kernel<98, 320><<<dim3(56, 32), blk, 0, stream>>>(S1h, S1l, S2h, S2l, XTh, Agh, Agl);
    dense_mfma_kernel<320, 96, 128, 1, 96><<<512, blk, 0, stream>>>(Agh, Agl, WtduH, WtduL, dub, hB, zr);
    proj_kernel<<<256, blk, 0, stream>>>(hB, pW, pb, go, out, t);
  }
}

// Round 13
// 4410.450 us; speedup vs baseline: 1.8079x; 1.1973x over previous
//
#include <hip/hip_runtime.h>
#include <hip/hip_bf16.h>

// MMGCRN on MFMA. Graph: S(hi+lo) x X(bf16); Dense: A(bf16) x W(hi+lo);
// cheb on MFMA (bf16x3). 32nx128j BK=64 graph tile, XCD-stable grids,
// XOR-swizzled LDS throughout.
// B=64, T=12, N=1024, HOR=12, RNN=64, DEC=96, K=3.
constexpr int B_ = 64, T_ = 12, NN = 1024, HOR_ = 12;

typedef __attribute__((ext_vector_type(8))) short short8;   // 8 bf16 (4 VGPRs)
typedef __attribute__((ext_vector_type(4))) float f32x4;    // MFMA C/D frag
typedef unsigned short ushort_t;

static __device__ inline ushort_t f2bh(float v) {
  __hip_bfloat16 h = __float2bfloat16(v);
  return *reinterpret_cast<ushort_t*>(&h);
}
static __device__ inline float bh2f(ushort_t u) {
  __hip_bfloat16 h = *reinterpret_cast<__hip_bfloat16*>(&u);
  return __bfloat162float(h);
}
static __device__ inline void split_bf16(float v, ushort_t& hi, ushort_t& lo) {
  hi = f2bh(v);
  lo = f2bh(v - bh2f(hi));
}

// async global->LDS, 16B per lane (LDS dest = wave-uniform base + lane*16).
static __device__ inline void gload_lds16(const ushort_t* g, ushort_t* l) {
  __builtin_amdgcn_global_load_lds(
      (const __attribute__((address_space(1))) unsigned int*)g,
      (__attribute__((address_space(3))) unsigned int*)l, 16, 0, 0);
}

// ---------------------------------------------------------------------------
// C = A (M x Kd) @ B (Ncol x Kd)^T, row-major, 64x64 tile, 4x4/thread. fp32.
__global__ void gemm_nt_kernel(const float* __restrict__ A, const float* __restrict__ Bm,
                               float* __restrict__ C, int Ncol, int Kd) {
  __shared__ float As[16][68];
  __shared__ float Bs[16][68];
  const int bm = blockIdx.y * 64, bn = blockIdx.x * 64;
  const int tid = threadIdx.x;
  const int tx = tid & 15, ty = tid >> 4;
  float acc[4][4] = {};
  for (int k0 = 0; k0 < Kd; k0 += 16) {
#pragma unroll
    for (int r = 0; r < 4; ++r) {
      const int m = (tid >> 4) + r * 16;
      const int kk = tid & 15;
      const int k = k0 + kk;
      As[kk][m] = (k < Kd) ? A[(size_t)(bm + m) * Kd + k] : 0.f;
      Bs[kk][m] = (k < Kd) ? Bm[(size_t)(bn + m) * Kd + k] : 0.f;
    }
    __syncthreads();
#pragma unroll
    for (int kk = 0; kk < 16; ++kk) {
      float a[4], b[4];
#pragma unroll
      for (int i = 0; i < 4; ++i) a[i] = As[kk][ty * 4 + i];
#pragma unroll
      for (int j = 0; j < 4; ++j) b[j] = Bs[kk][tx * 4 + j];
#pragma unroll
      for (int i = 0; i < 4; ++i)
#pragma unroll
        for (int j = 0; j < 4; ++j) acc[i][j] += a[i] * b[j];
    }
    __syncthreads();
  }
#pragma unroll
  for (int i = 0; i < 4; ++i)
#pragma unroll
    for (int j = 0; j < 4; ++j)
      C[(size_t)(bm + ty * 4 + i) * Ncol + bn + tx * 4 + j] = acc[i][j];
}

// ---------------------------------------------------------------------------
// In-place row softmax(relu(x)) over 1024 cols; also emits bf16 hi/lo split.
__global__ void relu_softmax_kernel(float* __restrict__ S, ushort_t* __restrict__ Sh,
                                    ushort_t* __restrict__ Sl) {
  const int row = blockIdx.x;
  float* r = S + (size_t)row * NN;
  const int tid = threadIdx.x;  // 256
  float v[4];
  float mx = 0.f;
#pragma unroll
  for (int j = 0; j < 4; ++j) {
    float xv = fmaxf(r[tid + j * 256], 0.f);
    v[j] = xv;
    mx = fmaxf(mx, xv);
  }
#pragma unroll
  for (int off = 1; off < 64; off <<= 1) mx = fmaxf(mx, __shfl_xor(mx, off));
  __shared__ float sred[4];
  const int wv = tid >> 6;
  if ((tid & 63) == 0) sred[wv] = mx;
  __syncthreads();
  mx = fmaxf(fmaxf(sred[0], sred[1]), fmaxf(sred[2], sred[3]));
  __syncthreads();
  float s = 0.f;
#pragma unroll
  for (int j = 0; j < 4; ++j) { v[j] = expf(v[j] - mx); s += v[j]; }
#pragma unroll
  for (int off = 1; off < 64; off <<= 1) s += __shfl_xor(s, off);
  if ((tid & 63) == 0) sred[wv] = s;
  __syncthreads();
  s = sred[0] + sred[1] + sred[2] + sred[3];
  const float inv = 1.f / s;
#pragma unroll
  for (int j = 0; j < 4; ++j) {
    const float sv = v[j] * inv;
    const size_t e = (size_t)row * NN + tid + j * 256;
    r[tid + j * 256] = sv;
    ushort_t hi, lo;
    split_bf16(sv, hi, lo);
    Sh[e] = hi;
    Sl[e] = lo;
  }
}

// ---------------------------------------------------------------------------
// ST = S^T, bf16 hi/lo split. LDS-tiled 64x64, both sides coalesced.
__global__ void st_kernel(const float* __restrict__ S, ushort_t* __restrict__ STh,
                          ushort_t* __restrict__ STl) {
  __shared__ float tile[64][65];
  const int bx = blockIdx.x * 64, by = blockIdx.y * 64;
  const int tid = threadIdx.x;
  const int cl = tid & 63, rq = tid >> 6;
#pragma unroll
  for (int r = 0; r < 16; ++r) {
    const int rr = rq + r * 4;
    tile[rr][cl] = S[(size_t)(by + rr) * NN + bx + cl];
  }
  __syncthreads();
#pragma unroll
  for (int r = 0; r < 16; ++r) {
    const int rr = rq + r * 4;
    const float v = tile[cl][rr];  // = S[by+cl][bx+rr]
    ushort_t hi, lo;
    split_bf16(v, hi, lo);
    STh[(size_t)(bx + rr) * NN + by + cl] = hi;
    STl[(size_t)(bx + rr) * NN + by + cl] = lo;
  }
}

// ---------------------------------------------------------------------------
// S2 = 2*S@S - I on MFMA, bf16x3 (A=S1 hi/lo, B=ST hi/lo), out hi/lo split.
// Tile 32n x 64j, BK=64, grid (16,32) = 512 blocks. XOR-swizzled LDS.
__global__ void cheb_mfma_kernel(const ushort_t* __restrict__ S1h,
                                 const ushort_t* __restrict__ S1l,
                                 const ushort_t* __restrict__ STh,
                                 const ushort_t* __restrict__ STl,
                                 ushort_t* __restrict__ S2h, ushort_t* __restrict__ S2l) {
  __shared__ __align__(16) ushort_t sA[2 * 32 * 64];  // 8 KB
  __shared__ __align__(16) ushort_t sB[2 * 64 * 64];  // 16 KB
  const int bj = blockIdx.x * 64, bn = blockIdx.y * 32;
  const int tid = threadIdx.x;
  const int w = tid >> 6, lane = tid & 63;
  const int row = lane & 15, kq = lane >> 4;
  const int srow8 = lane >> 3, sslot = lane & 7;
  f32x4 acc[2] = {};
  for (int k0 = 0; k0 < NN; k0 += 64) {
#pragma unroll
    for (int t2 = 0; t2 < 2; ++t2) {  // A: 8 chunks, wave stages 2
      const int c = w + t2 * 4, p = c >> 2, i = c & 3;
      const int grow = i * 8 + srow8;
      const int gch = sslot ^ (grow & 7);
      const ushort_t* src = (p ? S1l : S1h) + (size_t)(bn + grow) * NN + k0 + gch * 8;
      gload_lds16(src, sA + p * 2048 + i * 512);
    }
#pragma unroll
    for (int t2 = 0; t2 < 4; ++t2) {  // B: 16 chunks, wave stages 4
      const int c2 = w + t2 * 4, p = c2 >> 3, rb = c2 & 7;
      const int grow = rb * 8 + srow8;
      const int gch = sslot ^ (grow & 7);
      const ushort_t* src = (p ? STl : STh) + (size_t)(bj + grow) * NN + k0 + gch * 8;
      gload_lds16(src, sB + p * 4096 + rb * 512);
    }
    __syncthreads();
#pragma unroll
    for (int kk = 0; kk < 2; ++kk) {
      const int rB = w * 16 + row;
      const int chB = ((kk * 4 + kq) ^ (rB & 7)) * 8;
      const short8 bh = *(const short8*)(sB + rB * 64 + chB);
      const short8 bl = *(const short8*)(sB + 4096 + rB * 64 + chB);
#pragma unroll
      for (int mt = 0; mt < 2; ++mt) {
        const int rA = mt * 16 + row;
        const int chA = ((kk * 4 + kq) ^ (rA & 7)) * 8;
        const short8 ah = *(const short8*)(sA + rA * 64 + chA);
        const short8 al = *(const short8*)(sA + 2048 + rA * 64 + chA);
        acc[mt] = __builtin_amdgcn_mfma_f32_16x16x32_bf16(ah, bh, acc[mt], 0, 0, 0);
        acc[mt] = __builtin_amdgcn_mfma_f32_16x16x32_bf16(ah, bl, acc[mt], 0, 0, 0);
        acc[mt] = __builtin_amdgcn_mfma_f32_16x16x32_bf16(al, bh, acc[mt], 0, 0, 0);
      }
    }
    __syncthreads();
  }
  const int j = bj + w * 16 + row;
#pragma unroll
  for (int mt = 0; mt < 2; ++mt) {
    const int node0 = bn + mt * 16 + kq * 4;
#pragma unroll
    for (int r = 0; r < 4; ++r) {
      const float val = 2.f * acc[mt][r] - ((node0 + r) == j ? 1.f : 0.f);
      ushort_t hi, lo;
      split_bf16(val, hi, lo);
      S2h[(size_t)(node0 + r) * NN + j] = hi;
      S2l[(size_t)(node0 + r) * NN + j] = lo;
    }
  }
}

// ---------------------------------------------------------------------------
// Wt[no][k] = W[k][no], bf16 hi/lo, zero-padded to [NOP][KP].
__global__ void wt_kernel(const float* __restrict__ W, ushort_t* __restrict__ Wth,
                          ushort_t* __restrict__ Wtl, int KK, int NO, int KP, int NOP) {
  const int e = blockIdx.x * 256 + threadIdx.x;
  if (e >= NOP * KP) return;
  const int no = e / KP, k = e - no * KP;
  const float v = (no < NO && k < KK) ? W[(size_t)k * NO + no] : 0.f;
  ushort_t hi, lo;
  split_bf16(v, hi, lo);
  Wth[e] = hi;
  Wtl[e] = lo;
}

// ---------------------------------------------------------------------------
// prep: build cell input on the fly; write Ag (idx-major bf16, for dense)
// and XT (j-major transpose bf16, for graph B-operand).
// MODE 0: enc build [x_t, h]; 1: enc cand [x_t, z*h];
//      2: dec build [go, yc, h]; 3: dec cand [go, yc, z*h].
template <int C, int KP, int MODE>
__global__ void prep_kernel(const float* __restrict__ src0, const float* __restrict__ src1,
                            const float* __restrict__ hst, const float* __restrict__ zr,
                            ushort_t* __restrict__ Agh, ushort_t* __restrict__ XTh, int t) {
  __shared__ float tile[64][65];
  const int bj = blockIdx.x * 64, bn = blockIdx.y * 64;
  const int tid = threadIdx.x;
  const int jl = tid & 63, nq = tid >> 6;
  const int j = bj + jl;
  const int b = j / C, c = j - b * C;
#pragma unroll
  for (int r = 0; r < 16; ++r) {
    const int node = bn + nq + r * 4;
    const int idx = node * 64 + b;
    float v;
    if (MODE == 0) {
      v = (c == 0) ? src0[((size_t)b * T_ + t) * NN + node]
                   : hst[(size_t)idx * 64 + (c - 1)];
    } else if (MODE == 1) {
      v = (c == 0) ? src0[((size_t)b * T_ + t) * NN + node]
                   : zr[(size_t)idx * 128 + (c - 1)] * hst[(size_t)idx * 64 + (c - 1)];
    } else if (MODE == 2) {
      v = (c == 0) ? src0[idx]
        : (c == 1) ? src1[((size_t)b * HOR_ + t) * NN + node]
                   : hst[(size_t)idx * 96 + (c - 2)];
    } else {
      v = (c == 0) ? src0[idx]
        : (c == 1) ? src1[((size_t)b * HOR_ + t) * NN + node]
                   : zr[(size_t)idx * 192 + (c - 2)] * hst[(size_t)idx * 96 + (c - 2)];
    }
    tile[nq + r * 4][jl] = v;
    Agh[(size_t)idx * KP + c] = f2bh(v);
  }
  __syncthreads();
  const int nl = tid & 63, jq = tid >> 6;
#pragma unroll
  for (int r = 0; r < 16; ++r) {
    const int jj = bj + jq + r * 4;
    XTh[(size_t)jj * NN + bn + nl] = f2bh(tile[nl][jq + r * 4]);
  }
}

// ---------------------------------------------------------------------------
// Graph conv: 32 nodes x 128 j, BK=64, both supports, XOR-swizzled LDS.
// A = S hi+lo (4 planes x 32 rows), B = X bf16 (128 rows). Writes Agh only.
template <int C, int KP>
__global__ void graph_mfma_kernel(const ushort_t* __restrict__ S1h,
                                  const ushort_t* __restrict__ S1l,
                                  const ushort_t* __restrict__ S2h,
                                  const ushort_t* __restrict__ S2l,
                                  const ushort_t* __restrict__ XTh,
                                  ushort_t* __restrict__ Agh) {
  constexpr int W = B_ * C;
  const int bj = blockIdx.x * 128;
  if (bj >= W) return;  // padding block (keeps gridDim.x % 8 == 0)
  __shared__ __align__(16) ushort_t sA[4 * 32 * 64];   // 16 KB
  __shared__ __align__(16) ushort_t sB[128 * 64];      // 16 KB
  const int bn = blockIdx.y * 32;
  const int tid = threadIdx.x;
  const int w = tid >> 6, lane = tid & 63;
  const int row = lane & 15, kq = lane >> 4;

  const ushort_t* myA = (w == 0) ? S1h : (w == 1) ? S1l : (w == 2) ? S2h : S2l;
  ushort_t* ldsA_w = sA + w * (32 * 64);
  const int srow8 = lane >> 3;   // row within 8-row stage chunk
  const int sslot = lane & 7;    // LDS 16B slot within row

  const int s = w >> 1;
  const int jhalf = (w & 1) * 64;
  const ushort_t* Ah_lds = sA + (2 * s) * (32 * 64);
  const ushort_t* Al_lds = sA + (2 * s + 1) * (32 * 64);

  f32x4 acc[2][4] = {};
  for (int k0 = 0; k0 < NN; k0 += 64) {
#pragma unroll
    for (int i = 0; i < 4; ++i) {
      const int grow = i * 8 + srow8;
      const int gchunk = sslot ^ (grow & 7);
      const ushort_t* g = myA + (size_t)(bn + grow) * NN + k0 + gchunk * 8;
      gload_lds16(g, ldsA_w + i * (8 * 64));
    }
#pragma unroll
    for (int i = 0; i < 4; ++i) {
      const int brow = w * 32 + i * 8 + srow8;
      const int gchunk = sslot ^ (brow & 7);
      const ushort_t* g = XTh + (size_t)(bj + brow) * NN + k0 + gchunk * 8;
      gload_lds16(g, sB + (w * 32 + i * 8) * 64);
    }
    __syncthreads();
    short8 ah[2][2], al[2][2];  // [kk][mt]
#pragma unroll
    for (int kk = 0; kk < 2; ++kk)
#pragma unroll
      for (int mt = 0; mt < 2; ++mt) {
        const int r = mt * 16 + row;
        const int chunk = (kk * 4 + kq) ^ (r & 7);
        ah[kk][mt] = *(const short8*)(Ah_lds + r * 64 + chunk * 8);
        al[kk][mt] = *(const short8*)(Al_lds + r * 64 + chunk * 8);
      }
#pragma unroll
    for (int nt = 0; nt < 4; ++nt) {
#pragma unroll
      for (int kk = 0; kk < 2; ++kk) {
        const int r = jhalf + nt * 16 + row;
        const int chunk = (kk * 4 + kq) ^ (r & 7);
        const short8 bh = *(const short8*)(sB + r * 64 + chunk * 8);
#pragma unroll
        for (int mt = 0; mt < 2; ++mt) {
          acc[mt][nt] = __builtin_amdgcn_mfma_f32_16x16x32_bf16(ah[kk][mt], bh, acc[mt][nt], 0, 0, 0);
          acc[mt][nt] = __builtin_amdgcn_mfma_f32_16x16x32_bf16(al[kk][mt], bh, acc[mt][nt], 0, 0, 0);
        }
      }
    }
    __syncthreads();
  }
  // D mapping: col (=j) = lane&15, row (=node) = (lane>>4)*4 + reg.
  const int slice_off = (s + 1) * C;
#pragma unroll
  for (int nt = 0; nt < 4; ++nt) {
    const int j = bj + jhalf + nt * 16 + row;
    if (j < W) {
      const int b = j / C, c = j - b * C;
      const size_t coloff = (size_t)(slice_off + c);
#pragma unroll
      for (int mt = 0; mt < 2; ++mt) {
        const int node0 = bn + mt * 16 + kq * 4;
#pragma unroll
        for (int r = 0; r < 4; ++r) {
          const size_t a = (size_t)((node0 + r) * 64 + b) * KP + coloff;
          Agh[a] = f2bh(acc[mt][nt][r]);
        }
      }
    }
  }
}

// ---------------------------------------------------------------------------
// Dense on MFMA, T2-swizzled: A bf16 x W (hi+lo) -> 2 MFMAs/pair.
// 128 rows x NO cols. MODE 0: sigmoid -> zr. MODE 1: fused GRU combine.
template <int KP, int NO, int NOP, int MODE, int H>
__global__ void dense_mfma_kernel(const ushort_t* __restrict__ Agh,
                                  const ushort_t* __restrict__ Wth,
                                  const ushort_t* __restrict__ Wtl,
                                  const float* __restrict__ bias,
                                  float* __restrict__ outp,
                                  const float* __restrict__ zrin) {
  constexpr int NFR = NO / 16;
  __shared__ __align__(16) ushort_t sAh[128 * 32];
  __shared__ __align__(16) ushort_t sBh[NOP * 32];
  __shared__ __align__(16) ushort_t sBl[NOP * 32];
  const int row0 = blockIdx.x * 128;
  const int tid = threadIdx.x;
  const int w = tid >> 6, lane = tid & 63;
  const int col16 = lane & 15, four = lane >> 4;
  const int srow = lane >> 2;
  const int scol = ((lane & 3) ^ ((srow >> 1) & 3)) * 8;  // pre-swizzled source
  const int kqs = (four ^ ((col16 >> 1) & 3)) * 8;        // swizzled read slot
  f32x4 acc[2][NFR] = {};
  for (int k0 = 0; k0 < KP; k0 += 32) {
    for (int c = w; c < 8; c += 4) {
      const size_t g = (size_t)(row0 + c * 16 + srow) * KP + k0 + scol;
      gload_lds16(Agh + g, sAh + c * 512);
    }
    for (int c = w; c < NOP / 16; c += 4) {
      const size_t g = (size_t)(c * 16 + srow) * KP + k0 + scol;
      gload_lds16(Wth + g, sBh + c * 512);
      gload_lds16(Wtl + g, sBl + c * 512);
    }
    __syncthreads();
    short8 ah[2];
#pragma unroll
    for (int mt = 0; mt < 2; ++mt) {
      const int r = (w * 32 + mt * 16 + col16) * 32 + kqs;
      ah[mt] = *(const short8*)(sAh + r);
    }
#pragma unroll
    for (int nt = 0; nt < NFR; ++nt) {
      const int r = (nt * 16 + col16) * 32 + kqs;
      const short8 bh = *(const short8*)(sBh + r);
      const short8 bl = *(const short8*)(sBl + r);
#pragma unroll
      for (int mt = 0; mt < 2; ++mt) {
        acc[mt][nt] = __builtin_amdgcn_mfma_f32_16x16x32_bf16(ah[mt], bh, acc[mt][nt], 0, 0, 0);
        acc[mt][nt] = __builtin_amdgcn_mfma_f32_16x16x32_bf16(ah[mt], bl, acc[mt][nt], 0, 0, 0);
      }
    }
    __syncthreads();
  }
#pragma unroll
  for (int nt = 0; nt < NFR; ++nt) {
    const int col = nt * 16 + col16;
    const float bv = bias[col];
#pragma unroll
    for (int mt = 0; mt < 2; ++mt) {
      const int rbase = row0 + w * 32 + mt * 16 + four * 4;
#pragma unroll
      for (int r = 0; r < 4; ++r) {
        const int row = rbase + r;
        const float v = acc[mt][nt][r] + bv;
        if (MODE == 0) {
          outp[(size_t)row * NO + col] = 1.f / (1.f + expf(-v));
        } else {
          const float rg = zrin[(size_t)row * (2 * H) + H + col];
          const float hv = outp[(size_t)row * H + col];
          outp[(size_t)row * H + col] = rg * hv + (1.f - rg) * tanhf(v);
        }
      }
    }
  }
}

// ---------------------------------------------------------------------------
// attention + prototype + W_E + h0 build, fused. One thread per (n,b).
__global__ void attn_kernel(const float* __restrict__ h, const float* __restrict__ Wq,
                            const float* __restrict__ Mem, const float* __restrict__ FCE,
                            float* __restrict__ hB, float* __restrict__ WE) {
  __shared__ float sWq[64 * 32];
  __shared__ float sM[10 * 32];
  __shared__ float sF[32 * 8];
  const int tid = threadIdx.x;
  for (int i = tid; i < 64 * 32; i += 256) sWq[i] = Wq[i];
  for (int i = tid; i < 10 * 32; i += 256) sM[i] = Mem[i];
  for (int i = tid; i < 32 * 8; i += 256) sF[i] = FCE[i];
  __syncthreads();
  const int idx = blockIdx.x * 256 + tid;
  const float* hp = h + (size_t)idx * 64;
  float* hd = hB + (size_t)idx * 96;
  float q[32] = {};
  for (int i0 = 0; i0 < 16; ++i0) {
    const float4 h4 = *(const float4*)(hp + i0 * 4);
#pragma unroll
    for (int jj = 0; jj < 4; ++jj) {
      const float hv = ((const float*)&h4)[jj];
      hd[i0 * 4 + jj] = hv;  // h0 = [h, proto]
      const int i = i0 * 4 + jj;
#pragma unroll
      for (int c = 0; c < 32; ++c) q[c] += hv * sWq[i * 32 + c];
    }
  }
  float lg[10];
  float mx = -1e30f;
#pragma unroll
  for (int m = 0; m < 10; ++m) {
    float s = 0.f;
#pragma unroll
    for (int c = 0; c < 32; ++c) s += q[c] * sM[m * 32 + c];
    lg[m] = s;
    mx = fmaxf(mx, s);
  }
  float den = 0.f;
#pragma unroll
  for (int m = 0; m < 10; ++m) { lg[m] = expf(lg[m] - mx); den += lg[m]; }
  const float inv = 1.f / den;
  float p[32] = {};
#pragma unroll
  for (int m = 0; m < 10; ++m) {
    const float a = lg[m] * inv;
#pragma unroll
    for (int c = 0; c < 32; ++c) p[c] += a * sM[m * 32 + c];
  }
#pragma unroll
  for (int c = 0; c < 32; ++c) hd[64 + c] = p[c];
  float* wd = WE + (size_t)idx * 8;
#pragma unroll
  for (int e = 0; e < 8; ++e) {
    float s = 0.f;
#pragma unroll
    for (int c = 0; c < 32; ++c) s += p[c] * sF[c * 8 + e];
    wd[e] = s;
  }
}

__global__ void proj_kernel(const float* __restrict__ h, const float* __restrict__ pW,
                            const float* __restrict__ pb, float* __restrict__ go,
                            float* __restrict__ out, int t) {
  __shared__ float sW[96];
  if (threadIdx.x < 96) sW[threadIdx.x] = pW[threadIdx.x];
  __syncthreads();
  const int idx = blockIdx.x * 256 + threadIdx.x;
  const float* hp = h + (size_t)idx * 96;
  float acc = pb[0];
  for (int j0 = 0; j0 < 24; ++j0) {
    const float4 h4 = *(const float4*)(hp + j0 * 4);
    acc += h4.x * sW[j0 * 4] + h4.y * sW[j0 * 4 + 1] + h4.z * sW[j0 * 4 + 2] + h4.w * sW[j0 * 4 + 3];
  }
  go[idx] = acc;
  const int n = idx >> 6, b = idx & 63;
  out[((size_t)b * HOR_ + t) * NN + n] = acc;
}

// ---------------------------------------------------------------------------
extern "C" void kernel_launch(void* const* d_in, const int* in_sizes, int n_in,
                              void* d_out, int out_size, void* d_ws, size_t ws_size,
                              hipStream_t stream) {
  const float* x    = (const float*)d_in[0];
  const float* ycov = (const float*)d_in[1];
  const float* emb  = (const float*)d_in[2];
  const float* egW  = (const float*)d_in[3];
  const float* egb  = (const float*)d_in[4];
  const float* euW  = (const float*)d_in[5];
  const float* eub  = (const float*)d_in[6];
  const float* Mem  = (const float*)d_in[7];
  const float* Wq   = (const float*)d_in[8];
  const float* FCE  = (const float*)d_in[9];
  const float* dgW  = (const float*)d_in[10];
  const float* dgb  = (const float*)d_in[11];
  const float* duW  = (const float*)d_in[12];
  const float* dub  = (const float*)d_in[13];
  const float* pW   = (const float*)d_in[14];
  const float* pb   = (const float*)d_in[15];
  float* out = (float*)d_out;

  char* w = (char*)d_ws;
  auto alloc = [&](size_t bytes) {
    void* p = (void*)w;
    w += (bytes + 255) & ~(size_t)255;
    return p;
  };
  float* S1  = (float*)alloc((size_t)NN * NN * 4);
  float* zr  = (float*)alloc((size_t)NN * B_ * 192 * 4);
  float* hA  = (float*)alloc((size_t)NN * B_ * 64 * 4);
  float* hB  = (float*)alloc((size_t)NN * B_ * 96 * 4);
  float* go  = (float*)alloc((size_t)NN * B_ * 4);
  float* WE  = (float*)alloc((size_t)NN * B_ * 8 * 4);
  ushort_t* S1h = (ushort_t*)alloc((size_t)NN * NN * 2);
  ushort_t* S1l = (ushort_t*)alloc((size_t)NN * NN * 2);
  ushort_t* S2h = (ushort_t*)alloc((size_t)NN * NN * 2);
  ushort_t* S2l = (ushort_t*)alloc((size_t)NN * NN * 2);
  ushort_t* STh = (ushort_t*)alloc((size_t)NN * NN * 2);
  ushort_t* STl = (ushort_t*)alloc((size_t)NN * NN * 2);
  ushort_t* XTh = (ushort_t*)alloc((size_t)B_ * 98 * NN * 2);
  ushort_t* Agh = (ushort_t*)alloc((size_t)NN * B_ * 320 * 2);
  ushort_t* WtegH = (ushort_t*)alloc(128 * 224 * 2);
  ushort_t* WtegL = (ushort_t*)alloc(128 * 224 * 2);
  ushort_t* WteuH = (ushort_t*)alloc(64 * 224 * 2);
  ushort_t* WteuL = (ushort_t*)alloc(64 * 224 * 2);
  ushort_t* WtdgH = (ushort_t*)alloc(192 * 320 * 2);
  ushort_t* WtdgL = (ushort_t*)alloc(192 * 320 * 2);
  ushort_t* WtduH = (ushort_t*)alloc(128 * 320 * 2);
  ushort_t* WtduL = (ushort_t*)alloc(128 * 320 * 2);
  (void)ws_size; (void)in_sizes; (void)n_in; (void)out_size;

  const dim3 blk(256);

  // ---- weight transposes + buffer init (pad regions must be defined) ----
  wt_kernel<<<(128 * 224 + 255) / 256, blk, 0, stream>>>(egW, WtegH, WtegL, 195, 128, 224, 128);
  wt_kernel<<<(64 * 224 + 255) / 256, blk, 0, stream>>>(euW, WteuH, WteuL, 195, 64, 224, 64);
  wt_kernel<<<(192 * 320 + 255) / 256, blk, 0, stream>>>(dgW, WtdgH, WtdgL, 294, 192, 320, 192);
  wt_kernel<<<(128 * 320 + 255) / 256, blk, 0, stream>>>(duW, WtduH, WtduL, 294, 96, 320, 128);
  hipMemsetAsync(Agh, 0, (size_t)NN * B_ * 320 * 2, stream);
  hipMemsetAsync(hA, 0, (size_t)NN * B_ * 64 * 4, stream);
  hipMemsetAsync(go, 0, (size_t)NN * B_ * 4, stream);

  // ---- encoder supports ----
  gemm_nt_kernel<<<dim3(16, 16), blk, 0, stream>>>(emb, emb, S1, NN, 8);
  relu_softmax_kernel<<<NN, blk, 0, stream>>>(S1, S1h, S1l);
  st_kernel<<<dim3(16, 16), blk, 0, stream>>>(S1, STh, STl);
  cheb_mfma_kernel<<<dim3(16, 32), blk, 0, stream>>>(S1h, S1l, STh, STl, S2h, S2l);

  // ---- encoder scan ----  (W_enc = 4160; live j-tiles 33, padded to 40)
  for (int t = 0; t < T_; ++t) {
    prep_kernel<65, 224, 0><<<dim3(65, 16), blk, 0, stream>>>(x, nullptr, hA, nullptr, Agh, XTh, t);
    graph_mfma_kernel<65, 224><<<dim3(40, 32), blk, 0, stream>>>(S1h, S1l, S2h, S2l, XTh, Agh);
    dense_mfma_kernel<224, 128, 128, 0, 64><<<512, blk, 0, stream>>>(Agh, WtegH, WtegL, egb, zr, nullptr);
    prep_kernel<65, 224, 1><<<dim3(65, 16), blk, 0, stream>>>(x, nullptr, hA, zr, Agh, XTh, t);
    graph_mfma_kernel<65, 224><<<dim3(40, 32), blk, 0, stream>>>(S1h, S1l, S2h, S2l, XTh, Agh);
    dense_mfma_kernel<224, 64, 64, 1, 64><<<512, blk, 0, stream>>>(Agh, WteuH, WteuL, eub, hA, zr);
  }

  // ---- attention / memory / decoder supports ----
  attn_kernel<<<256, blk, 0, stream>>>(hA, Wq, Mem, FCE, hB, WE);
  gemm_nt_kernel<<<dim3(16, 16), blk, 0, stream>>>(WE, WE, S1, NN, 512);
  relu_softmax_kernel<<<NN, blk, 0, stream>>>(S1, S1h, S1l);
  st_kernel<<<dim3(16, 16), blk, 0, stream>>>(S1, STh, STl);
  cheb_mfma_kernel<<<dim3(16, 32), blk, 0, stream>>>(S1h, S1l, STh, STl, S2h, S2l);

  // ---- decoder scan ----  (W_dec = 6272; live j-tiles 49, padded to 56)
  for (int t = 0; t < HOR_; ++t) {
    prep_kernel<98, 320, 2><<<dim3(98, 16), blk, 0, stream>>>(go, ycov, hB, nullptr, Agh, XTh, t);
    graph_mfma_kernel<98, 320><<<dim3(56, 32), blk, 0, stream>>>(S1h, S1l, S2h, S2l, XTh, Agh);
    dense_mfma_kernel<320, 192, 192, 0, 96><<<512, blk, 0, stream>>>(Agh, WtdgH, WtdgL, dgb, zr, nullptr);
    prep_kernel<98, 320, 3><<<dim3(98, 16), blk, 0, stream>>>(go, ycov, hB, zr, Agh, XTh, t);
    graph_mfma_kernel<98, 320><<<dim3(56, 32), blk, 0, stream>>>(S1h, S1l, S2h, S2l, XTh, Agh);
    dense_mfma_kernel<320, 96, 128, 1, 96><<<512, blk, 0, stream>>>(Agh, WtduH, WtduL, dub, hB, zr);
    proj_kernel<<<256, blk, 0, stream>>>(hB, pW, pb, go, out, t);
  }
}

// Round 14
// 3913.176 us; speedup vs baseline: 2.0377x; 1.1271x over previous
//
#include <hip/hip_runtime.h>
#include <hip/hip_bf16.h>

// MMGCRN on MFMA. Graph: S(bf16) x X(bf16), slice2 via M=2S^2 (bf16) with
// exact -X in fp32 epilogue. Dense: A(bf16) x W(hi+lo). cheb bf16x3 -> Mh.
// 32nx128j BK=64 graph tile, XCD-stable grids, XOR-swizzled LDS.
// B=64, T=12, N=1024, HOR=12, RNN=64, DEC=96, K=3.
constexpr int B_ = 64, T_ = 12, NN = 1024, HOR_ = 12;

typedef __attribute__((ext_vector_type(8))) short short8;   // 8 bf16 (4 VGPRs)
typedef __attribute__((ext_vector_type(4))) float f32x4;    // MFMA C/D frag
typedef unsigned short ushort_t;

static __device__ inline ushort_t f2bh(float v) {
  __hip_bfloat16 h = __float2bfloat16(v);
  return *reinterpret_cast<ushort_t*>(&h);
}
static __device__ inline float bh2f(ushort_t u) {
  __hip_bfloat16 h = *reinterpret_cast<__hip_bfloat16*>(&u);
  return __bfloat162float(h);
}
static __device__ inline void split_bf16(float v, ushort_t& hi, ushort_t& lo) {
  hi = f2bh(v);
  lo = f2bh(v - bh2f(hi));
}

// async global->LDS, 16B per lane (LDS dest = wave-uniform base + lane*16).
static __device__ inline void gload_lds16(const ushort_t* g, ushort_t* l) {
  __builtin_amdgcn_global_load_lds(
      (const __attribute__((address_space(1))) unsigned int*)g,
      (__attribute__((address_space(3))) unsigned int*)l, 16, 0, 0);
}

// ---------------------------------------------------------------------------
// C = A (M x Kd) @ B (Ncol x Kd)^T, row-major, 64x64 tile, 4x4/thread. fp32.
__global__ void gemm_nt_kernel(const float* __restrict__ A, const float* __restrict__ Bm,
                               float* __restrict__ C, int Ncol, int Kd) {
  __shared__ float As[16][68];
  __shared__ float Bs[16][68];
  const int bm = blockIdx.y * 64, bn = blockIdx.x * 64;
  const int tid = threadIdx.x;
  const int tx = tid & 15, ty = tid >> 4;
  float acc[4][4] = {};
  for (int k0 = 0; k0 < Kd; k0 += 16) {
#pragma unroll
    for (int r = 0; r < 4; ++r) {
      const int m = (tid >> 4) + r * 16;
      const int kk = tid & 15;
      const int k = k0 + kk;
      As[kk][m] = (k < Kd) ? A[(size_t)(bm + m) * Kd + k] : 0.f;
      Bs[kk][m] = (k < Kd) ? Bm[(size_t)(bn + m) * Kd + k] : 0.f;
    }
    __syncthreads();
#pragma unroll
    for (int kk = 0; kk < 16; ++kk) {
      float a[4], b[4];
#pragma unroll
      for (int i = 0; i < 4; ++i) a[i] = As[kk][ty * 4 + i];
#pragma unroll
      for (int j = 0; j < 4; ++j) b[j] = Bs[kk][tx * 4 + j];
#pragma unroll
      for (int i = 0; i < 4; ++i)
#pragma unroll
        for (int j = 0; j < 4; ++j) acc[i][j] += a[i] * b[j];
    }
    __syncthreads();
  }
#pragma unroll
  for (int i = 0; i < 4; ++i)
#pragma unroll
    for (int j = 0; j < 4; ++j)
      C[(size_t)(bm + ty * 4 + i) * Ncol + bn + tx * 4 + j] = acc[i][j];
}

// ---------------------------------------------------------------------------
// In-place row softmax(relu(x)) over 1024 cols; also emits bf16 hi/lo split.
__global__ void relu_softmax_kernel(float* __restrict__ S, ushort_t* __restrict__ Sh,
                                    ushort_t* __restrict__ Sl) {
  const int row = blockIdx.x;
  float* r = S + (size_t)row * NN;
  const int tid = threadIdx.x;  // 256
  float v[4];
  float mx = 0.f;
#pragma unroll
  for (int j = 0; j < 4; ++j) {
    float xv = fmaxf(r[tid + j * 256], 0.f);
    v[j] = xv;
    mx = fmaxf(mx, xv);
  }
#pragma unroll
  for (int off = 1; off < 64; off <<= 1) mx = fmaxf(mx, __shfl_xor(mx, off));
  __shared__ float sred[4];
  const int wv = tid >> 6;
  if ((tid & 63) == 0) sred[wv] = mx;
  __syncthreads();
  mx = fmaxf(fmaxf(sred[0], sred[1]), fmaxf(sred[2], sred[3]));
  __syncthreads();
  float s = 0.f;
#pragma unroll
  for (int j = 0; j < 4; ++j) { v[j] = expf(v[j] - mx); s += v[j]; }
#pragma unroll
  for (int off = 1; off < 64; off <<= 1) s += __shfl_xor(s, off);
  if ((tid & 63) == 0) sred[wv] = s;
  __syncthreads();
  s = sred[0] + sred[1] + sred[2] + sred[3];
  const float inv = 1.f / s;
#pragma unroll
  for (int j = 0; j < 4; ++j) {
    const float sv = v[j] * inv;
    const size_t e = (size_t)row * NN + tid + j * 256;
    r[tid + j * 256] = sv;
    ushort_t hi, lo;
    split_bf16(sv, hi, lo);
    Sh[e] = hi;
    Sl[e] = lo;
  }
}

// ---------------------------------------------------------------------------
// ST = S^T, bf16 hi/lo split. LDS-tiled 64x64, both sides coalesced.
__global__ void st_kernel(const float* __restrict__ S, ushort_t* __restrict__ STh,
                          ushort_t* __restrict__ STl) {
  __shared__ float tile[64][65];
  const int bx = blockIdx.x * 64, by = blockIdx.y * 64;
  const int tid = threadIdx.x;
  const int cl = tid & 63, rq = tid >> 6;
#pragma unroll
  for (int r = 0; r < 16; ++r) {
    const int rr = rq + r * 4;
    tile[rr][cl] = S[(size_t)(by + rr) * NN + bx + cl];
  }
  __syncthreads();
#pragma unroll
  for (int r = 0; r < 16; ++r) {
    const int rr = rq + r * 4;
    const float v = tile[cl][rr];  // = S[by+cl][bx+rr]
    ushort_t hi, lo;
    split_bf16(v, hi, lo);
    STh[(size_t)(bx + rr) * NN + by + cl] = hi;
    STl[(size_t)(bx + rr) * NN + by + cl] = lo;
  }
}

// ---------------------------------------------------------------------------
// M = 2*S@S on MFMA, bf16x3 (A=S1 hi/lo, B=ST hi/lo), out single bf16 plane.
// (The -I of the Chebyshev support is applied exactly in the graph epilogue.)
// Tile 32n x 64j, BK=64, grid (16,32) = 512 blocks. XOR-swizzled LDS.
__global__ void cheb_mfma_kernel(const ushort_t* __restrict__ S1h,
                                 const ushort_t* __restrict__ S1l,
                                 const ushort_t* __restrict__ STh,
                                 const ushort_t* __restrict__ STl,
                                 ushort_t* __restrict__ Mh) {
  __shared__ __align__(16) ushort_t sA[2 * 32 * 64];  // 8 KB
  __shared__ __align__(16) ushort_t sB[2 * 64 * 64];  // 16 KB
  const int bj = blockIdx.x * 64, bn = blockIdx.y * 32;
  const int tid = threadIdx.x;
  const int w = tid >> 6, lane = tid & 63;
  const int row = lane & 15, kq = lane >> 4;
  const int srow8 = lane >> 3, sslot = lane & 7;
  f32x4 acc[2] = {};
  for (int k0 = 0; k0 < NN; k0 += 64) {
#pragma unroll
    for (int t2 = 0; t2 < 2; ++t2) {  // A: 8 chunks, wave stages 2
      const int c = w + t2 * 4, p = c >> 2, i = c & 3;
      const int grow = i * 8 + srow8;
      const int gch = sslot ^ (grow & 7);
      const ushort_t* src = (p ? S1l : S1h) + (size_t)(bn + grow) * NN + k0 + gch * 8;
      gload_lds16(src, sA + p * 2048 + i * 512);
    }
#pragma unroll
    for (int t2 = 0; t2 < 4; ++t2) {  // B: 16 chunks, wave stages 4
      const int c2 = w + t2 * 4, p = c2 >> 3, rb = c2 & 7;
      const int grow = rb * 8 + srow8;
      const int gch = sslot ^ (grow & 7);
      const ushort_t* src = (p ? STl : STh) + (size_t)(bj + grow) * NN + k0 + gch * 8;
      gload_lds16(src, sB + p * 4096 + rb * 512);
    }
    __syncthreads();
#pragma unroll
    for (int kk = 0; kk < 2; ++kk) {
      const int rB = w * 16 + row;
      const int chB = ((kk * 4 + kq) ^ (rB & 7)) * 8;
      const short8 bh = *(const short8*)(sB + rB * 64 + chB);
      const short8 bl = *(const short8*)(sB + 4096 + rB * 64 + chB);
#pragma unroll
      for (int mt = 0; mt < 2; ++mt) {
        const int rA = mt * 16 + row;
        const int chA = ((kk * 4 + kq) ^ (rA & 7)) * 8;
        const short8 ah = *(const short8*)(sA + rA * 64 + chA);
        const short8 al = *(const short8*)(sA + 2048 + rA * 64 + chA);
        acc[mt] = __builtin_amdgcn_mfma_f32_16x16x32_bf16(ah, bh, acc[mt], 0, 0, 0);
        acc[mt] = __builtin_amdgcn_mfma_f32_16x16x32_bf16(ah, bl, acc[mt], 0, 0, 0);
        acc[mt] = __builtin_amdgcn_mfma_f32_16x16x32_bf16(al, bh, acc[mt], 0, 0, 0);
      }
    }
    __syncthreads();
  }
  const int j = bj + w * 16 + row;
#pragma unroll
  for (int mt = 0; mt < 2; ++mt) {
    const int node0 = bn + mt * 16 + kq * 4;
#pragma unroll
    for (int r = 0; r < 4; ++r)
      Mh[(size_t)(node0 + r) * NN + j] = f2bh(2.f * acc[mt][r]);
  }
}

// ---------------------------------------------------------------------------
// Wt[no][k] = W[k][no], bf16 hi/lo, zero-padded to [NOP][KP].
__global__ void wt_kernel(const float* __restrict__ W, ushort_t* __restrict__ Wth,
                          ushort_t* __restrict__ Wtl, int KK, int NO, int KP, int NOP) {
  const int e = blockIdx.x * 256 + threadIdx.x;
  if (e >= NOP * KP) return;
  const int no = e / KP, k = e - no * KP;
  const float v = (no < NO && k < KK) ? W[(size_t)k * NO + no] : 0.f;
  ushort_t hi, lo;
  split_bf16(v, hi, lo);
  Wth[e] = hi;
  Wtl[e] = lo;
}

// ---------------------------------------------------------------------------
// prep: build cell input on the fly; write Ag (idx-major bf16, for dense)
// and XT (j-major transpose bf16, for graph B-operand).
// MODE 0: enc build [x_t, h]; 1: enc cand [x_t, z*h];
//      2: dec build [go, yc, h]; 3: dec cand [go, yc, z*h].
template <int C, int KP, int MODE>
__global__ void prep_kernel(const float* __restrict__ src0, const float* __restrict__ src1,
                            const float* __restrict__ hst, const float* __restrict__ zr,
                            ushort_t* __restrict__ Agh, ushort_t* __restrict__ XTh, int t) {
  __shared__ float tile[64][65];
  const int bj = blockIdx.x * 64, bn = blockIdx.y * 64;
  const int tid = threadIdx.x;
  const int jl = tid & 63, nq = tid >> 6;
  const int j = bj + jl;
  const int b = j / C, c = j - b * C;
#pragma unroll
  for (int r = 0; r < 16; ++r) {
    const int node = bn + nq + r * 4;
    const int idx = node * 64 + b;
    float v;
    if (MODE == 0) {
      v = (c == 0) ? src0[((size_t)b * T_ + t) * NN + node]
                   : hst[(size_t)idx * 64 + (c - 1)];
    } else if (MODE == 1) {
      v = (c == 0) ? src0[((size_t)b * T_ + t) * NN + node]
                   : zr[(size_t)idx * 128 + (c - 1)] * hst[(size_t)idx * 64 + (c - 1)];
    } else if (MODE == 2) {
      v = (c == 0) ? src0[idx]
        : (c == 1) ? src1[((size_t)b * HOR_ + t) * NN + node]
                   : hst[(size_t)idx * 96 + (c - 2)];
    } else {
      v = (c == 0) ? src0[idx]
        : (c == 1) ? src1[((size_t)b * HOR_ + t) * NN + node]
                   : zr[(size_t)idx * 192 + (c - 2)] * hst[(size_t)idx * 96 + (c - 2)];
    }
    tile[nq + r * 4][jl] = v;
    Agh[(size_t)idx * KP + c] = f2bh(v);
  }
  __syncthreads();
  const int nl = tid & 63, jq = tid >> 6;
#pragma unroll
  for (int r = 0; r < 16; ++r) {
    const int jj = bj + jq + r * 4;
    XTh[(size_t)jj * NN + bn + nl] = f2bh(tile[nl][jq + r * 4]);
  }
}

// ---------------------------------------------------------------------------
// Graph conv: 32 nodes x 128 j, BK=64, XOR-swizzled LDS.
// A planes = {S1 bf16, M bf16}; B = X bf16. Wave w: plane s=w>>1, jhalf.
// slice1 = S1@X; slice2 = M@X - X (exact -I in fp32 epilogue).
template <int C, int KP>
__global__ void graph_mfma_kernel(const ushort_t* __restrict__ S1h,
                                  const ushort_t* __restrict__ Mh,
                                  const ushort_t* __restrict__ XTh,
                                  ushort_t* __restrict__ Agh) {
  constexpr int W = B_ * C;
  const int bj = blockIdx.x * 128;
  if (bj >= W) return;  // padding block (keeps gridDim.x % 8 == 0)
  __shared__ __align__(16) ushort_t sA[2 * 32 * 64];   // 8 KB
  __shared__ __align__(16) ushort_t sB[128 * 64];      // 16 KB
  const int bn = blockIdx.y * 32;
  const int tid = threadIdx.x;
  const int w = tid >> 6, lane = tid & 63;
  const int row = lane & 15, kq = lane >> 4;
  const int srow8 = lane >> 3;   // row within 8-row stage chunk
  const int sslot = lane & 7;    // LDS 16B slot within row

  const int s = w >> 1;
  const int jhalf = (w & 1) * 64;
  const ushort_t* A_lds = sA + s * (32 * 64);

  f32x4 acc[2][4] = {};
  for (int k0 = 0; k0 < NN; k0 += 64) {
    // 24 stage chunks of 8 rows; wave w stages chunks w, w+4, ..., w+20.
#pragma unroll
    for (int t2 = 0; t2 < 6; ++t2) {
      const int cid = w + t2 * 4;
      if (cid < 8) {  // A: plane p (0=S1,1=M), row-block i
        const int p = cid >> 2, i = cid & 3;
        const int grow = i * 8 + srow8;
        const int gch = sslot ^ (grow & 7);
        const ushort_t* g = (p ? Mh : S1h) + (size_t)(bn + grow) * NN + k0 + gch * 8;
        gload_lds16(g, sA + p * (32 * 64) + i * 512);
      } else {        // B: row-block rb of 16
        const int rb = cid - 8;
        const int brow = rb * 8 + srow8;
        const int gch = sslot ^ (brow & 7);
        const ushort_t* g = XTh + (size_t)(bj + brow) * NN + k0 + gch * 8;
        gload_lds16(g, sB + rb * 512);
      }
    }
    __syncthreads();
    short8 a[2][2];  // [kk][mt]
#pragma unroll
    for (int kk = 0; kk < 2; ++kk)
#pragma unroll
      for (int mt = 0; mt < 2; ++mt) {
        const int r = mt * 16 + row;
        const int chunk = (kk * 4 + kq) ^ (r & 7);
        a[kk][mt] = *(const short8*)(A_lds + r * 64 + chunk * 8);
      }
#pragma unroll
    for (int nt = 0; nt < 4; ++nt) {
#pragma unroll
      for (int kk = 0; kk < 2; ++kk) {
        const int r = jhalf + nt * 16 + row;
        const int chunk = (kk * 4 + kq) ^ (r & 7);
        const short8 bh = *(const short8*)(sB + r * 64 + chunk * 8);
#pragma unroll
        for (int mt = 0; mt < 2; ++mt)
          acc[mt][nt] = __builtin_amdgcn_mfma_f32_16x16x32_bf16(a[kk][mt], bh, acc[mt][nt], 0, 0, 0);
      }
    }
    __syncthreads();
  }
  // D mapping: col (=j) = lane&15, row (=node) = (lane>>4)*4 + reg.
  const int slice_off = (s + 1) * C;
#pragma unroll
  for (int nt = 0; nt < 4; ++nt) {
    const int j = bj + jhalf + nt * 16 + row;
    if (j < W) {
      const int b = j / C, c = j - b * C;
      const size_t coloff = (size_t)(slice_off + c);
#pragma unroll
      for (int mt = 0; mt < 2; ++mt) {
        const int node0 = bn + mt * 16 + kq * 4;
        float sub[4] = {0.f, 0.f, 0.f, 0.f};
        if (s == 1) {  // exact -X for the Chebyshev -I term
          const ushort_t* xp = XTh + (size_t)j * NN + node0;
#pragma unroll
          for (int r = 0; r < 4; ++r) sub[r] = bh2f(xp[r]);
        }
#pragma unroll
        for (int r = 0; r < 4; ++r) {
          const size_t a = (size_t)((node0 + r) * 64 + b) * KP + coloff;
          Agh[a] = f2bh(acc[mt][nt][r] - sub[r]);
        }
      }
    }
  }
}

// ---------------------------------------------------------------------------
// Dense on MFMA, T2-swizzled: A bf16 x W (hi+lo) -> 2 MFMAs/pair.
// 128 rows x NO cols. MODE 0: sigmoid -> zr. MODE 1: fused GRU combine.
template <int KP, int NO, int NOP, int MODE, int H>
__global__ void dense_mfma_kernel(const ushort_t* __restrict__ Agh,
                                  const ushort_t* __restrict__ Wth,
                                  const ushort_t* __restrict__ Wtl,
                                  const float* __restrict__ bias,
                                  float* __restrict__ outp,
                                  const float* __restrict__ zrin) {
  constexpr int NFR = NO / 16;
  __shared__ __align__(16) ushort_t sAh[128 * 32];
  __shared__ __align__(16) ushort_t sBh[NOP * 32];
  __shared__ __align__(16) ushort_t sBl[NOP * 32];
  const int row0 = blockIdx.x * 128;
  const int tid = threadIdx.x;
  const int w = tid >> 6, lane = tid & 63;
  const int col16 = lane & 15, four = lane >> 4;
  const int srow = lane >> 2;
  const int scol = ((lane & 3) ^ ((srow >> 1) & 3)) * 8;  // pre-swizzled source
  const int kqs = (four ^ ((col16 >> 1) & 3)) * 8;        // swizzled read slot
  f32x4 acc[2][NFR] = {};
  for (int k0 = 0; k0 < KP; k0 += 32) {
    for (int c = w; c < 8; c += 4) {
      const size_t g = (size_t)(row0 + c * 16 + srow) * KP + k0 + scol;
      gload_lds16(Agh + g, sAh + c * 512);
    }
    for (int c = w; c < NOP / 16; c += 4) {
      const size_t g = (size_t)(c * 16 + srow) * KP + k0 + scol;
      gload_lds16(Wth + g, sBh + c * 512);
      gload_lds16(Wtl + g, sBl + c * 512);
    }
    __syncthreads();
    short8 ah[2];
#pragma unroll
    for (int mt = 0; mt < 2; ++mt) {
      const int r = (w * 32 + mt * 16 + col16) * 32 + kqs;
      ah[mt] = *(const short8*)(sAh + r);
    }
#pragma unroll
    for (int nt = 0; nt < NFR; ++nt) {
      const int r = (nt * 16 + col16) * 32 + kqs;
      const short8 bh = *(const short8*)(sBh + r);
      const short8 bl = *(const short8*)(sBl + r);
#pragma unroll
      for (int mt = 0; mt < 2; ++mt) {
        acc[mt][nt] = __builtin_amdgcn_mfma_f32_16x16x32_bf16(ah[mt], bh, acc[mt][nt], 0, 0, 0);
        acc[mt][nt] = __builtin_amdgcn_mfma_f32_16x16x32_bf16(ah[mt], bl, acc[mt][nt], 0, 0, 0);
      }
    }
    __syncthreads();
  }
#pragma unroll
  for (int nt = 0; nt < NFR; ++nt) {
    const int col = nt * 16 + col16;
    const float bv = bias[col];
#pragma unroll
    for (int mt = 0; mt < 2; ++mt) {
      const int rbase = row0 + w * 32 + mt * 16 + four * 4;
#pragma unroll
      for (int r = 0; r < 4; ++r) {
        const int row = rbase + r;
        const float v = acc[mt][nt][r] + bv;
        if (MODE == 0) {
          outp[(size_t)row * NO + col] = 1.f / (1.f + expf(-v));
        } else {
          const float rg = zrin[(size_t)row * (2 * H) + H + col];
          const float hv = outp[(size_t)row * H + col];
          outp[(size_t)row * H + col] = rg * hv + (1.f - rg) * tanhf(v);
        }
      }
    }
  }
}

// ---------------------------------------------------------------------------
// attention + prototype + W_E + h0 build, fused. One thread per (n,b).
__global__ void attn_kernel(const float* __restrict__ h, const float* __restrict__ Wq,
                            const float* __restrict__ Mem, const float* __restrict__ FCE,
                            float* __restrict__ hB, float* __restrict__ WE) {
  __shared__ float sWq[64 * 32];
  __shared__ float sM[10 * 32];
  __shared__ float sF[32 * 8];
  const int tid = threadIdx.x;
  for (int i = tid; i < 64 * 32; i += 256) sWq[i] = Wq[i];
  for (int i = tid; i < 10 * 32; i += 256) sM[i] = Mem[i];
  for (int i = tid; i < 32 * 8; i += 256) sF[i] = FCE[i];
  __syncthreads();
  const int idx = blockIdx.x * 256 + tid;
  const float* hp = h + (size_t)idx * 64;
  float* hd = hB + (size_t)idx * 96;
  float q[32] = {};
  for (int i0 = 0; i0 < 16; ++i0) {
    const float4 h4 = *(const float4*)(hp + i0 * 4);
#pragma unroll
    for (int jj = 0; jj < 4; ++jj) {
      const float hv = ((const float*)&h4)[jj];
      hd[i0 * 4 + jj] = hv;  // h0 = [h, proto]
      const int i = i0 * 4 + jj;
#pragma unroll
      for (int c = 0; c < 32; ++c) q[c] += hv * sWq[i * 32 + c];
    }
  }
  float lg[10];
  float mx = -1e30f;
#pragma unroll
  for (int m = 0; m < 10; ++m) {
    float s = 0.f;
#pragma unroll
    for (int c = 0; c < 32; ++c) s += q[c] * sM[m * 32 + c];
    lg[m] = s;
    mx = fmaxf(mx, s);
  }
  float den = 0.f;
#pragma unroll
  for (int m = 0; m < 10; ++m) { lg[m] = expf(lg[m] - mx); den += lg[m]; }
  const float inv = 1.f / den;
  float p[32] = {};
#pragma unroll
  for (int m = 0; m < 10; ++m) {
    const float a = lg[m] * inv;
#pragma unroll
    for (int c = 0; c < 32; ++c) p[c] += a * sM[m * 32 + c];
  }
#pragma unroll
  for (int c = 0; c < 32; ++c) hd[64 + c] = p[c];
  float* wd = WE + (size_t)idx * 8;
#pragma unroll
  for (int e = 0; e < 8; ++e) {
    float s = 0.f;
#pragma unroll
    for (int c = 0; c < 32; ++c) s += p[c] * sF[c * 8 + e];
    wd[e] = s;
  }
}

__global__ void proj_kernel(const float* __restrict__ h, const float* __restrict__ pW,
                            const float* __restrict__ pb, float* __restrict__ go,
                            float* __restrict__ out, int t) {
  __shared__ float sW[96];
  if (threadIdx.x < 96) sW[threadIdx.x] = pW[threadIdx.x];
  __syncthreads();
  const int idx = blockIdx.x * 256 + threadIdx.x;
  const float* hp = h + (size_t)idx * 96;
  float acc = pb[0];
  for (int j0 = 0; j0 < 24; ++j0) {
    const float4 h4 = *(const float4*)(hp + j0 * 4);
    acc += h4.x * sW[j0 * 4] + h4.y * sW[j0 * 4 + 1] + h4.z * sW[j0 * 4 + 2] + h4.w * sW[j0 * 4 + 3];
  }
  go[idx] = acc;
  const int n = idx >> 6, b = idx & 63;
  out[((size_t)b * HOR_ + t) * NN + n] = acc;
}

// ---------------------------------------------------------------------------
extern "C" void kernel_launch(void* const* d_in, const int* in_sizes, int n_in,
                              void* d_out, int out_size, void* d_ws, size_t ws_size,
                              hipStream_t stream) {
  const float* x    = (const float*)d_in[0];
  const float* ycov = (const float*)d_in[1];
  const float* emb  = (const float*)d_in[2];
  const float* egW  = (const float*)d_in[3];
  const float* egb  = (const float*)d_in[4];
  const float* euW  = (const float*)d_in[5];
  const float* eub  = (const float*)d_in[6];
  const float* Mem  = (const float*)d_in[7];
  const float* Wq   = (const float*)d_in[8];
  const float* FCE  = (const float*)d_in[9];
  const float* dgW  = (const float*)d_in[10];
  const float* dgb  = (const float*)d_in[11];
  const float* duW  = (const float*)d_in[12];
  const float* dub  = (const float*)d_in[13];
  const float* pW   = (const float*)d_in[14];
  const float* pb   = (const float*)d_in[15];
  float* out = (float*)d_out;

  char* w = (char*)d_ws;
  auto alloc = [&](size_t bytes) {
    void* p = (void*)w;
    w += (bytes + 255) & ~(size_t)255;
    return p;
  };
  float* S1  = (float*)alloc((size_t)NN * NN * 4);
  float* zr  = (float*)alloc((size_t)NN * B_ * 192 * 4);
  float* hA  = (float*)alloc((size_t)NN * B_ * 64 * 4);
  float* hB  = (float*)alloc((size_t)NN * B_ * 96 * 4);
  float* go  = (float*)alloc((size_t)NN * B_ * 4);
  float* WE  = (float*)alloc((size_t)NN * B_ * 8 * 4);
  ushort_t* S1h = (ushort_t*)alloc((size_t)NN * NN * 2);
  ushort_t* S1l = (ushort_t*)alloc((size_t)NN * NN * 2);
  ushort_t* Mh  = (ushort_t*)alloc((size_t)NN * NN * 2);
  ushort_t* STh = (ushort_t*)alloc((size_t)NN * NN * 2);
  ushort_t* STl = (ushort_t*)alloc((size_t)NN * NN * 2);
  ushort_t* XTh = (ushort_t*)alloc((size_t)B_ * 98 * NN * 2);
  ushort_t* Agh = (ushort_t*)alloc((size_t)NN * B_ * 320 * 2);
  ushort_t* WtegH = (ushort_t*)alloc(128 * 224 * 2);
  ushort_t* WtegL = (ushort_t*)alloc(128 * 224 * 2);
  ushort_t* WteuH = (ushort_t*)alloc(64 * 224 * 2);
  ushort_t* WteuL = (ushort_t*)alloc(64 * 224 * 2);
  ushort_t* WtdgH = (ushort_t*)alloc(192 * 320 * 2);
  ushort_t* WtdgL = (ushort_t*)alloc(192 * 320 * 2);
  ushort_t* WtduH = (ushort_t*)alloc(128 * 320 * 2);
  ushort_t* WtduL = (ushort_t*)alloc(128 * 320 * 2);
  (void)ws_size; (void)in_sizes; (void)n_in; (void)out_size;

  const dim3 blk(256);

  // ---- weight transposes + buffer init (pad regions must be defined) ----
  wt_kernel<<<(128 * 224 + 255) / 256, blk, 0, stream>>>(egW, WtegH, WtegL, 195, 128, 224, 128);
  wt_kernel<<<(64 * 224 + 255) / 256, blk, 0, stream>>>(euW, WteuH, WteuL, 195, 64, 224, 64);
  wt_kernel<<<(192 * 320 + 255) / 256, blk, 0, stream>>>(dgW, WtdgH, WtdgL, 294, 192, 320, 192);
  wt_kernel<<<(128 * 320 + 255) / 256, blk, 0, stream>>>(duW, WtduH, WtduL, 294, 96, 320, 128);
  hipMemsetAsync(Agh, 0, (size_t)NN * B_ * 320 * 2, stream);
  hipMemsetAsync(hA, 0, (size_t)NN * B_ * 64 * 4, stream);
  hipMemsetAsync(go, 0, (size_t)NN * B_ * 4, stream);

  // ---- encoder supports ----
  gemm_nt_kernel<<<dim3(16, 16), blk, 0, stream>>>(emb, emb, S1, NN, 8);
  relu_softmax_kernel<<<NN, blk, 0, stream>>>(S1, S1h, S1l);
  st_kernel<<<dim3(16, 16), blk, 0, stream>>>(S1, STh, STl);
  cheb_mfma_kernel<<<dim3(16, 32), blk, 0, stream>>>(S1h, S1l, STh, STl, Mh);

  // ---- encoder scan ----  (W_enc = 4160; live j-tiles 33, padded to 40)
  for (int t = 0; t < T_; ++t) {
    prep_kernel<65, 224, 0><<<dim3(65, 16), blk, 0, stream>>>(x, nullptr, hA, nullptr, Agh, XTh, t);
    graph_mfma_kernel<65, 224><<<dim3(40, 32), blk, 0, stream>>>(S1h, Mh, XTh, Agh);
    dense_mfma_kernel<224, 128, 128, 0, 64><<<512, blk, 0, stream>>>(Agh, WtegH, WtegL, egb, zr, nullptr);
    prep_kernel<65, 224, 1><<<dim3(65, 16), blk, 0, stream>>>(x, nullptr, hA, zr, Agh, XTh, t);
    graph_mfma_kernel<65, 224><<<dim3(40, 32), blk, 0, stream>>>(S1h, Mh, XTh, Agh);
    dense_mfma_kernel<224, 64, 64, 1, 64><<<512, blk, 0, stream>>>(Agh, WteuH, WteuL, eub, hA, zr);
  }

  // ---- attention / memory / decoder supports ----
  attn_kernel<<<256, blk, 0, stream>>>(hA, Wq, Mem, FCE, hB, WE);
  gemm_nt_kernel<<<dim3(16, 16), blk, 0, stream>>>(WE, WE, S1, NN, 512);
  relu_softmax_kernel<<<NN, blk, 0, stream>>>(S1, S1h, S1l);
  st_kernel<<<dim3(16, 16), blk, 0, stream>>>(S1, STh, STl);
  cheb_mfma_kernel<<<dim3(16, 32), blk, 0, stream>>>(S1h, S1l, STh, STl, Mh);

  // ---- decoder scan ----  (W_dec = 6272; live j-tiles 49, padded to 56)
  for (int t = 0; t < HOR_; ++t) {
    prep_kernel<98, 320, 2><<<dim3(98, 16), blk, 0, stream>>>(go, ycov, hB, nullptr, Agh, XTh, t);
    graph_mfma_kernel<98, 320><<<dim3(56, 32), blk, 0, stream>>>(S1h, Mh, XTh, Agh);
    dense_mfma_kernel<320, 192, 192, 0, 96><<<512, blk, 0, stream>>>(Agh, WtdgH, WtdgL, dgb, zr, nullptr);
    prep_kernel<98, 320, 3><<<dim3(98, 16), blk, 0, stream>>>(go, ycov, hB, zr, Agh, XTh, t);
    graph_mfma_kernel<98, 320><<<dim3(56, 32), blk, 0, stream>>>(S1h, Mh, XTh, Agh);
    dense_mfma_kernel<320, 96, 128, 1, 96><<<512, blk, 0, stream>>>(Agh, WtduH, WtduL, dub, hB, zr);
    proj_kernel<<<256, blk, 0, stream>>>(hB, pW, pb, go, out, t);
  }
}

// Round 15
// 3859.821 us; speedup vs baseline: 2.0658x; 1.0138x over previous
//
#include <hip/hip_runtime.h>
#include <hip/hip_bf16.h>

// MMGCRN on MFMA. Graph: S(bf16) x X(bf16), slice2 via M=2S^2 (bf16) with
// exact -X in fp32 epilogue. Dense: A(bf16) x W(bf16) -> 1 MFMA/pair.
// cheb bf16x3 -> Mh. 32nx128j BK=64 graph tile, XCD-stable grids,
// XOR-swizzled LDS.
// B=64, T=12, N=1024, HOR=12, RNN=64, DEC=96, K=3.
constexpr int B_ = 64, T_ = 12, NN = 1024, HOR_ = 12;

typedef __attribute__((ext_vector_type(8))) short short8;   // 8 bf16 (4 VGPRs)
typedef __attribute__((ext_vector_type(4))) float f32x4;    // MFMA C/D frag
typedef unsigned short ushort_t;

static __device__ inline ushort_t f2bh(float v) {
  __hip_bfloat16 h = __float2bfloat16(v);
  return *reinterpret_cast<ushort_t*>(&h);
}
static __device__ inline float bh2f(ushort_t u) {
  __hip_bfloat16 h = *reinterpret_cast<__hip_bfloat16*>(&u);
  return __bfloat162float(h);
}
static __device__ inline void split_bf16(float v, ushort_t& hi, ushort_t& lo) {
  hi = f2bh(v);
  lo = f2bh(v - bh2f(hi));
}

// async global->LDS, 16B per lane (LDS dest = wave-uniform base + lane*16).
static __device__ inline void gload_lds16(const ushort_t* g, ushort_t* l) {
  __builtin_amdgcn_global_load_lds(
      (const __attribute__((address_space(1))) unsigned int*)g,
      (__attribute__((address_space(3))) unsigned int*)l, 16, 0, 0);
}

// ---------------------------------------------------------------------------
// C = A (M x Kd) @ B (Ncol x Kd)^T, row-major, 64x64 tile, 4x4/thread. fp32.
__global__ void gemm_nt_kernel(const float* __restrict__ A, const float* __restrict__ Bm,
                               float* __restrict__ C, int Ncol, int Kd) {
  __shared__ float As[16][68];
  __shared__ float Bs[16][68];
  const int bm = blockIdx.y * 64, bn = blockIdx.x * 64;
  const int tid = threadIdx.x;
  const int tx = tid & 15, ty = tid >> 4;
  float acc[4][4] = {};
  for (int k0 = 0; k0 < Kd; k0 += 16) {
#pragma unroll
    for (int r = 0; r < 4; ++r) {
      const int m = (tid >> 4) + r * 16;
      const int kk = tid & 15;
      const int k = k0 + kk;
      As[kk][m] = (k < Kd) ? A[(size_t)(bm + m) * Kd + k] : 0.f;
      Bs[kk][m] = (k < Kd) ? Bm[(size_t)(bn + m) * Kd + k] : 0.f;
    }
    __syncthreads();
#pragma unroll
    for (int kk = 0; kk < 16; ++kk) {
      float a[4], b[4];
#pragma unroll
      for (int i = 0; i < 4; ++i) a[i] = As[kk][ty * 4 + i];
#pragma unroll
      for (int j = 0; j < 4; ++j) b[j] = Bs[kk][tx * 4 + j];
#pragma unroll
      for (int i = 0; i < 4; ++i)
#pragma unroll
        for (int j = 0; j < 4; ++j) acc[i][j] += a[i] * b[j];
    }
    __syncthreads();
  }
#pragma unroll
  for (int i = 0; i < 4; ++i)
#pragma unroll
    for (int j = 0; j < 4; ++j)
      C[(size_t)(bm + ty * 4 + i) * Ncol + bn + tx * 4 + j] = acc[i][j];
}

// ---------------------------------------------------------------------------
// In-place row softmax(relu(x)) over 1024 cols; also emits bf16 hi/lo split.
__global__ void relu_softmax_kernel(float* __restrict__ S, ushort_t* __restrict__ Sh,
                                    ushort_t* __restrict__ Sl) {
  const int row = blockIdx.x;
  float* r = S + (size_t)row * NN;
  const int tid = threadIdx.x;  // 256
  float v[4];
  float mx = 0.f;
#pragma unroll
  for (int j = 0; j < 4; ++j) {
    float xv = fmaxf(r[tid + j * 256], 0.f);
    v[j] = xv;
    mx = fmaxf(mx, xv);
  }
#pragma unroll
  for (int off = 1; off < 64; off <<= 1) mx = fmaxf(mx, __shfl_xor(mx, off));
  __shared__ float sred[4];
  const int wv = tid >> 6;
  if ((tid & 63) == 0) sred[wv] = mx;
  __syncthreads();
  mx = fmaxf(fmaxf(sred[0], sred[1]), fmaxf(sred[2], sred[3]));
  __syncthreads();
  float s = 0.f;
#pragma unroll
  for (int j = 0; j < 4; ++j) { v[j] = expf(v[j] - mx); s += v[j]; }
#pragma unroll
  for (int off = 1; off < 64; off <<= 1) s += __shfl_xor(s, off);
  if ((tid & 63) == 0) sred[wv] = s;
  __syncthreads();
  s = sred[0] + sred[1] + sred[2] + sred[3];
  const float inv = 1.f / s;
#pragma unroll
  for (int j = 0; j < 4; ++j) {
    const float sv = v[j] * inv;
    const size_t e = (size_t)row * NN + tid + j * 256;
    r[tid + j * 256] = sv;
    ushort_t hi, lo;
    split_bf16(sv, hi, lo);
    Sh[e] = hi;
    Sl[e] = lo;
  }
}

// ---------------------------------------------------------------------------
// ST = S^T, bf16 hi/lo split. LDS-tiled 64x64, both sides coalesced.
__global__ void st_kernel(const float* __restrict__ S, ushort_t* __restrict__ STh,
                          ushort_t* __restrict__ STl) {
  __shared__ float tile[64][65];
  const int bx = blockIdx.x * 64, by = blockIdx.y * 64;
  const int tid = threadIdx.x;
  const int cl = tid & 63, rq = tid >> 6;
#pragma unroll
  for (int r = 0; r < 16; ++r) {
    const int rr = rq + r * 4;
    tile[rr][cl] = S[(size_t)(by + rr) * NN + bx + cl];
  }
  __syncthreads();
#pragma unroll
  for (int r = 0; r < 16; ++r) {
    const int rr = rq + r * 4;
    const float v = tile[cl][rr];  // = S[by+cl][bx+rr]
    ushort_t hi, lo;
    split_bf16(v, hi, lo);
    STh[(size_t)(bx + rr) * NN + by + cl] = hi;
    STl[(size_t)(bx + rr) * NN + by + cl] = lo;
  }
}

// ---------------------------------------------------------------------------
// M = 2*S@S on MFMA, bf16x3 (A=S1 hi/lo, B=ST hi/lo), out single bf16 plane.
// (The -I of the Chebyshev support is applied exactly in the graph epilogue.)
// Tile 32n x 64j, BK=64, grid (16,32) = 512 blocks. XOR-swizzled LDS.
__global__ void cheb_mfma_kernel(const ushort_t* __restrict__ S1h,
                                 const ushort_t* __restrict__ S1l,
                                 const ushort_t* __restrict__ STh,
                                 const ushort_t* __restrict__ STl,
                                 ushort_t* __restrict__ Mh) {
  __shared__ __align__(16) ushort_t sA[2 * 32 * 64];  // 8 KB
  __shared__ __align__(16) ushort_t sB[2 * 64 * 64];  // 16 KB
  const int bj = blockIdx.x * 64, bn = blockIdx.y * 32;
  const int tid = threadIdx.x;
  const int w = tid >> 6, lane = tid & 63;
  const int row = lane & 15, kq = lane >> 4;
  const int srow8 = lane >> 3, sslot = lane & 7;
  f32x4 acc[2] = {};
  for (int k0 = 0; k0 < NN; k0 += 64) {
#pragma unroll
    for (int t2 = 0; t2 < 2; ++t2) {  // A: 8 chunks, wave stages 2
      const int c = w + t2 * 4, p = c >> 2, i = c & 3;
      const int grow = i * 8 + srow8;
      const int gch = sslot ^ (grow & 7);
      const ushort_t* src = (p ? S1l : S1h) + (size_t)(bn + grow) * NN + k0 + gch * 8;
      gload_lds16(src, sA + p * 2048 + i * 512);
    }
#pragma unroll
    for (int t2 = 0; t2 < 4; ++t2) {  // B: 16 chunks, wave stages 4
      const int c2 = w + t2 * 4, p = c2 >> 3, rb = c2 & 7;
      const int grow = rb * 8 + srow8;
      const int gch = sslot ^ (grow & 7);
      const ushort_t* src = (p ? STl : STh) + (size_t)(bj + grow) * NN + k0 + gch * 8;
      gload_lds16(src, sB + p * 4096 + rb * 512);
    }
    __syncthreads();
#pragma unroll
    for (int kk = 0; kk < 2; ++kk) {
      const int rB = w * 16 + row;
      const int chB = ((kk * 4 + kq) ^ (rB & 7)) * 8;
      const short8 bh = *(const short8*)(sB + rB * 64 + chB);
      const short8 bl = *(const short8*)(sB + 4096 + rB * 64 + chB);
#pragma unroll
      for (int mt = 0; mt < 2; ++mt) {
        const int rA = mt * 16 + row;
        const int chA = ((kk * 4 + kq) ^ (rA & 7)) * 8;
        const short8 ah = *(const short8*)(sA + rA * 64 + chA);
        const short8 al = *(const short8*)(sA + 2048 + rA * 64 + chA);
        acc[mt] = __builtin_amdgcn_mfma_f32_16x16x32_bf16(ah, bh, acc[mt], 0, 0, 0);
        acc[mt] = __builtin_amdgcn_mfma_f32_16x16x32_bf16(ah, bl, acc[mt], 0, 0, 0);
        acc[mt] = __builtin_amdgcn_mfma_f32_16x16x32_bf16(al, bh, acc[mt], 0, 0, 0);
      }
    }
    __syncthreads();
  }
  const int j = bj + w * 16 + row;
#pragma unroll
  for (int mt = 0; mt < 2; ++mt) {
    const int node0 = bn + mt * 16 + kq * 4;
#pragma unroll
    for (int r = 0; r < 4; ++r)
      Mh[(size_t)(node0 + r) * NN + j] = f2bh(2.f * acc[mt][r]);
  }
}

// ---------------------------------------------------------------------------
// Wt[no][k] = W[k][no], plain bf16, zero-padded to [NOP][KP].
__global__ void wt_kernel(const float* __restrict__ W, ushort_t* __restrict__ Wth,
                          int KK, int NO, int KP, int NOP) {
  const int e = blockIdx.x * 256 + threadIdx.x;
  if (e >= NOP * KP) return;
  const int no = e / KP, k = e - no * KP;
  const float v = (no < NO && k < KK) ? W[(size_t)k * NO + no] : 0.f;
  Wth[e] = f2bh(v);
}

// ---------------------------------------------------------------------------
// prep: build cell input on the fly; write Ag (idx-major bf16, for dense)
// and XT (j-major transpose bf16, for graph B-operand).
// MODE 0: enc build [x_t, h]; 1: enc cand [x_t, z*h];
//      2: dec build [go, yc, h]; 3: dec cand [go, yc, z*h].
template <int C, int KP, int MODE>
__global__ void prep_kernel(const float* __restrict__ src0, const float* __restrict__ src1,
                            const float* __restrict__ hst, const float* __restrict__ zr,
                            ushort_t* __restrict__ Agh, ushort_t* __restrict__ XTh, int t) {
  __shared__ float tile[64][65];
  const int bj = blockIdx.x * 64, bn = blockIdx.y * 64;
  const int tid = threadIdx.x;
  const int jl = tid & 63, nq = tid >> 6;
  const int j = bj + jl;
  const int b = j / C, c = j - b * C;
#pragma unroll
  for (int r = 0; r < 16; ++r) {
    const int node = bn + nq + r * 4;
    const int idx = node * 64 + b;
    float v;
    if (MODE == 0) {
      v = (c == 0) ? src0[((size_t)b * T_ + t) * NN + node]
                   : hst[(size_t)idx * 64 + (c - 1)];
    } else if (MODE == 1) {
      v = (c == 0) ? src0[((size_t)b * T_ + t) * NN + node]
                   : zr[(size_t)idx * 128 + (c - 1)] * hst[(size_t)idx * 64 + (c - 1)];
    } else if (MODE == 2) {
      v = (c == 0) ? src0[idx]
        : (c == 1) ? src1[((size_t)b * HOR_ + t) * NN + node]
                   : hst[(size_t)idx * 96 + (c - 2)];
    } else {
      v = (c == 0) ? src0[idx]
        : (c == 1) ? src1[((size_t)b * HOR_ + t) * NN + node]
                   : zr[(size_t)idx * 192 + (c - 2)] * hst[(size_t)idx * 96 + (c - 2)];
    }
    tile[nq + r * 4][jl] = v;
    Agh[(size_t)idx * KP + c] = f2bh(v);
  }
  __syncthreads();
  const int nl = tid & 63, jq = tid >> 6;
#pragma unroll
  for (int r = 0; r < 16; ++r) {
    const int jj = bj + jq + r * 4;
    XTh[(size_t)jj * NN + bn + nl] = f2bh(tile[nl][jq + r * 4]);
  }
}

// ---------------------------------------------------------------------------
// Graph conv: 32 nodes x 128 j, BK=64, XOR-swizzled LDS.
// A planes = {S1 bf16, M bf16}; B = X bf16. Wave w: plane s=w>>1, jhalf.
// slice1 = S1@X; slice2 = M@X - X (exact -I in fp32 epilogue).
template <int C, int KP>
__global__ void graph_mfma_kernel(const ushort_t* __restrict__ S1h,
                                  const ushort_t* __restrict__ Mh,
                                  const ushort_t* __restrict__ XTh,
                                  ushort_t* __restrict__ Agh) {
  constexpr int W = B_ * C;
  const int bj = blockIdx.x * 128;
  if (bj >= W) return;  // padding block (keeps gridDim.x % 8 == 0)
  __shared__ __align__(16) ushort_t sA[2 * 32 * 64];   // 8 KB
  __shared__ __align__(16) ushort_t sB[128 * 64];      // 16 KB
  const int bn = blockIdx.y * 32;
  const int tid = threadIdx.x;
  const int w = tid >> 6, lane = tid & 63;
  const int row = lane & 15, kq = lane >> 4;
  const int srow8 = lane >> 3;   // row within 8-row stage chunk
  const int sslot = lane & 7;    // LDS 16B slot within row

  const int s = w >> 1;
  const int jhalf = (w & 1) * 64;
  const ushort_t* A_lds = sA + s * (32 * 64);

  f32x4 acc[2][4] = {};
  for (int k0 = 0; k0 < NN; k0 += 64) {
    // 24 stage chunks of 8 rows; wave w stages chunks w, w+4, ..., w+20.
#pragma unroll
    for (int t2 = 0; t2 < 6; ++t2) {
      const int cid = w + t2 * 4;
      if (cid < 8) {  // A: plane p (0=S1,1=M), row-block i
        const int p = cid >> 2, i = cid & 3;
        const int grow = i * 8 + srow8;
        const int gch = sslot ^ (grow & 7);
        const ushort_t* g = (p ? Mh : S1h) + (size_t)(bn + grow) * NN + k0 + gch * 8;
        gload_lds16(g, sA + p * (32 * 64) + i * 512);
      } else {        // B: row-block rb of 16
        const int rb = cid - 8;
        const int brow = rb * 8 + srow8;
        const int gch = sslot ^ (brow & 7);
        const ushort_t* g = XTh + (size_t)(bj + brow) * NN + k0 + gch * 8;
        gload_lds16(g, sB + rb * 512);
      }
    }
    __syncthreads();
    short8 a[2][2];  // [kk][mt]
#pragma unroll
    for (int kk = 0; kk < 2; ++kk)
#pragma unroll
      for (int mt = 0; mt < 2; ++mt) {
        const int r = mt * 16 + row;
        const int chunk = (kk * 4 + kq) ^ (r & 7);
        a[kk][mt] = *(const short8*)(A_lds + r * 64 + chunk * 8);
      }
#pragma unroll
    for (int nt = 0; nt < 4; ++nt) {
#pragma unroll
      for (int kk = 0; kk < 2; ++kk) {
        const int r = jhalf + nt * 16 + row;
        const int chunk = (kk * 4 + kq) ^ (r & 7);
        const short8 bh = *(const short8*)(sB + r * 64 + chunk * 8);
#pragma unroll
        for (int mt = 0; mt < 2; ++mt)
          acc[mt][nt] = __builtin_amdgcn_mfma_f32_16x16x32_bf16(a[kk][mt], bh, acc[mt][nt], 0, 0, 0);
      }
    }
    __syncthreads();
  }
  // D mapping: col (=j) = lane&15, row (=node) = (lane>>4)*4 + reg.
  const int slice_off = (s + 1) * C;
#pragma unroll
  for (int nt = 0; nt < 4; ++nt) {
    const int j = bj + jhalf + nt * 16 + row;
    if (j < W) {
      const int b = j / C, c = j - b * C;
      const size_t coloff = (size_t)(slice_off + c);
#pragma unroll
      for (int mt = 0; mt < 2; ++mt) {
        const int node0 = bn + mt * 16 + kq * 4;
        float sub[4] = {0.f, 0.f, 0.f, 0.f};
        if (s == 1) {  // exact -X for the Chebyshev -I term
          const ushort_t* xp = XTh + (size_t)j * NN + node0;
#pragma unroll
          for (int r = 0; r < 4; ++r) sub[r] = bh2f(xp[r]);
        }
#pragma unroll
        for (int r = 0; r < 4; ++r) {
          const size_t a = (size_t)((node0 + r) * 64 + b) * KP + coloff;
          Agh[a] = f2bh(acc[mt][nt][r] - sub[r]);
        }
      }
    }
  }
}

// ---------------------------------------------------------------------------
// Dense on MFMA, T2-swizzled: A bf16 x W bf16 -> 1 MFMA/pair.
// 128 rows x NO cols. MODE 0: sigmoid -> zr. MODE 1: fused GRU combine.
template <int KP, int NO, int NOP, int MODE, int H>
__global__ void dense_mfma_kernel(const ushort_t* __restrict__ Agh,
                                  const ushort_t* __restrict__ Wth,
                                  const float* __restrict__ bias,
                                  float* __restrict__ outp,
                                  const float* __restrict__ zrin) {
  constexpr int NFR = NO / 16;
  __shared__ __align__(16) ushort_t sAh[128 * 32];
  __shared__ __align__(16) ushort_t sBh[NOP * 32];
  const int row0 = blockIdx.x * 128;
  const int tid = threadIdx.x;
  const int w = tid >> 6, lane = tid & 63;
  const int col16 = lane & 15, four = lane >> 4;
  const int srow = lane >> 2;
  const int scol = ((lane & 3) ^ ((srow >> 1) & 3)) * 8;  // pre-swizzled source
  const int kqs = (four ^ ((col16 >> 1) & 3)) * 8;        // swizzled read slot
  f32x4 acc[2][NFR] = {};
  for (int k0 = 0; k0 < KP; k0 += 32) {
    for (int c = w; c < 8; c += 4) {
      const size_t g = (size_t)(row0 + c * 16 + srow) * KP + k0 + scol;
      gload_lds16(Agh + g, sAh + c * 512);
    }
    for (int c = w; c < NOP / 16; c += 4) {
      const size_t g = (size_t)(c * 16 + srow) * KP + k0 + scol;
      gload_lds16(Wth + g, sBh + c * 512);
    }
    __syncthreads();
    short8 ah[2];
#pragma unroll
    for (int mt = 0; mt < 2; ++mt) {
      const int r = (w * 32 + mt * 16 + col16) * 32 + kqs;
      ah[mt] = *(const short8*)(sAh + r);
    }
#pragma unroll
    for (int nt = 0; nt < NFR; ++nt) {
      const int r = (nt * 16 + col16) * 32 + kqs;
      const short8 bh = *(const short8*)(sBh + r);
#pragma unroll
      for (int mt = 0; mt < 2; ++mt)
        acc[mt][nt] = __builtin_amdgcn_mfma_f32_16x16x32_bf16(ah[mt], bh, acc[mt][nt], 0, 0, 0);
    }
    __syncthreads();
  }
#pragma unroll
  for (int nt = 0; nt < NFR; ++nt) {
    const int col = nt * 16 + col16;
    const float bv = bias[col];
#pragma unroll
    for (int mt = 0; mt < 2; ++mt) {
      const int rbase = row0 + w * 32 + mt * 16 + four * 4;
#pragma unroll
      for (int r = 0; r < 4; ++r) {
        const int row = rbase + r;
        const float v = acc[mt][nt][r] + bv;
        if (MODE == 0) {
          outp[(size_t)row * NO + col] = 1.f / (1.f + expf(-v));
        } else {
          const float rg = zrin[(size_t)row * (2 * H) + H + col];
          const float hv = outp[(size_t)row * H + col];
          outp[(size_t)row * H + col] = rg * hv + (1.f - rg) * tanhf(v);
        }
      }
    }
  }
}

// ---------------------------------------------------------------------------
// attention + prototype + W_E + h0 build, fused. One thread per (n,b).
__global__ void attn_kernel(const float* __restrict__ h, const float* __restrict__ Wq,
                            const float* __restrict__ Mem, const float* __restrict__ FCE,
                            float* __restrict__ hB, float* __restrict__ WE) {
  __shared__ float sWq[64 * 32];
  __shared__ float sM[10 * 32];
  __shared__ float sF[32 * 8];
  const int tid = threadIdx.x;
  for (int i = tid; i < 64 * 32; i += 256) sWq[i] = Wq[i];
  for (int i = tid; i < 10 * 32; i += 256) sM[i] = Mem[i];
  for (int i = tid; i < 32 * 8; i += 256) sF[i] = FCE[i];
  __syncthreads();
  const int idx = blockIdx.x * 256 + tid;
  const float* hp = h + (size_t)idx * 64;
  float* hd = hB + (size_t)idx * 96;
  float q[32] = {};
  for (int i0 = 0; i0 < 16; ++i0) {
    const float4 h4 = *(const float4*)(hp + i0 * 4);
#pragma unroll
    for (int jj = 0; jj < 4; ++jj) {
      const float hv = ((const float*)&h4)[jj];
      hd[i0 * 4 + jj] = hv;  // h0 = [h, proto]
      const int i = i0 * 4 + jj;
#pragma unroll
      for (int c = 0; c < 32; ++c) q[c] += hv * sWq[i * 32 + c];
    }
  }
  float lg[10];
  float mx = -1e30f;
#pragma unroll
  for (int m = 0; m < 10; ++m) {
    float s = 0.f;
#pragma unroll
    for (int c = 0; c < 32; ++c) s += q[c] * sM[m * 32 + c];
    lg[m] = s;
    mx = fmaxf(mx, s);
  }
  float den = 0.f;
#pragma unroll
  for (int m = 0; m < 10; ++m) { lg[m] = expf(lg[m] - mx); den += lg[m]; }
  const float inv = 1.f / den;
  float p[32] = {};
#pragma unroll
  for (int m = 0; m < 10; ++m) {
    const float a = lg[m] * inv;
#pragma unroll
    for (int c = 0; c < 32; ++c) p[c] += a * sM[m * 32 + c];
  }
#pragma unroll
  for (int c = 0; c < 32; ++c) hd[64 + c] = p[c];
  float* wd = WE + (size_t)idx * 8;
#pragma unroll
  for (int e = 0; e < 8; ++e) {
    float s = 0.f;
#pragma unroll
    for (int c = 0; c < 32; ++c) s += p[c] * sF[c * 8 + e];
    wd[e] = s;
  }
}

__global__ void proj_kernel(const float* __restrict__ h, const float* __restrict__ pW,
                            const float* __restrict__ pb, float* __restrict__ go,
                            float* __restrict__ out, int t) {
  __shared__ float sW[96];
  if (threadIdx.x < 96) sW[threadIdx.x] = pW[threadIdx.x];
  __syncthreads();
  const int idx = blockIdx.x * 256 + threadIdx.x;
  const float* hp = h + (size_t)idx * 96;
  float acc = pb[0];
  for (int j0 = 0; j0 < 24; ++j0) {
    const float4 h4 = *(const float4*)(hp + j0 * 4);
    acc += h4.x * sW[j0 * 4] + h4.y * sW[j0 * 4 + 1] + h4.z * sW[j0 * 4 + 2] + h4.w * sW[j0 * 4 + 3];
  }
  go[idx] = acc;
  const int n = idx >> 6, b = idx & 63;
  out[((size_t)b * HOR_ + t) * NN + n] = acc;
}

// ---------------------------------------------------------------------------
extern "C" void kernel_launch(void* const* d_in, const int* in_sizes, int n_in,
                              void* d_out, int out_size, void* d_ws, size_t ws_size,
                              hipStream_t stream) {
  const float* x    = (const float*)d_in[0];
  const float* ycov = (const float*)d_in[1];
  const float* emb  = (const float*)d_in[2];
  const float* egW  = (const float*)d_in[3];
  const float* egb  = (const float*)d_in[4];
  const float* euW  = (const float*)d_in[5];
  const float* eub  = (const float*)d_in[6];
  const float* Mem  = (const float*)d_in[7];
  const float* Wq   = (const float*)d_in[8];
  const float* FCE  = (const float*)d_in[9];
  const float* dgW  = (const float*)d_in[10];
  const float* dgb  = (const float*)d_in[11];
  const float* duW  = (const float*)d_in[12];
  const float* dub  = (const float*)d_in[13];
  const float* pW   = (const float*)d_in[14];
  const float* pb   = (const float*)d_in[15];
  float* out = (float*)d_out;

  char* w = (char*)d_ws;
  auto alloc = [&](size_t bytes) {
    void* p = (void*)w;
    w += (bytes + 255) & ~(size_t)255;
    return p;
  };
  float* S1  = (float*)alloc((size_t)NN * NN * 4);
  float* zr  = (float*)alloc((size_t)NN * B_ * 192 * 4);
  float* hA  = (float*)alloc((size_t)NN * B_ * 64 * 4);
  float* hB  = (float*)alloc((size_t)NN * B_ * 96 * 4);
  float* go  = (float*)alloc((size_t)NN * B_ * 4);
  float* WE  = (float*)alloc((size_t)NN * B_ * 8 * 4);
  ushort_t* S1h = (ushort_t*)alloc((size_t)NN * NN * 2);
  ushort_t* S1l = (ushort_t*)alloc((size_t)NN * NN * 2);
  ushort_t* Mh  = (ushort_t*)alloc((size_t)NN * NN * 2);
  ushort_t* STh = (ushort_t*)alloc((size_t)NN * NN * 2);
  ushort_t* STl = (ushort_t*)alloc((size_t)NN * NN * 2);
  ushort_t* XTh = (ushort_t*)alloc((size_t)B_ * 98 * NN * 2);
  ushort_t* Agh = (ushort_t*)alloc((size_t)NN * B_ * 320 * 2);
  ushort_t* WtegH = (ushort_t*)alloc(128 * 224 * 2);
  ushort_t* WteuH = (ushort_t*)alloc(64 * 224 * 2);
  ushort_t* WtdgH = (ushort_t*)alloc(192 * 320 * 2);
  ushort_t* WtduH = (ushort_t*)alloc(128 * 320 * 2);
  (void)ws_size; (void)in_sizes; (void)n_in; (void)out_size;

  const dim3 blk(256);

  // ---- weight transposes + buffer init (pad regions must be defined) ----
  wt_kernel<<<(128 * 224 + 255) / 256, blk, 0, stream>>>(egW, WtegH, 195, 128, 224, 128);
  wt_kernel<<<(64 * 224 + 255) / 256, blk, 0, stream>>>(euW, WteuH, 195, 64, 224, 64);
  wt_kernel<<<(192 * 320 + 255) / 256, blk, 0, stream>>>(dgW, WtdgH, 294, 192, 320, 192);
  wt_kernel<<<(128 * 320 + 255) / 256, blk, 0, stream>>>(duW, WtduH, 294, 96, 320, 128);
  hipMemsetAsync(Agh, 0, (size_t)NN * B_ * 320 * 2, stream);
  hipMemsetAsync(hA, 0, (size_t)NN * B_ * 64 * 4, stream);
  hipMemsetAsync(go, 0, (size_t)NN * B_ * 4, stream);

  // ---- encoder supports ----
  gemm_nt_kernel<<<dim3(16, 16), blk, 0, stream>>>(emb, emb, S1, NN, 8);
  relu_softmax_kernel<<<NN, blk, 0, stream>>>(S1, S1h, S1l);
  st_kernel<<<dim3(16, 16), blk, 0, stream>>>(S1, STh, STl);
  cheb_mfma_kernel<<<dim3(16, 32), blk, 0, stream>>>(S1h, S1l, STh, STl, Mh);

  // ---- encoder scan ----  (W_enc = 4160; live j-tiles 33, padded to 40)
  for (int t = 0; t < T_; ++t) {
    prep_kernel<65, 224, 0><<<dim3(65, 16), blk, 0, stream>>>(x, nullptr, hA, nullptr, Agh, XTh, t);
    graph_mfma_kernel<65, 224><<<dim3(40, 32), blk, 0, stream>>>(S1h, Mh, XTh, Agh);
    dense_mfma_kernel<224, 128, 128, 0, 64><<<512, blk, 0, stream>>>(Agh, WtegH, egb, zr, nullptr);
    prep_kernel<65, 224, 1><<<dim3(65, 16), blk, 0, stream>>>(x, nullptr, hA, zr, Agh, XTh, t);
    graph_mfma_kernel<65, 224><<<dim3(40, 32), blk, 0, stream>>>(S1h, Mh, XTh, Agh);
    dense_mfma_kernel<224, 64, 64, 1, 64><<<512, blk, 0, stream>>>(Agh, WteuH, eub, hA, zr);
  }

  // ---- attention / memory / decoder supports ----
  attn_kernel<<<256, blk, 0, stream>>>(hA, Wq, Mem, FCE, hB, WE);
  gemm_nt_kernel<<<dim3(16, 16), blk, 0, stream>>>(WE, WE, S1, NN, 512);
  relu_softmax_kernel<<<NN, blk, 0, stream>>>(S1, S1h, S1l);
  st_kernel<<<dim3(16, 16), blk, 0, stream>>>(S1, STh, STl);
  cheb_mfma_kernel<<<dim3(16, 32), blk, 0, stream>>>(S1h, S1l, STh, STl, Mh);

  // ---- decoder scan ----  (W_dec = 6272; live j-tiles 49, padded to 56)
  for (int t = 0; t < HOR_; ++t) {
    prep_kernel<98, 320, 2><<<dim3(98, 16), blk, 0, stream>>>(go, ycov, hB, nullptr, Agh, XTh, t);
    graph_mfma_kernel<98, 320><<<dim3(56, 32), blk, 0, stream>>>(S1h, Mh, XTh, Agh);
    dense_mfma_kernel<320, 192, 192, 0, 96><<<512, blk, 0, stream>>>(Agh, WtdgH, dgb, zr, nullptr);
    prep_kernel<98, 320, 3><<<dim3(98, 16), blk, 0, stream>>>(go, ycov, hB, zr, Agh, XTh, t);
    graph_mfma_kernel<98, 320><<<dim3(56, 32), blk, 0, stream>>>(S1h, Mh, XTh, Agh);
    dense_mfma_kernel<320, 96, 128, 1, 96><<<512, blk, 0, stream>>>(Agh, WtduH, dub, hB, zr);
    proj_kernel<<<256, blk, 0, stream>>>(hB, pW, pb, go, out, t);
  }
}